// Round 14
// baseline (686.786 us; speedup 1.0000x reference)
//
#include <hip/hip_runtime.h>
#include <stdint.h>

typedef unsigned short u16;
typedef __bf16 bf16x8 __attribute__((ext_vector_type(8)));
typedef float f32x4 __attribute__((ext_vector_type(4)));

#define D_MODEL 2048
#define NHEADS 16
#define DK 128
#define DFF 5504
#define DFFP 5632
#define BB 2
#define SS 2048
#define MTOK 4096
#define DQKV 6144

#define AS1 __attribute__((address_space(1)))
#define AS3 __attribute__((address_space(3)))

__device__ __forceinline__ u16 f2bf(float f){
  union { float f; uint32_t u; } v; v.f = f;
  uint32_t r = v.u + 0x7fffu + ((v.u >> 16) & 1u);
  return (u16)(r >> 16);
}
__device__ __forceinline__ float bf2f(u16 u){
  union { uint32_t u; float f; } v; v.u = ((uint32_t)u) << 16;
  return v.f;
}
__device__ __forceinline__ u16 cvt_bf16(float f){
  union { __bf16 h; u16 u; } v; v.h = (__bf16)f; return v.u;
}
__device__ __forceinline__ float fexp2(float x){
#if __has_builtin(__builtin_amdgcn_exp2f)
  return __builtin_amdgcn_exp2f(x);
#else
  return exp2f(x);
#endif
}

// ---- fp32 W[K][Nsrc] -> bf16 Wt[n][K], zero-fill n >= Nsrc ----
__global__ __launch_bounds__(256) void k_transpose_w(const float* __restrict__ W,
                                                     u16* __restrict__ Wt, int K, int Nsrc){
  __shared__ float tile[32][33];
  int n0 = blockIdx.x * 32, k0 = blockIdx.y * 32;
  int tx = threadIdx.x, ty = threadIdx.y;
  #pragma unroll
  for (int r = 0; r < 4; ++r){
    int n = n0 + tx;
    tile[ty + r*8][tx] = (n < Nsrc) ? W[(size_t)(k0 + ty + r*8) * Nsrc + n] : 0.0f;
  }
  __syncthreads();
  #pragma unroll
  for (int r = 0; r < 4; ++r)
    Wt[(size_t)(n0 + ty + r*8) * K + k0 + tx] = f2bf(tile[tx][ty + r*8]);
}

// ---- batched 2048x2048 transpose: z selects among 4 matrices ----
__global__ __launch_bounds__(256) void k_transpose_w4(
    const float* __restrict__ w0s, const float* __restrict__ w1s,
    const float* __restrict__ w2s, const float* __restrict__ w3s,
    u16* __restrict__ d0, u16* __restrict__ d1,
    u16* __restrict__ d2, u16* __restrict__ d3){
  __shared__ float tile[32][33];
  const float* W = blockIdx.z == 0 ? w0s : blockIdx.z == 1 ? w1s : blockIdx.z == 2 ? w2s : w3s;
  u16* Wt = blockIdx.z == 0 ? d0 : blockIdx.z == 1 ? d1 : blockIdx.z == 2 ? d2 : d3;
  int n0 = blockIdx.x * 32, k0 = blockIdx.y * 32;
  int tx = threadIdx.x, ty = threadIdx.y;
  #pragma unroll
  for (int r = 0; r < 4; ++r)
    tile[ty + r*8][tx] = W[(size_t)(k0 + ty + r*8) * D_MODEL + n0 + tx];
  __syncthreads();
  #pragma unroll
  for (int r = 0; r < 4; ++r)
    Wt[(size_t)(n0 + ty + r*8) * D_MODEL + k0 + tx] = f2bf(tile[tx][ty + r*8]);
}

// ---- batched DFFP-row transpose: z=0 -> w1, z=1 -> w3 (zero-pad past DFF) ----
__global__ __launch_bounds__(256) void k_transpose_w13(
    const float* __restrict__ w1s, const float* __restrict__ w3s,
    u16* __restrict__ dst){
  __shared__ float tile[32][33];
  const float* W = blockIdx.z == 0 ? w1s : w3s;
  u16* Wt = dst + (size_t)blockIdx.z * DFFP * D_MODEL;
  int n0 = blockIdx.x * 32, k0 = blockIdx.y * 32;
  int tx = threadIdx.x, ty = threadIdx.y;
  #pragma unroll
  for (int r = 0; r < 4; ++r){
    int n = n0 + tx;
    tile[ty + r*8][tx] = (n < DFF) ? W[(size_t)(k0 + ty + r*8) * DFF + n] : 0.0f;
  }
  __syncthreads();
  #pragma unroll
  for (int r = 0; r < 4; ++r)
    Wt[(size_t)(n0 + ty + r*8) * D_MODEL + k0 + tx] = f2bf(tile[tx][ty + r*8]);
}

// ---- per-head V transpose from fused QKV ----
__global__ __launch_bounds__(256) void k_transpose_v(const u16* __restrict__ V,
                                                     u16* __restrict__ Vt, int ld){
  __shared__ u16 tile[32][33];
  int s0 = blockIdx.x * 32;
  int bh = blockIdx.y >> 2, dt = blockIdx.y & 3;
  int b = bh >> 4, h = bh & 15;
  int tx = threadIdx.x, ty = threadIdx.y;
  #pragma unroll
  for (int r = 0; r < 4; ++r)
    tile[ty + r*8][tx] = V[(size_t)(b*SS + s0 + ty + r*8) * ld + h*DK + dt*32 + tx];
  __syncthreads();
  #pragma unroll
  for (int r = 0; r < 4; ++r)
    Vt[(size_t)(bh*DK + dt*32 + ty + r*8) * SS + s0 + tx] = tile[tx][ty + r*8];
}

__global__ __launch_bounds__(256) void k_concat3(const float* __restrict__ a,
                                                 const float* __restrict__ b,
                                                 const float* __restrict__ c,
                                                 float* __restrict__ o){
  int i = blockIdx.x*256 + threadIdx.x;
  if (i >= DQKV) return;
  o[i] = (i < 2048) ? a[i] : (i < 4096 ? b[i-2048] : c[i-4096]);
}

// ---- RMSNorm: fp32 row -> bf16 row ----
__global__ __launch_bounds__(256) void k_rmsnorm(const float* __restrict__ X,
                                                 const float* __restrict__ g,
                                                 u16* __restrict__ out){
  int row = blockIdx.x, tid = threadIdx.x;
  const float* x = X + (size_t)row * D_MODEL;
  float4 a = ((const float4*)x)[tid*2];
  float4 b = ((const float4*)x)[tid*2+1];
  float ss = a.x*a.x + a.y*a.y + a.z*a.z + a.w*a.w
           + b.x*b.x + b.y*b.y + b.z*b.z + b.w*b.w;
  #pragma unroll
  for (int m = 1; m < 64; m <<= 1) ss += __shfl_xor(ss, m, 64);
  __shared__ float red[4];
  if ((tid & 63) == 0) red[tid >> 6] = ss;
  __syncthreads();
  float tot = red[0] + red[1] + red[2] + red[3];
  float sc = rsqrtf(tot * (1.0f / D_MODEL) + 1e-6f);
  float4 ga = ((const float4*)g)[tid*2];
  float4 gb = ((const float4*)g)[tid*2+1];
  uint32_t w0 = f2bf(a.x*sc*ga.x) | ((uint32_t)f2bf(a.y*sc*ga.y) << 16);
  uint32_t w1 = f2bf(a.z*sc*ga.z) | ((uint32_t)f2bf(a.w*sc*ga.w) << 16);
  uint32_t w2 = f2bf(b.x*sc*gb.x) | ((uint32_t)f2bf(b.y*sc*gb.y) << 16);
  uint32_t w3 = f2bf(b.z*sc*gb.z) | ((uint32_t)f2bf(b.w*sc*gb.w) << 16);
  ((uint4*)(out + (size_t)row * D_MODEL))[tid] = make_uint4(w0, w1, w2, w3);
}

// ---- fused: out = x + bias + p0 + p1 ; nrm = rmsnorm(out)*g (bf16) ----
__global__ __launch_bounds__(256) void k_addres_rms(
    const float* __restrict__ X, const float* __restrict__ bias,
    const float* __restrict__ p0, const float* __restrict__ p1,
    const float* __restrict__ g, float* __restrict__ out,
    u16* __restrict__ nrm){
  int row = blockIdx.x, tid = threadIdx.x;
  size_t base = (size_t)row * D_MODEL;
  float4 a  = ((const float4*)(X  + base))[tid*2];
  float4 b  = ((const float4*)(X  + base))[tid*2+1];
  float4 ba = ((const float4*)bias)[tid*2];
  float4 bb = ((const float4*)bias)[tid*2+1];
  float4 pa = ((const float4*)(p0 + base))[tid*2];
  float4 pb = ((const float4*)(p0 + base))[tid*2+1];
  float4 qa = ((const float4*)(p1 + base))[tid*2];
  float4 qb = ((const float4*)(p1 + base))[tid*2+1];
  a.x += ba.x + pa.x + qa.x; a.y += ba.y + pa.y + qa.y;
  a.z += ba.z + pa.z + qa.z; a.w += ba.w + pa.w + qa.w;
  b.x += bb.x + pb.x + qb.x; b.y += bb.y + pb.y + qb.y;
  b.z += bb.z + pb.z + qb.z; b.w += bb.w + pb.w + qb.w;
  ((float4*)(out + base))[tid*2]   = a;
  ((float4*)(out + base))[tid*2+1] = b;
  float ss = a.x*a.x + a.y*a.y + a.z*a.z + a.w*a.w
           + b.x*b.x + b.y*b.y + b.z*b.z + b.w*b.w;
  #pragma unroll
  for (int m = 1; m < 64; m <<= 1) ss += __shfl_xor(ss, m, 64);
  __shared__ float red[4];
  if ((tid & 63) == 0) red[tid >> 6] = ss;
  __syncthreads();
  float tot = red[0] + red[1] + red[2] + red[3];
  float sc = rsqrtf(tot * (1.0f / D_MODEL) + 1e-6f);
  float4 ga = ((const float4*)g)[tid*2];
  float4 gb = ((const float4*)g)[tid*2+1];
  uint32_t w0 = f2bf(a.x*sc*ga.x) | ((uint32_t)f2bf(a.y*sc*ga.y) << 16);
  uint32_t w1 = f2bf(a.z*sc*ga.z) | ((uint32_t)f2bf(a.w*sc*ga.w) << 16);
  uint32_t w2 = f2bf(b.x*sc*gb.x) | ((uint32_t)f2bf(b.y*sc*gb.y) << 16);
  uint32_t w3 = f2bf(b.z*sc*gb.z) | ((uint32_t)f2bf(b.w*sc*gb.w) << 16);
  ((uint4*)(nrm + base))[tid] = make_uint4(w0, w1, w2, w3);
}

// ---- hg = silu(h1) * h3 (bf16, 8 elems/thread) ----
__global__ __launch_bounds__(256) void k_silu_mul(const u16* __restrict__ a,
                                                  const u16* __restrict__ b,
                                                  u16* __restrict__ o, int n8){
  int i = blockIdx.x * 256 + threadIdx.x;
  if (i >= n8) return;
  uint4 av = ((const uint4*)a)[i];
  uint4 bv = ((const uint4*)b)[i];
  uint32_t aa[4] = {av.x, av.y, av.z, av.w};
  uint32_t bb[4] = {bv.x, bv.y, bv.z, bv.w};
  uint32_t rr[4];
  #pragma unroll
  for (int j = 0; j < 4; ++j){
    float x0 = bf2f((u16)(aa[j] & 0xffff)), x1 = bf2f((u16)(aa[j] >> 16));
    float y0 = bf2f((u16)(bb[j] & 0xffff)), y1 = bf2f((u16)(bb[j] >> 16));
    float r0 = x0 / (1.f + __expf(-x0)) * y0;
    float r1 = x1 / (1.f + __expf(-x1)) * y1;
    rr[j] = f2bf(r0) | ((uint32_t)f2bf(r1) << 16);
  }
  ((uint4*)o)[i] = make_uint4(rr[0], rr[1], rr[2], rr[3]);
}

// ============ 256x256 8-wave GEMM — 8-phase, balanced stages, counted vmcnt ============
// row&7 chunk swizzle both-sides (conflict-free, verified r10).
// EPI 0: bf16 +bias; EPI 5: dual bf16 out (n0<5632 -> Cout, else aux-5632)
// EPI 6: split-K x2 -> fp32 partials (slice0 -> Cout, slice1 -> aux)
// EPI 7: split-K x2 -> fp32 atomicAdd into Cout (residual accumulate)
template<int EPI>
__global__ __launch_bounds__(512, 2) void k_gemm8p(
    const u16* __restrict__ A, const u16* __restrict__ Bt,
    const float* __restrict__ bias, const u16* __restrict__ aux,
    void* __restrict__ Cout, int M, int N, int K,
    int lda, int ldb, int ldc)
{
  extern __shared__ __align__(16) char smem[];
  const int tid = threadIdx.x;
  const int lane = tid & 63, wid = tid >> 6;
  const int wr = wid >> 2, wc = wid & 3;
  const int lrow = lane & 15, lhi = lane >> 4;

  int nwg = gridDim.x, wg = blockIdx.x;
  int ksl = 0;
  if constexpr (EPI == 6 || EPI == 7){
    int hn = nwg >> 1;
    if (wg >= hn){ ksl = 1; wg -= hn; }
    nwg = hn;
    A  += (size_t)ksl * K;
    Bt += (size_t)ksl * K;
  }

  int nbx = N >> 8, nbm = M >> 8;
  int xcd = wg & 7, sub = wg >> 3;
  int m0, n0;
  if ((nwg & 7) == 0 && (nbm & 1) == 0 && (nbx & 3) == 0){
    int mh = nbm >> 1;
    int mr = sub % mh, nc = sub / mh;
    m0 = (((xcd & 1) * mh) + mr) << 8;
    n0 = (((xcd >> 1) * (nbx >> 2)) + nc) << 8;
  } else {
    int qq = nwg >> 3, rr2 = nwg & 7;
    int swz = (xcd < rr2 ? xcd*(qq+1) : rr2*(qq+1) + (xcd-rr2)*qq) + sub;
    m0 = (swz / nbx) << 8; n0 = (swz % nbx) << 8;
  }

  const int nk = K >> 6;
  const int hA = wr, hB = wc >> 1;
  const int gA = wc;
  const int gB = (wr << 1) | (wc & 1);

  const u16* aSrc[2][2]; int aDst[2][2];
  const u16* bSrc[2][2]; int bDst[2][2];
  #pragma unroll
  for (int q = 0; q < 2; ++q)
    #pragma unroll
    for (int L = 0; L < 2; ++L){
      int p = q*8192 + gA*2048 + L*1024 + lane*16;
      int row = p >> 7;
      int o = (p & 127) ^ ((row & 7) << 4);
      aSrc[q][L] = A + (size_t)(m0 + hA*128 + row)*lda + (o >> 1);
      aDst[q][L] = hA*16384 + p;
      int pb = q*4096 + (gB >> 1)*8192 + (gB & 1)*2048 + L*1024 + lane*16;
      int rowb = pb >> 7;
      int ob = (pb & 127) ^ ((rowb & 7) << 4);
      bSrc[q][L] = Bt + (size_t)(n0 + hB*128 + rowb)*ldb + (ob >> 1);
      bDst[q][L] = 32768 + hB*16384 + pb;
    }
  const int xo0 = (lhi*16) ^ ((lrow & 7) << 4);
  const int xo1 = (64 + lhi*16) ^ ((lrow & 7) << 4);

  auto stA = [&](int d, int kk, int q){
    #pragma unroll
    for (int L = 0; L < 2; ++L)
      __builtin_amdgcn_global_load_lds(
        (const AS1 void*)(aSrc[q][L] + kk),
        (AS3 void*)(smem + d*65536 + aDst[q][L]), 16, 0, 0);
  };
  auto stB = [&](int d, int kk, int s){
    #pragma unroll
    for (int L = 0; L < 2; ++L)
      __builtin_amdgcn_global_load_lds(
        (const AS1 void*)(bSrc[s][L] + kk),
        (AS3 void*)(smem + d*65536 + bDst[s][L]), 16, 0, 0);
  };
  auto rdA = [&](int d, int rloc, int ks)->bf16x8{
    return *(const bf16x8*)(smem + d*65536 + hA*16384 + rloc*128 + (ks ? xo1 : xo0));
  };
  auto rdB = [&](int d, int rloc, int ks)->bf16x8{
    return *(const bf16x8*)(smem + d*65536 + 32768 + hB*16384 + rloc*128 + (ks ? xo1 : xo0));
  };

  f32x4 acc[8][4] = {};

  // prologue in issue order Aq0, Bs0, Bs1, Aq1 (positions 1-8)
  stA(0, 0, 0); stB(0, 0, 0); stB(0, 0, 1); stA(0, 0, 1);
  asm volatile("s_waitcnt vmcnt(0)" ::: "memory");
  __builtin_amdgcn_s_barrier();

  for (int t = 0; t < nk; ++t){
    int d = t & 1, dn = d ^ 1, kkn = (t + 1) << 6;
    bool pf = (t + 1 < nk);
    bf16x8 aR[8], bQ0[4], bQ1[4];

    // ---- phase 0: Q00 (reads Aq0+Bs0-own; stage t+1 Aq0) ----
    #pragma unroll
    for (int ii = 0; ii < 4; ++ii){
      aR[ii*2]   = rdA(d, ii*16 + lrow, 0);
      aR[ii*2+1] = rdA(d, ii*16 + lrow, 1);
    }
    #pragma unroll
    for (int j = 0; j < 2; ++j){
      bQ0[j*2]   = rdB(d, (wc&1)*64 + j*16 + lrow, 0);
      bQ0[j*2+1] = rdB(d, (wc&1)*64 + j*16 + lrow, 1);
    }
    if (pf) stA(dn, kkn, 0);
    __builtin_amdgcn_s_barrier();
    asm volatile("s_waitcnt lgkmcnt(0)" ::: "memory");
    __builtin_amdgcn_sched_barrier(0);
    __builtin_amdgcn_s_setprio(1);
    #pragma unroll
    for (int ii = 0; ii < 4; ++ii)
      #pragma unroll
      for (int j = 0; j < 2; ++j){
        acc[ii][j] = __builtin_amdgcn_mfma_f32_16x16x32_bf16(aR[ii*2],   bQ0[j*2],   acc[ii][j], 0, 0, 0);
        acc[ii][j] = __builtin_amdgcn_mfma_f32_16x16x32_bf16(aR[ii*2+1], bQ0[j*2+1], acc[ii][j], 0, 0, 0);
      }
    __builtin_amdgcn_s_setprio(0);
    if (pf) asm volatile("s_waitcnt vmcnt(4)" ::: "memory");   // t's Bs1 landed
    else    asm volatile("s_waitcnt vmcnt(2)" ::: "memory");
    __builtin_amdgcn_sched_barrier(0);
    __builtin_amdgcn_s_barrier();

    // ---- phase 1: Q01 (reads Bs1-own; stage t+1 Bs0; reuse aR) ----
    #pragma unroll
    for (int j = 0; j < 2; ++j){
      bQ1[j*2]   = rdB(d, (wc&1)*64 + 32 + j*16 + lrow, 0);
      bQ1[j*2+1] = rdB(d, (wc&1)*64 + 32 + j*16 + lrow, 1);
    }
    if (pf) stB(dn, kkn, 0);
    __builtin_amdgcn_s_barrier();
    asm volatile("s_waitcnt lgkmcnt(0)" ::: "memory");
    __builtin_amdgcn_sched_barrier(0);
    __builtin_amdgcn_s_setprio(1);
    #pragma unroll
    for (int ii = 0; ii < 4; ++ii)
      #pragma unroll
      for (int j = 0; j < 2; ++j){
        acc[ii][2+j] = __builtin_amdgcn_mfma_f32_16x16x32_bf16(aR[ii*2],   bQ1[j*2],   acc[ii][2+j], 0, 0, 0);
        acc[ii][2+j] = __builtin_amdgcn_mfma_f32_16x16x32_bf16(aR[ii*2+1], bQ1[j*2+1], acc[ii][2+j], 0, 0, 0);
      }
    __builtin_amdgcn_s_setprio(0);
    if (pf) asm volatile("s_waitcnt vmcnt(4)" ::: "memory");   // t's Aq1 landed
    else    asm volatile("s_waitcnt vmcnt(0)" ::: "memory");
    __builtin_amdgcn_sched_barrier(0);
    __builtin_amdgcn_s_barrier();

    // ---- phase 2: Q11 (reads Aq1; stage t+1 Bs1; reuse bQ1) ----
    #pragma unroll
    for (int ii = 0; ii < 4; ++ii){
      aR[ii*2]   = rdA(d, 64 + ii*16 + lrow, 0);
      aR[ii*2+1] = rdA(d, 64 + ii*16 + lrow, 1);
    }
    if (pf) stB(dn, kkn, 1);
    __builtin_amdgcn_s_barrier();
    asm volatile("s_waitcnt lgkmcnt(0)" ::: "memory");
    __builtin_amdgcn_sched_barrier(0);
    __builtin_amdgcn_s_setprio(1);
    #pragma unroll
    for (int ii = 0; ii < 4; ++ii)
      #pragma unroll
      for (int j = 0; j < 2; ++j){
        acc[4+ii][2+j] = __builtin_amdgcn_mfma_f32_16x16x32_bf16(aR[ii*2],   bQ1[j*2],   acc[4+ii][2+j], 0, 0, 0);
        acc[4+ii][2+j] = __builtin_amdgcn_mfma_f32_16x16x32_bf16(aR[ii*2+1], bQ1[j*2+1], acc[4+ii][2+j], 0, 0, 0);
      }
    __builtin_amdgcn_s_setprio(0);
    __builtin_amdgcn_s_barrier();

    // ---- phase 3: Q10 (no reads; stage t+1 Aq1; reuse aR + bQ0) ----
    if (pf) stA(dn, kkn, 1);
    __builtin_amdgcn_s_setprio(1);
    #pragma unroll
    for (int ii = 0; ii < 4; ++ii)
      #pragma unroll
      for (int j = 0; j < 2; ++j){
        acc[4+ii][j] = __builtin_amdgcn_mfma_f32_16x16x32_bf16(aR[ii*2],   bQ0[j*2],   acc[4+ii][j], 0, 0, 0);
        acc[4+ii][j] = __builtin_amdgcn_mfma_f32_16x16x32_bf16(aR[ii*2+1], bQ0[j*2+1], acc[4+ii][j], 0, 0, 0);
      }
    __builtin_amdgcn_s_setprio(0);
    if (pf) asm volatile("s_waitcnt vmcnt(4)" ::: "memory");   // t+1's Aq0,Bs0 landed
    __builtin_amdgcn_sched_barrier(0);
    __builtin_amdgcn_s_barrier();
  }

  // epilogue
  if constexpr (EPI == 6){
    float* P = ksl ? (float*)aux : (float*)Cout;
    #pragma unroll
    for (int i = 0; i < 8; ++i)
      #pragma unroll
      for (int j = 0; j < 4; ++j){
        int col = n0 + wc*64 + j*16 + lrow;
        #pragma unroll
        for (int q = 0; q < 4; ++q){
          int row = m0 + wr*128 + i*16 + lhi*4 + q;
          P[(size_t)row*ldc + col] = acc[i][j][q];
        }
      }
    return;
  }
  if constexpr (EPI == 7){
    float* P = (float*)Cout;
    #pragma unroll
    for (int i = 0; i < 8; ++i)
      #pragma unroll
      for (int j = 0; j < 4; ++j){
        int col = n0 + wc*64 + j*16 + lrow;
        #pragma unroll
        for (int q = 0; q < 4; ++q){
          int row = m0 + wr*128 + i*16 + lhi*4 + q;
          atomicAdd(P + (size_t)row*ldc + col, acc[i][j][q]);
        }
      }
    return;
  }
  u16* Cw = (u16*)Cout;
  int cofs = 0;
  if constexpr (EPI == 5){
    if (n0 >= 5632){ Cw = (u16*)aux; cofs = 5632; }
  }
  #pragma unroll
  for (int i = 0; i < 8; ++i){
    #pragma unroll
    for (int j = 0; j < 4; ++j){
      int col = n0 + wc*64 + j*16 + lrow;
      float bv = 0.f;
      if constexpr (EPI == 0) bv = bias[col];
      #pragma unroll
      for (int q = 0; q < 4; ++q){
        int row = m0 + wr*128 + i*16 + lhi*4 + q;
        float v = acc[i][j][q] + bv;
        Cw[(size_t)row*ldc + (col - cofs)] = f2bf(v);
      }
    }
  }
}

// ---- 128x128 GEMM (3-buffer counted vmcnt, row&3 chunk swizzle) — fallback ----
template<int EPI>
__global__ __launch_bounds__(256) void k_gemm_bt(
    const u16* __restrict__ A, const u16* __restrict__ Bt,
    const float* __restrict__ bias, const float* __restrict__ res,
    const u16* __restrict__ aux,
    void* __restrict__ Cout, int M, int N, int K,
    int lda, int ldb, int ldc)
{
  __shared__ __align__(16) u16 As[3][128*32];
  __shared__ __align__(16) u16 Bs[3][128*32];
  int tid = threadIdx.x;

  int nwg = gridDim.x, wg = blockIdx.x;
  int qq = nwg >> 3, rr = nwg & 7;
  int xcd = wg & 7, sub = wg >> 3;
  int swz = (xcd < rr ? xcd*(qq+1) : rr*(qq+1) + (xcd-rr)*qq) + sub;
  int nbx = N >> 7;
  int m0 = (swz / nbx) << 7, n0 = (swz % nbx) << 7;

  int lane = tid & 63, wave = tid >> 6;
  int wr = wave >> 1, wc = wave & 1;
  int lrow = lane & 15, lhi = lane >> 4;
  f32x4 acc[4][4] = {};
  int srow = tid >> 2;
  int schk = tid & 3;
  const int nk = K >> 5;

  auto stage = [&](int slot, int kt){
    int k0 = kt << 5;
    int c = schk ^ (srow & 3);
    #pragma unroll
    for (int cc = 0; cc < 2; ++cc){
      int r = cc*64 + srow;
      __builtin_amdgcn_global_load_lds(
        (const AS1 void*)(A + (size_t)(m0 + r)*lda + k0 + c*8),
        (AS3 void*)(&As[slot][r*32 + schk*8]), 16, 0, 0);
      __builtin_amdgcn_global_load_lds(
        (const AS1 void*)(Bt + (size_t)(n0 + r)*ldb + k0 + c*8),
        (AS3 void*)(&Bs[slot][r*32 + schk*8]), 16, 0, 0);
    }
  };

  stage(0, 0);
  if (nk > 1) stage(1, 1);
  if (nk > 1) asm volatile("s_waitcnt vmcnt(4)" ::: "memory");
  else        asm volatile("s_waitcnt vmcnt(0)" ::: "memory");
  __builtin_amdgcn_s_barrier();

  for (int kt = 0; kt < nk; ++kt){
    int cur = kt % 3;
    if (kt + 2 < nk) stage((kt + 2) % 3, kt + 2);
    int rchk = lhi ^ (lrow & 3);
    bf16x8 af[4], bfv[4];
    #pragma unroll
    for (int i = 0; i < 4; ++i){
      af[i]  = *(const bf16x8*)(&As[cur][(wr*64 + i*16 + lrow)*32 + rchk*8]);
      bfv[i] = *(const bf16x8*)(&Bs[cur][(wc*64 + i*16 + lrow)*32 + rchk*8]);
    }
    #pragma unroll
    for (int i = 0; i < 4; ++i)
      #pragma unroll
      for (int j = 0; j < 4; ++j)
        acc[i][j] = __builtin_amdgcn_mfma_f32_16x16x32_bf16(af[i], bfv[j], acc[i][j], 0, 0, 0);
    if (kt + 2 < nk) asm volatile("s_waitcnt vmcnt(4)" ::: "memory");
    else             asm volatile("s_waitcnt vmcnt(0)" ::: "memory");
    __builtin_amdgcn_s_barrier();
  }

  #pragma unroll
  for (int i = 0; i < 4; ++i){
    #pragma unroll
    for (int j = 0; j < 4; ++j){
      int col = n0 + wc*64 + j*16 + lrow;
      float bv = 0.f;
      if constexpr (EPI == 0 || EPI == 1) bv = bias[col];
      #pragma unroll
      for (int q = 0; q < 4; ++q){
        int row = m0 + wr*64 + i*16 + lhi*4 + q;
        size_t idx = (size_t)row*ldc + col;
        float v = acc[i][j][q] + bv;
        if constexpr (EPI == 1 || EPI == 3) v += res[idx];
        if constexpr (EPI == 4){
          float a0 = bf2f(aux[idx]);
          v = a0 / (1.f + __expf(-a0)) * v;
        }
        if constexpr (EPI == 0 || EPI == 2 || EPI == 4) ((u16*)Cout)[idx] = f2bf(v);
        else ((float*)Cout)[idx] = v;
      }
    }
  }
}

// ---- causal flash attention: paired-qblock load balancing (unchanged) ----
__global__ __launch_bounds__(512) void k_attn(
    const u16* __restrict__ Q, const u16* __restrict__ Kb,
    const u16* __restrict__ Vt, u16* __restrict__ O, int ldq)
{
  int tid = threadIdx.x, lane = tid & 63, wave = tid >> 6;
  int lrow = lane & 15, lhi = lane >> 4;
  int bidx = blockIdx.x;
  int bh = bidx >> 3, j = bidx & 7;
  int b = bh >> 4, h = bh & 15;

  __shared__ __align__(16) u16 Kbuf[2][64*128];
  __shared__ __align__(16) u16 Vbuf[2][128*64];
  __shared__ __align__(16) u16 P_lds[8][16*64];
  char* pw = (char*)&P_lds[wave][0];
  const float sc2 = 0.08838834764831845f * 1.44269504088896340736f;

  auto stage = [&](int bufi, int kt){
    int kv0 = kt << 6;
    char* kd = (char*)&Kbuf[bufi][0];
    char* vd = (char*)&Vbuf[bufi][0];
    #pragma unroll
    for (int L = 0; L < 2; ++L){
      int cid = wave*128 + L*64 + lane;
      int r = cid >> 4, c = cid & 15;
      int cg = c ^ (r & 7);
      __builtin_amdgcn_global_load_lds(
        (const AS1 void*)(Kb + (size_t)(b*SS + kv0 + r)*ldq + h*DK + cg*8),
        (AS3 void*)(kd + wave*2048 + L*1024 + lane*16), 16, 0, 0);
      int dd = cid >> 3, c8 = cid & 7;
      int cv = c8 ^ (dd & 7);
      __builtin_amdgcn_global_load_lds(
        (const AS1 void*)(Vt + (size_t)bh*DK*SS + (size_t)dd*SS + kv0 + cv*8),
        (AS3 void*)(vd + wave*2048 + L*1024 + lane*16), 16, 0, 0);
    }
  };

  #pragma unroll 1
  for (int item = 0; item < 2; ++item){
    int qi = item == 0 ? 15 - j : j;
    int qs = qi * 128;
    int nt = 2*qi + 2;
    int qrow = qs + wave * 16;

    bf16x8 qf[4];
    const u16* qbase = Q + (size_t)(b*SS + qrow + lrow)*ldq + h*DK + lhi*8;
    #pragma unroll
    for (int dc = 0; dc < 4; ++dc) qf[dc] = *(const bf16x8*)(qbase + dc*32);

    f32x4 accO[8] = {};
    float mr[4] = {-1e30f,-1e30f,-1e30f,-1e30f};
    float lr[4] = {0.f,0.f,0.f,0.f};

    stage(0, 0);
    __syncthreads();

    for (int kt = 0; kt < nt; ++kt){
      int cur = kt & 1;
      if (kt + 1 < nt) stage(cur ^ 1, kt + 1);
      int kv0 = kt << 6;
      if (kv0 <= qrow + 15){
        const char* kl = (const char*)&Kbuf[cur][0];
        const char* vl = (const char*)&Vbuf[cur][0];
        bool domask = (kv0 + 63 > qrow);

        f32x4 sf[4];
        #pragma unroll
        for (int hf = 0; hf < 4; ++hf){
          int rl = hf*16 + lrow;
          int sw = rl & 7;
          f32x4 a = {};
          #pragma unroll
          for (int dc = 0; dc < 4; ++dc){
            bf16x8 kf = *(const bf16x8*)(kl + rl*256 + (((lhi + dc*4) ^ sw) << 4));
            a = __builtin_amdgcn_mfma_f32_16x16x32_bf16(qf[dc], kf, a, 0, 0, 0);
          }
          sf[hf] = a;
        }

        float p[4][4], mx[4];
        #pragma unroll
        for (int q = 0; q < 4; ++q){
          float s0 = sf[0][q]*sc2, s1 = sf[1][q]*sc2, s2 = sf[2][q]*sc2, s3 = sf[3][q]*sc2;
          if (domask){
            int qg = qrow + lhi*4 + q;
            if (kv0      + lrow > qg) s0 = -1e30f;
            if (kv0 + 16 + lrow > qg) s1 = -1e30f;
            if (kv0 + 32 + lrow > qg) s2 = -1e30f;
            if (kv0 + 48 + lrow > qg) s3 = -1e30f;
          }
          p[q][0]=s0; p[q][1]=s1; p[q][2]=s2; p[q][3]=s3;
          float m = fmaxf(fmaxf(s0,s1), fmaxf(s2,s3));
          m = fmaxf(m, __shfl_xor(m, 1, 64));
          m = fmaxf(m, __shfl_xor(m, 2, 64));
          m = fmaxf(m, __shfl_xor(m, 4, 64));
          m = fmaxf(m, __shfl_xor(m, 8, 64));
          mx[q] = m;
        }
        float dmax = fmaxf(fmaxf(mx[0]-mr[0], mx[1]-mr[1]), fmaxf(mx[2]-mr[2], mx[3]-mr[3]));
        bool rescale = !__all(dmax <= 8.0f);
        float al[4];
        #pragma unroll
        for (int q = 0; q < 4; ++q){
          if (rescale){
            float mn = fmaxf(mr[q], mx[q]);
            al[q] = fexp2(mr[q] - mn);
            mr[q] = mn;
          } else al[q] = 1.0f;
          p[q][0] = fexp2(p[q][0] - mr[q]);
          p[q][1] = fexp2(p[q][1] - mr[q]);
          p[q][2] = fexp2(p[q][2] - mr[q]);
          p[q][3] = fexp2(p[q][3] - mr[q]);
          float sm = (p[q][0] + p[q][1]) + (p[q][2] + p[q][3]);
          sm += __shfl_xor(sm, 1, 64);
          sm += __shfl_xor(sm, 2, 64);
          sm += __shfl_xor(sm, 4, 64);
          sm += __shfl_xor(sm, 8, 64);
          lr[q] = lr[q]*al[q] + sm;
        }
        if (rescale){
          #pragma unroll
          for (int f = 0; f < 8; ++f)
            #pragma unroll
            for (int q = 0; q < 4; ++q) accO[f][q] *= al[q];
        }

        #pragma unroll
        for (int q = 0; q < 4; ++q){
          int row = lhi*4 + q;
          int rb = row*128, sw = (row & 7) << 4;
          #pragma unroll
          for (int hf = 0; hf < 4; ++hf)
            *(u16*)(pw + rb + ((hf*32 + lrow*2) ^ sw)) = cvt_bf16(p[q][hf]);
        }
        __builtin_amdgcn_sched_barrier(0);
        int rsw = (lrow & 7) << 4;
        bf16x8 pa0 = *(const bf16x8*)(pw + lrow*128 + ((     lhi*16) ^ rsw));
        bf16x8 pa1 = *(const bf16x8*)(pw + lrow*128 + ((64 + lhi*16) ^ rsw));

        #pragma unroll
        for (int f = 0; f < 8; ++f){
          int d = f*16 + lrow;
          int swv = d & 7;
          bf16x8 v0 = *(const bf16x8*)(vl + d*128 + (((lhi    ) ^ swv) << 4));
          bf16x8 v1 = *(const bf16x8*)(vl + d*128 + (((lhi + 4) ^ swv) << 4));
          accO[f] = __builtin_amdgcn_mfma_f32_16x16x32_bf16(pa0, v0, accO[f], 0, 0, 0);
          accO[f] = __builtin_amdgcn_mfma_f32_16x16x32_bf16(pa1, v1, accO[f], 0, 0, 0);
        }
      }
      __syncthreads();
    }

    #pragma unroll
    for (int q = 0; q < 4; ++q){
      float inv = 1.0f / lr[q];
      #pragma unroll
      for (int f = 0; f < 8; ++f){
        int row = b*SS + qrow + lhi*4 + q;
        int col = h*DK + f*16 + lrow;
        O[(size_t)row*D_MODEL + col] = cvt_bf16(accO[f][q] * inv);
      }
    }
    __syncthreads();
  }
}

extern "C" void kernel_launch(void* const* d_in, const int* in_sizes, int n_in,
                              void* d_out, int out_size, void* d_ws, size_t ws_size,
                              hipStream_t stream)
{
  (void)in_sizes; (void)n_in; (void)out_size;
  const float* x  = (const float*)d_in[0];
  const float* wq = (const float*)d_in[2];
  const float* bq = (const float*)d_in[3];
  const float* wk = (const float*)d_in[4];
  const float* bk = (const float*)d_in[5];
  const float* wv = (const float*)d_in[6];
  const float* bv = (const float*)d_in[7];
  const float* wo = (const float*)d_in[8];
  const float* bo = (const float*)d_in[9];
  const float* g1 = (const float*)d_in[10];
  const float* g2 = (const float*)d_in[11];
  const float* w1 = (const float*)d_in[12];
  const float* w3 = (const float*)d_in[13];
  const float* w2 = (const float*)d_in[14];
  float* out = (float*)d_out;

  const size_t MB = 1u << 20;
  const size_t W2T_B = (size_t)D_MODEL * DFF * sizeof(u16);
  const size_t NEED = 152*MB + W2T_B + 32768;
  if (ws_size < NEED) return;
  char* ws = (char*)d_ws;
  u16* bufA  = (u16*)(ws + 0);        // 16 MiB: nbf1 -> aob -> nbf2
  u16* qkv   = (u16*)(ws + 16*MB);    // 48 MiB fused QKV [4096][6144]
  u16* h1    = qkv;                   // [4096][5632], aliases after attn
  u16* wqkvt = (u16*)(ws + 64*MB);    // 24 MiB, dead after QKV GEMM
  u16* w1w3t = (u16*)(ws + 64*MB);    // [11264][2048] (64-108)
  u16* wot   = (u16*)(ws + 88*MB);    // 8 MiB (w1w3 transpose AFTER O-proj)
  u16* vtb   = (u16*)(ws + 96*MB);    // 16 MiB (dead after attn)
  u16* h3    = (u16*)(ws + 108*MB);   // [4096][5632] (108-152)
  float* p0o = (float*)(ws + 16*MB);  // O-proj partials: qkv dead after attn
  float* p1o = (float*)(ws + 108*MB); //   h3 region, consumed before h3 written
  u16* w2t   = (u16*)(ws + 152*MB);
  float* bqkv = (float*)(ws + 152*MB + W2T_B);
  // fp32 residual x1 lives in d_out

  bool big = true;
  big &= hipFuncSetAttribute((const void*)k_gemm8p<0>, hipFuncAttributeMaxDynamicSharedMemorySize, 131072) == hipSuccess;
  big &= hipFuncSetAttribute((const void*)k_gemm8p<5>, hipFuncAttributeMaxDynamicSharedMemorySize, 131072) == hipSuccess;
  big &= hipFuncSetAttribute((const void*)k_gemm8p<6>, hipFuncAttributeMaxDynamicSharedMemorySize, 131072) == hipSuccess;
  big &= hipFuncSetAttribute((const void*)k_gemm8p<7>, hipFuncAttributeMaxDynamicSharedMemorySize, 131072) == hipSuccess;

  dim3 tb(32, 8);
  k_transpose_w4<<<dim3(64,64,4), tb, 0, stream>>>(wq, wk, wv, wo,
      wqkvt, wqkvt + 2048*2048, wqkvt + 2*2048*2048, wot);
  k_transpose_w<<<dim3(64, DFF/32), tb, 0, stream>>>(w2, w2t, DFF, D_MODEL);
  k_concat3<<<24, 256, 0, stream>>>(bq, bk, bv, bqkv);

  k_rmsnorm<<<MTOK, 256, 0, stream>>>(x, g1, bufA);
  if (big){
    k_gemm8p<0><<<(MTOK/256)*(DQKV/256), 512, 131072, stream>>>(bufA, wqkvt, bqkv, nullptr, qkv, MTOK, DQKV, D_MODEL, D_MODEL, D_MODEL, DQKV);
    k_transpose_v<<<dim3(SS/32, 128), tb, 0, stream>>>(qkv + 4096, vtb, DQKV);
    k_attn<<<dim3(BB*NHEADS*8), 512, 0, stream>>>(qkv, qkv + 2048, vtb, bufA, DQKV);
    // O-proj split-K x2 -> fp32 partials; fused reduce+residual+rmsnorm2 follows
    k_gemm8p<6><<<2*(MTOK/256)*(D_MODEL/256), 512, 131072, stream>>>(bufA, wot, nullptr, (const u16*)p1o, p0o, MTOK, D_MODEL, D_MODEL/2, D_MODEL, D_MODEL, D_MODEL);
    // w1|w3 -> w1w3t (dead wqkvt + wot + vtb): after O-proj & attn
    k_transpose_w13<<<dim3(DFFP/32, 64, 2), tb, 0, stream>>>(w1, w3, w1w3t);
    k_addres_rms<<<MTOK, 256, 0, stream>>>(x, bo, p0o, p1o, g2, out, bufA);
    // combined W1|W3: N=11264, dual output h1/h3, ldc=DFFP
    k_gemm8p<5><<<(MTOK/256)*((2*DFFP)/256), 512, 131072, stream>>>(bufA, w1w3t, nullptr, h3, h1, MTOK, 2*DFFP, D_MODEL, D_MODEL, D_MODEL, DFFP);
    k_silu_mul<<<(MTOK*DFFP/8 + 255)/256, 256, 0, stream>>>(h1, h3, h1, MTOK*DFFP/8);
    // W2 split-K x2 -> atomicAdd into out (holds x1): final output
    k_gemm8p<7><<<2*(MTOK/256)*(D_MODEL/256), 512, 131072, stream>>>(h1, w2t, nullptr, nullptr, out, MTOK, D_MODEL, DFF/2, DFFP, DFF, D_MODEL);
  } else {
    k_gemm_bt<0><<<(DQKV/128)*(MTOK/128), 256, 0, stream>>>(bufA, wqkvt, bqkv, nullptr, nullptr, qkv, MTOK, DQKV, D_MODEL, D_MODEL, D_MODEL, DQKV);
    k_transpose_v<<<dim3(SS/32, 128), tb, 0, stream>>>(qkv + 4096, vtb, DQKV);
    k_transpose_w13<<<dim3(DFFP/32, 64, 2), tb, 0, stream>>>(w1, w3, w1w3t);
    k_attn<<<dim3(BB*NHEADS*8), 512, 0, stream>>>(qkv, qkv + 2048, vtb, bufA, DQKV);
    k_gemm_bt<1><<<16*32, 256, 0, stream>>>(bufA, wot, bo, x, nullptr, out, MTOK, D_MODEL, D_MODEL, D_MODEL, D_MODEL, D_MODEL);
    k_rmsnorm<<<MTOK, 256, 0, stream>>>(out, g2, bufA);
    k_gemm_bt<2><<<(DFFP/128)*32, 256, 0, stream>>>(bufA, w1w3t, nullptr, nullptr, nullptr, h1, MTOK, DFFP, D_MODEL, D_MODEL, D_MODEL, DFFP);
    k_gemm_bt<2><<<(DFFP/128)*32, 256, 0, stream>>>(bufA, w1w3t + (size_t)DFFP*2048, nullptr, nullptr, nullptr, h3, MTOK, DFFP, D_MODEL, D_MODEL, D_MODEL, DFFP);
    k_silu_mul<<<(MTOK*DFFP/8 + 255)/256, 256, 0, stream>>>(h1, h3, h1, MTOK*DFFP/8);
    k_gemm_bt<3><<<16*32, 256, 0, stream>>>(h1, w2t, nullptr, out, nullptr, out, MTOK, D_MODEL, DFF, DFFP, DFF, D_MODEL);
  }
}

// Round 15
// 666.027 us; speedup vs baseline: 1.0312x; 1.0312x over previous
//
#include <hip/hip_runtime.h>
#include <stdint.h>

typedef unsigned short u16;
typedef __bf16 bf16x8 __attribute__((ext_vector_type(8)));
typedef float f32x4 __attribute__((ext_vector_type(4)));

#define D_MODEL 2048
#define NHEADS 16
#define DK 128
#define DFF 5504
#define DFFP 5632
#define BB 2
#define SS 2048
#define MTOK 4096
#define DQKV 6144

#define AS1 __attribute__((address_space(1)))
#define AS3 __attribute__((address_space(3)))

__device__ __forceinline__ u16 f2bf(float f){
  union { float f; uint32_t u; } v; v.f = f;
  uint32_t r = v.u + 0x7fffu + ((v.u >> 16) & 1u);
  return (u16)(r >> 16);
}
__device__ __forceinline__ float bf2f(u16 u){
  union { uint32_t u; float f; } v; v.u = ((uint32_t)u) << 16;
  return v.f;
}
__device__ __forceinline__ u16 cvt_bf16(float f){
  union { __bf16 h; u16 u; } v; v.h = (__bf16)f; return v.u;
}
__device__ __forceinline__ float fexp2(float x){
#if __has_builtin(__builtin_amdgcn_exp2f)
  return __builtin_amdgcn_exp2f(x);
#else
  return exp2f(x);
#endif
}

// ---- fp32 W[K][Nsrc] -> bf16 Wt[n][K], zero-fill n >= Nsrc ----
__global__ __launch_bounds__(256) void k_transpose_w(const float* __restrict__ W,
                                                     u16* __restrict__ Wt, int K, int Nsrc){
  __shared__ float tile[32][33];
  int n0 = blockIdx.x * 32, k0 = blockIdx.y * 32;
  int tx = threadIdx.x, ty = threadIdx.y;
  #pragma unroll
  for (int r = 0; r < 4; ++r){
    int n = n0 + tx;
    tile[ty + r*8][tx] = (n < Nsrc) ? W[(size_t)(k0 + ty + r*8) * Nsrc + n] : 0.0f;
  }
  __syncthreads();
  #pragma unroll
  for (int r = 0; r < 4; ++r)
    Wt[(size_t)(n0 + ty + r*8) * K + k0 + tx] = f2bf(tile[tx][ty + r*8]);
}

// ---- batched 2048x2048 transpose: z selects among 4 matrices ----
__global__ __launch_bounds__(256) void k_transpose_w4(
    const float* __restrict__ w0s, const float* __restrict__ w1s,
    const float* __restrict__ w2s, const float* __restrict__ w3s,
    u16* __restrict__ d0, u16* __restrict__ d1,
    u16* __restrict__ d2, u16* __restrict__ d3){
  __shared__ float tile[32][33];
  const float* W = blockIdx.z == 0 ? w0s : blockIdx.z == 1 ? w1s : blockIdx.z == 2 ? w2s : w3s;
  u16* Wt = blockIdx.z == 0 ? d0 : blockIdx.z == 1 ? d1 : blockIdx.z == 2 ? d2 : d3;
  int n0 = blockIdx.x * 32, k0 = blockIdx.y * 32;
  int tx = threadIdx.x, ty = threadIdx.y;
  #pragma unroll
  for (int r = 0; r < 4; ++r)
    tile[ty + r*8][tx] = W[(size_t)(k0 + ty + r*8) * D_MODEL + n0 + tx];
  __syncthreads();
  #pragma unroll
  for (int r = 0; r < 4; ++r)
    Wt[(size_t)(n0 + ty + r*8) * D_MODEL + k0 + tx] = f2bf(tile[tx][ty + r*8]);
}

// ---- batched DFFP-row transpose: z=0 -> w1, z=1 -> w3 (zero-pad past DFF) ----
__global__ __launch_bounds__(256) void k_transpose_w13(
    const float* __restrict__ w1s, const float* __restrict__ w3s,
    u16* __restrict__ dst){
  __shared__ float tile[32][33];
  const float* W = blockIdx.z == 0 ? w1s : w3s;
  u16* Wt = dst + (size_t)blockIdx.z * DFFP * D_MODEL;
  int n0 = blockIdx.x * 32, k0 = blockIdx.y * 32;
  int tx = threadIdx.x, ty = threadIdx.y;
  #pragma unroll
  for (int r = 0; r < 4; ++r){
    int n = n0 + tx;
    tile[ty + r*8][tx] = (n < DFF) ? W[(size_t)(k0 + ty + r*8) * DFF + n] : 0.0f;
  }
  __syncthreads();
  #pragma unroll
  for (int r = 0; r < 4; ++r)
    Wt[(size_t)(n0 + ty + r*8) * D_MODEL + k0 + tx] = f2bf(tile[tx][ty + r*8]);
}

// ---- per-head V transpose from fused QKV ----
__global__ __launch_bounds__(256) void k_transpose_v(const u16* __restrict__ V,
                                                     u16* __restrict__ Vt, int ld){
  __shared__ u16 tile[32][33];
  int s0 = blockIdx.x * 32;
  int bh = blockIdx.y >> 2, dt = blockIdx.y & 3;
  int b = bh >> 4, h = bh & 15;
  int tx = threadIdx.x, ty = threadIdx.y;
  #pragma unroll
  for (int r = 0; r < 4; ++r)
    tile[ty + r*8][tx] = V[(size_t)(b*SS + s0 + ty + r*8) * ld + h*DK + dt*32 + tx];
  __syncthreads();
  #pragma unroll
  for (int r = 0; r < 4; ++r)
    Vt[(size_t)(bh*DK + dt*32 + ty + r*8) * SS + s0 + tx] = tile[tx][ty + r*8];
}

__global__ __launch_bounds__(256) void k_concat3(const float* __restrict__ a,
                                                 const float* __restrict__ b,
                                                 const float* __restrict__ c,
                                                 float* __restrict__ o){
  int i = blockIdx.x*256 + threadIdx.x;
  if (i >= DQKV) return;
  o[i] = (i < 2048) ? a[i] : (i < 4096 ? b[i-2048] : c[i-4096]);
}

// ---- RMSNorm: fp32 row -> bf16 row ----
__global__ __launch_bounds__(256) void k_rmsnorm(const float* __restrict__ X,
                                                 const float* __restrict__ g,
                                                 u16* __restrict__ out){
  int row = blockIdx.x, tid = threadIdx.x;
  const float* x = X + (size_t)row * D_MODEL;
  float4 a = ((const float4*)x)[tid*2];
  float4 b = ((const float4*)x)[tid*2+1];
  float ss = a.x*a.x + a.y*a.y + a.z*a.z + a.w*a.w
           + b.x*b.x + b.y*b.y + b.z*b.z + b.w*b.w;
  #pragma unroll
  for (int m = 1; m < 64; m <<= 1) ss += __shfl_xor(ss, m, 64);
  __shared__ float red[4];
  if ((tid & 63) == 0) red[tid >> 6] = ss;
  __syncthreads();
  float tot = red[0] + red[1] + red[2] + red[3];
  float sc = rsqrtf(tot * (1.0f / D_MODEL) + 1e-6f);
  float4 ga = ((const float4*)g)[tid*2];
  float4 gb = ((const float4*)g)[tid*2+1];
  uint32_t w0 = f2bf(a.x*sc*ga.x) | ((uint32_t)f2bf(a.y*sc*ga.y) << 16);
  uint32_t w1 = f2bf(a.z*sc*ga.z) | ((uint32_t)f2bf(a.w*sc*ga.w) << 16);
  uint32_t w2 = f2bf(b.x*sc*gb.x) | ((uint32_t)f2bf(b.y*sc*gb.y) << 16);
  uint32_t w3 = f2bf(b.z*sc*gb.z) | ((uint32_t)f2bf(b.w*sc*gb.w) << 16);
  ((uint4*)(out + (size_t)row * D_MODEL))[tid] = make_uint4(w0, w1, w2, w3);
}

// ---- fused: out = x + bias + p0 + p1 ; nrm = rmsnorm(out)*g (bf16) ----
__global__ __launch_bounds__(256) void k_addres_rms(
    const float* __restrict__ X, const float* __restrict__ bias,
    const float* __restrict__ p0, const float* __restrict__ p1,
    const float* __restrict__ g, float* __restrict__ out,
    u16* __restrict__ nrm){
  int row = blockIdx.x, tid = threadIdx.x;
  size_t base = (size_t)row * D_MODEL;
  float4 a  = ((const float4*)(X  + base))[tid*2];
  float4 b  = ((const float4*)(X  + base))[tid*2+1];
  float4 ba = ((const float4*)bias)[tid*2];
  float4 bb = ((const float4*)bias)[tid*2+1];
  float4 pa = ((const float4*)(p0 + base))[tid*2];
  float4 pb = ((const float4*)(p0 + base))[tid*2+1];
  float4 qa = ((const float4*)(p1 + base))[tid*2];
  float4 qb = ((const float4*)(p1 + base))[tid*2+1];
  a.x += ba.x + pa.x + qa.x; a.y += ba.y + pa.y + qa.y;
  a.z += ba.z + pa.z + qa.z; a.w += ba.w + pa.w + qa.w;
  b.x += bb.x + pb.x + qb.x; b.y += bb.y + pb.y + qb.y;
  b.z += bb.z + pb.z + qb.z; b.w += bb.w + pb.w + qb.w;
  ((float4*)(out + base))[tid*2]   = a;
  ((float4*)(out + base))[tid*2+1] = b;
  float ss = a.x*a.x + a.y*a.y + a.z*a.z + a.w*a.w
           + b.x*b.x + b.y*b.y + b.z*b.z + b.w*b.w;
  #pragma unroll
  for (int m = 1; m < 64; m <<= 1) ss += __shfl_xor(ss, m, 64);
  __shared__ float red[4];
  if ((tid & 63) == 0) red[tid >> 6] = ss;
  __syncthreads();
  float tot = red[0] + red[1] + red[2] + red[3];
  float sc = rsqrtf(tot * (1.0f / D_MODEL) + 1e-6f);
  float4 ga = ((const float4*)g)[tid*2];
  float4 gb = ((const float4*)g)[tid*2+1];
  uint32_t w0 = f2bf(a.x*sc*ga.x) | ((uint32_t)f2bf(a.y*sc*ga.y) << 16);
  uint32_t w1 = f2bf(a.z*sc*ga.z) | ((uint32_t)f2bf(a.w*sc*ga.w) << 16);
  uint32_t w2 = f2bf(b.x*sc*gb.x) | ((uint32_t)f2bf(b.y*sc*gb.y) << 16);
  uint32_t w3 = f2bf(b.z*sc*gb.z) | ((uint32_t)f2bf(b.w*sc*gb.w) << 16);
  ((uint4*)(nrm + base))[tid] = make_uint4(w0, w1, w2, w3);
}

// ---- hg = silu(h1) * h3 (bf16, 8 elems/thread) ----
__global__ __launch_bounds__(256) void k_silu_mul(const u16* __restrict__ a,
                                                  const u16* __restrict__ b,
                                                  u16* __restrict__ o, int n8){
  int i = blockIdx.x * 256 + threadIdx.x;
  if (i >= n8) return;
  uint4 av = ((const uint4*)a)[i];
  uint4 bv = ((const uint4*)b)[i];
  uint32_t aa[4] = {av.x, av.y, av.z, av.w};
  uint32_t bb[4] = {bv.x, bv.y, bv.z, bv.w};
  uint32_t rr[4];
  #pragma unroll
  for (int j = 0; j < 4; ++j){
    float x0 = bf2f((u16)(aa[j] & 0xffff)), x1 = bf2f((u16)(aa[j] >> 16));
    float y0 = bf2f((u16)(bb[j] & 0xffff)), y1 = bf2f((u16)(bb[j] >> 16));
    float r0 = x0 / (1.f + __expf(-x0)) * y0;
    float r1 = x1 / (1.f + __expf(-x1)) * y1;
    rr[j] = f2bf(r0) | ((uint32_t)f2bf(r1) << 16);
  }
  ((uint4*)o)[i] = make_uint4(rr[0], rr[1], rr[2], rr[3]);
}

// ---- out += p0 + p1 (fp32, float4) — split-K reduction into residual ----
__global__ __launch_bounds__(256) void k_add2(float* __restrict__ out,
                                              const float* __restrict__ p0,
                                              const float* __restrict__ p1, int n4){
  int stride = gridDim.x * 256;
  for (int i = blockIdx.x * 256 + threadIdx.x; i < n4; i += stride){
    float4 o = ((const float4*)out)[i];
    float4 a = ((const float4*)p0)[i];
    float4 b = ((const float4*)p1)[i];
    o.x += a.x + b.x; o.y += a.y + b.y; o.z += a.z + b.z; o.w += a.w + b.w;
    ((float4*)out)[i] = o;
  }
}

// ============ 256x256 8-wave GEMM — 8-phase (r12-proven schedule) ============
// row&7 chunk swizzle both-sides (conflict-free, verified r10).
// EPI 0: bf16 +bias; EPI 5: dual bf16 out (n0<5632 -> Cout, else aux-5632)
// EPI 6: split-K x2 -> fp32 partials (slice0 -> Cout, slice1 -> aux)
template<int EPI>
__global__ __launch_bounds__(512, 2) void k_gemm8p(
    const u16* __restrict__ A, const u16* __restrict__ Bt,
    const float* __restrict__ bias, const u16* __restrict__ aux,
    void* __restrict__ Cout, int M, int N, int K,
    int lda, int ldb, int ldc)
{
  extern __shared__ __align__(16) char smem[];
  const int tid = threadIdx.x;
  const int lane = tid & 63, wid = tid >> 6;
  const int wr = wid >> 2, wc = wid & 3;
  const int lrow = lane & 15, lhi = lane >> 4;

  int nwg = gridDim.x, wg = blockIdx.x;
  int ksl = 0;
  if constexpr (EPI == 6){
    int hn = nwg >> 1;
    if (wg >= hn){ ksl = 1; wg -= hn; }
    nwg = hn;
    A  += (size_t)ksl * K;
    Bt += (size_t)ksl * K;
  }

  int nbx = N >> 8, nbm = M >> 8;
  int xcd = wg & 7, sub = wg >> 3;
  int m0, n0;
  if ((nwg & 7) == 0 && (nbm & 1) == 0 && (nbx & 3) == 0){
    int mh = nbm >> 1;
    int mr = sub % mh, nc = sub / mh;
    m0 = (((xcd & 1) * mh) + mr) << 8;
    n0 = (((xcd >> 1) * (nbx >> 2)) + nc) << 8;
  } else {
    int qq = nwg >> 3, rr2 = nwg & 7;
    int swz = (xcd < rr2 ? xcd*(qq+1) : rr2*(qq+1) + (xcd-rr2)*qq) + sub;
    m0 = (swz / nbx) << 8; n0 = (swz % nbx) << 8;
  }

  const int nk = K >> 6;
  const int hA = wr, hB = wc >> 1;
  const int gA = wc;
  const int gB = (wr << 1) | (wc & 1);

  const u16* aSrc[2][2]; int aDst[2][2];
  const u16* bSrc[2][2]; int bDst[2][2];
  #pragma unroll
  for (int q = 0; q < 2; ++q)
    #pragma unroll
    for (int L = 0; L < 2; ++L){
      int p = q*8192 + gA*2048 + L*1024 + lane*16;
      int row = p >> 7;
      int o = (p & 127) ^ ((row & 7) << 4);
      aSrc[q][L] = A + (size_t)(m0 + hA*128 + row)*lda + (o >> 1);
      aDst[q][L] = hA*16384 + p;
      int pb = q*4096 + (gB >> 1)*8192 + (gB & 1)*2048 + L*1024 + lane*16;
      int rowb = pb >> 7;
      int ob = (pb & 127) ^ ((rowb & 7) << 4);
      bSrc[q][L] = Bt + (size_t)(n0 + hB*128 + rowb)*ldb + (ob >> 1);
      bDst[q][L] = 32768 + hB*16384 + pb;
    }
  const int xo0 = (lhi*16) ^ ((lrow & 7) << 4);
  const int xo1 = (64 + lhi*16) ^ ((lrow & 7) << 4);

  auto stA = [&](int d, int kk, int q){
    #pragma unroll
    for (int L = 0; L < 2; ++L)
      __builtin_amdgcn_global_load_lds(
        (const AS1 void*)(aSrc[q][L] + kk),
        (AS3 void*)(smem + d*65536 + aDst[q][L]), 16, 0, 0);
  };
  auto stB = [&](int d, int kk, int s){
    #pragma unroll
    for (int L = 0; L < 2; ++L)
      __builtin_amdgcn_global_load_lds(
        (const AS1 void*)(bSrc[s][L] + kk),
        (AS3 void*)(smem + d*65536 + bDst[s][L]), 16, 0, 0);
  };
  auto rdA = [&](int d, int rloc, int ks)->bf16x8{
    return *(const bf16x8*)(smem + d*65536 + hA*16384 + rloc*128 + (ks ? xo1 : xo0));
  };
  auto rdB = [&](int d, int rloc, int ks)->bf16x8{
    return *(const bf16x8*)(smem + d*65536 + 32768 + hB*16384 + rloc*128 + (ks ? xo1 : xo0));
  };

  f32x4 acc[8][4] = {};

  stA(0, 0, 0); stB(0, 0, 0); stB(0, 0, 1); stA(0, 0, 1);
  asm volatile("s_waitcnt vmcnt(0)" ::: "memory");
  __builtin_amdgcn_s_barrier();

  for (int t = 0; t < nk; ++t){
    int d = t & 1, dn = d ^ 1, kkn = (t + 1) << 6;
    bool pf = (t + 1 < nk);
    bf16x8 aR[8], bQ0[4], bQ1[4];

    // ---- phase 0: Q00 (reads Aq0+Bs0-own; stage t+1 Aq0+Bs0) ----
    #pragma unroll
    for (int ii = 0; ii < 4; ++ii){
      aR[ii*2]   = rdA(d, ii*16 + lrow, 0);
      aR[ii*2+1] = rdA(d, ii*16 + lrow, 1);
    }
    #pragma unroll
    for (int j = 0; j < 2; ++j){
      bQ0[j*2]   = rdB(d, (wc&1)*64 + j*16 + lrow, 0);
      bQ0[j*2+1] = rdB(d, (wc&1)*64 + j*16 + lrow, 1);
    }
    if (pf){ stA(dn, kkn, 0); stB(dn, kkn, 0); }
    __builtin_amdgcn_s_barrier();
    asm volatile("s_waitcnt lgkmcnt(0)" ::: "memory");
    __builtin_amdgcn_sched_barrier(0);
    __builtin_amdgcn_s_setprio(1);
    #pragma unroll
    for (int ii = 0; ii < 4; ++ii)
      #pragma unroll
      for (int j = 0; j < 2; ++j){
        acc[ii][j] = __builtin_amdgcn_mfma_f32_16x16x32_bf16(aR[ii*2],   bQ0[j*2],   acc[ii][j], 0, 0, 0);
        acc[ii][j] = __builtin_amdgcn_mfma_f32_16x16x32_bf16(aR[ii*2+1], bQ0[j*2+1], acc[ii][j], 0, 0, 0);
      }
    __builtin_amdgcn_s_setprio(0);
    if (pf) asm volatile("s_waitcnt vmcnt(6)" ::: "memory");
    else    asm volatile("s_waitcnt vmcnt(2)" ::: "memory");
    __builtin_amdgcn_sched_barrier(0);
    __builtin_amdgcn_s_barrier();

    // ---- phase 1: Q01 (reads Bs1-own; stage t+1 Bs1; reuse aR) ----
    #pragma unroll
    for (int j = 0; j < 2; ++j){
      bQ1[j*2]   = rdB(d, (wc&1)*64 + 32 + j*16 + lrow, 0);
      bQ1[j*2+1] = rdB(d, (wc&1)*64 + 32 + j*16 + lrow, 1);
    }
    if (pf) stB(dn, kkn, 1);
    __builtin_amdgcn_s_barrier();
    asm volatile("s_waitcnt lgkmcnt(0)" ::: "memory");
    __builtin_amdgcn_sched_barrier(0);
    __builtin_amdgcn_s_setprio(1);
    #pragma unroll
    for (int ii = 0; ii < 4; ++ii)
      #pragma unroll
      for (int j = 0; j < 2; ++j){
        acc[ii][2+j] = __builtin_amdgcn_mfma_f32_16x16x32_bf16(aR[ii*2],   bQ1[j*2],   acc[ii][2+j], 0, 0, 0);
        acc[ii][2+j] = __builtin_amdgcn_mfma_f32_16x16x32_bf16(aR[ii*2+1], bQ1[j*2+1], acc[ii][2+j], 0, 0, 0);
      }
    __builtin_amdgcn_s_setprio(0);
    if (pf) asm volatile("s_waitcnt vmcnt(6)" ::: "memory");
    else    asm volatile("s_waitcnt vmcnt(0)" ::: "memory");
    __builtin_amdgcn_sched_barrier(0);
    __builtin_amdgcn_s_barrier();

    // ---- phase 2: Q11 (reads Aq1; stage t+1 Aq1; reuse bQ1) ----
    #pragma unroll
    for (int ii = 0; ii < 4; ++ii){
      aR[ii*2]   = rdA(d, 64 + ii*16 + lrow, 0);
      aR[ii*2+1] = rdA(d, 64 + ii*16 + lrow, 1);
    }
    if (pf) stA(dn, kkn, 1);
    __builtin_amdgcn_s_barrier();
    asm volatile("s_waitcnt lgkmcnt(0)" ::: "memory");
    __builtin_amdgcn_sched_barrier(0);
    __builtin_amdgcn_s_setprio(1);
    #pragma unroll
    for (int ii = 0; ii < 4; ++ii)
      #pragma unroll
      for (int j = 0; j < 2; ++j){
        acc[4+ii][2+j] = __builtin_amdgcn_mfma_f32_16x16x32_bf16(aR[ii*2],   bQ1[j*2],   acc[4+ii][2+j], 0, 0, 0);
        acc[4+ii][2+j] = __builtin_amdgcn_mfma_f32_16x16x32_bf16(aR[ii*2+1], bQ1[j*2+1], acc[4+ii][2+j], 0, 0, 0);
      }
    __builtin_amdgcn_s_setprio(0);
    __builtin_amdgcn_s_barrier();

    // ---- phase 3: Q10 (no reads; reuse aR + bQ0) ----
    __builtin_amdgcn_s_setprio(1);
    #pragma unroll
    for (int ii = 0; ii < 4; ++ii)
      #pragma unroll
      for (int j = 0; j < 2; ++j){
        acc[4+ii][j] = __builtin_amdgcn_mfma_f32_16x16x32_bf16(aR[ii*2],   bQ0[j*2],   acc[4+ii][j], 0, 0, 0);
        acc[4+ii][j] = __builtin_amdgcn_mfma_f32_16x16x32_bf16(aR[ii*2+1], bQ0[j*2+1], acc[4+ii][j], 0, 0, 0);
      }
    __builtin_amdgcn_s_setprio(0);
    if (pf) asm volatile("s_waitcnt vmcnt(4)" ::: "memory");
    __builtin_amdgcn_sched_barrier(0);
    __builtin_amdgcn_s_barrier();
  }

  // epilogue
  if constexpr (EPI == 6){
    float* P = ksl ? (float*)aux : (float*)Cout;
    #pragma unroll
    for (int i = 0; i < 8; ++i)
      #pragma unroll
      for (int j = 0; j < 4; ++j){
        int col = n0 + wc*64 + j*16 + lrow;
        #pragma unroll
        for (int q = 0; q < 4; ++q){
          int row = m0 + wr*128 + i*16 + lhi*4 + q;
          P[(size_t)row*ldc + col] = acc[i][j][q];
        }
      }
    return;
  }
  u16* Cw = (u16*)Cout;
  int cofs = 0;
  if constexpr (EPI == 5){
    if (n0 >= 5632){ Cw = (u16*)aux; cofs = 5632; }
  }
  #pragma unroll
  for (int i = 0; i < 8; ++i){
    #pragma unroll
    for (int j = 0; j < 4; ++j){
      int col = n0 + wc*64 + j*16 + lrow;
      float bv = 0.f;
      if constexpr (EPI == 0) bv = bias[col];
      #pragma unroll
      for (int q = 0; q < 4; ++q){
        int row = m0 + wr*128 + i*16 + lhi*4 + q;
        float v = acc[i][j][q] + bv;
        Cw[(size_t)row*ldc + (col - cofs)] = f2bf(v);
      }
    }
  }
}

// ---- 128x128 GEMM (3-buffer counted vmcnt, row&3 chunk swizzle) — fallback ----
template<int EPI>
__global__ __launch_bounds__(256) void k_gemm_bt(
    const u16* __restrict__ A, const u16* __restrict__ Bt,
    const float* __restrict__ bias, const float* __restrict__ res,
    const u16* __restrict__ aux,
    void* __restrict__ Cout, int M, int N, int K,
    int lda, int ldb, int ldc)
{
  __shared__ __align__(16) u16 As[3][128*32];
  __shared__ __align__(16) u16 Bs[3][128*32];
  int tid = threadIdx.x;

  int nwg = gridDim.x, wg = blockIdx.x;
  int qq = nwg >> 3, rr = nwg & 7;
  int xcd = wg & 7, sub = wg >> 3;
  int swz = (xcd < rr ? xcd*(qq+1) : rr*(qq+1) + (xcd-rr)*qq) + sub;
  int nbx = N >> 7;
  int m0 = (swz / nbx) << 7, n0 = (swz % nbx) << 7;

  int lane = tid & 63, wave = tid >> 6;
  int wr = wave >> 1, wc = wave & 1;
  int lrow = lane & 15, lhi = lane >> 4;
  f32x4 acc[4][4] = {};
  int srow = tid >> 2;
  int schk = tid & 3;
  const int nk = K >> 5;

  auto stage = [&](int slot, int kt){
    int k0 = kt << 5;
    int c = schk ^ (srow & 3);
    #pragma unroll
    for (int cc = 0; cc < 2; ++cc){
      int r = cc*64 + srow;
      __builtin_amdgcn_global_load_lds(
        (const AS1 void*)(A + (size_t)(m0 + r)*lda + k0 + c*8),
        (AS3 void*)(&As[slot][r*32 + schk*8]), 16, 0, 0);
      __builtin_amdgcn_global_load_lds(
        (const AS1 void*)(Bt + (size_t)(n0 + r)*ldb + k0 + c*8),
        (AS3 void*)(&Bs[slot][r*32 + schk*8]), 16, 0, 0);
    }
  };

  stage(0, 0);
  if (nk > 1) stage(1, 1);
  if (nk > 1) asm volatile("s_waitcnt vmcnt(4)" ::: "memory");
  else        asm volatile("s_waitcnt vmcnt(0)" ::: "memory");
  __builtin_amdgcn_s_barrier();

  for (int kt = 0; kt < nk; ++kt){
    int cur = kt % 3;
    if (kt + 2 < nk) stage((kt + 2) % 3, kt + 2);
    int rchk = lhi ^ (lrow & 3);
    bf16x8 af[4], bfv[4];
    #pragma unroll
    for (int i = 0; i < 4; ++i){
      af[i]  = *(const bf16x8*)(&As[cur][(wr*64 + i*16 + lrow)*32 + rchk*8]);
      bfv[i] = *(const bf16x8*)(&Bs[cur][(wc*64 + i*16 + lrow)*32 + rchk*8]);
    }
    #pragma unroll
    for (int i = 0; i < 4; ++i)
      #pragma unroll
      for (int j = 0; j < 4; ++j)
        acc[i][j] = __builtin_amdgcn_mfma_f32_16x16x32_bf16(af[i], bfv[j], acc[i][j], 0, 0, 0);
    if (kt + 2 < nk) asm volatile("s_waitcnt vmcnt(4)" ::: "memory");
    else             asm volatile("s_waitcnt vmcnt(0)" ::: "memory");
    __builtin_amdgcn_s_barrier();
  }

  #pragma unroll
  for (int i = 0; i < 4; ++i){
    #pragma unroll
    for (int j = 0; j < 4; ++j){
      int col = n0 + wc*64 + j*16 + lrow;
      float bv = 0.f;
      if constexpr (EPI == 0 || EPI == 1) bv = bias[col];
      #pragma unroll
      for (int q = 0; q < 4; ++q){
        int row = m0 + wr*64 + i*16 + lhi*4 + q;
        size_t idx = (size_t)row*ldc + col;
        float v = acc[i][j][q] + bv;
        if constexpr (EPI == 1 || EPI == 3) v += res[idx];
        if constexpr (EPI == 4){
          float a0 = bf2f(aux[idx]);
          v = a0 / (1.f + __expf(-a0)) * v;
        }
        if constexpr (EPI == 0 || EPI == 2 || EPI == 4) ((u16*)Cout)[idx] = f2bf(v);
        else ((float*)Cout)[idx] = v;
      }
    }
  }
}

// ---- causal flash attention: paired-qblock load balancing (unchanged) ----
__global__ __launch_bounds__(512) void k_attn(
    const u16* __restrict__ Q, const u16* __restrict__ Kb,
    const u16* __restrict__ Vt, u16* __restrict__ O, int ldq)
{
  int tid = threadIdx.x, lane = tid & 63, wave = tid >> 6;
  int lrow = lane & 15, lhi = lane >> 4;
  int bidx = blockIdx.x;
  int bh = bidx >> 3, j = bidx & 7;
  int b = bh >> 4, h = bh & 15;

  __shared__ __align__(16) u16 Kbuf[2][64*128];
  __shared__ __align__(16) u16 Vbuf[2][128*64];
  __shared__ __align__(16) u16 P_lds[8][16*64];
  char* pw = (char*)&P_lds[wave][0];
  const float sc2 = 0.08838834764831845f * 1.44269504088896340736f;

  auto stage = [&](int bufi, int kt){
    int kv0 = kt << 6;
    char* kd = (char*)&Kbuf[bufi][0];
    char* vd = (char*)&Vbuf[bufi][0];
    #pragma unroll
    for (int L = 0; L < 2; ++L){
      int cid = wave*128 + L*64 + lane;
      int r = cid >> 4, c = cid & 15;
      int cg = c ^ (r & 7);
      __builtin_amdgcn_global_load_lds(
        (const AS1 void*)(Kb + (size_t)(b*SS + kv0 + r)*ldq + h*DK + cg*8),
        (AS3 void*)(kd + wave*2048 + L*1024 + lane*16), 16, 0, 0);
      int dd = cid >> 3, c8 = cid & 7;
      int cv = c8 ^ (dd & 7);
      __builtin_amdgcn_global_load_lds(
        (const AS1 void*)(Vt + (size_t)bh*DK*SS + (size_t)dd*SS + kv0 + cv*8),
        (AS3 void*)(vd + wave*2048 + L*1024 + lane*16), 16, 0, 0);
    }
  };

  #pragma unroll 1
  for (int item = 0; item < 2; ++item){
    int qi = item == 0 ? 15 - j : j;
    int qs = qi * 128;
    int nt = 2*qi + 2;
    int qrow = qs + wave * 16;

    bf16x8 qf[4];
    const u16* qbase = Q + (size_t)(b*SS + qrow + lrow)*ldq + h*DK + lhi*8;
    #pragma unroll
    for (int dc = 0; dc < 4; ++dc) qf[dc] = *(const bf16x8*)(qbase + dc*32);

    f32x4 accO[8] = {};
    float mr[4] = {-1e30f,-1e30f,-1e30f,-1e30f};
    float lr[4] = {0.f,0.f,0.f,0.f};

    stage(0, 0);
    __syncthreads();

    for (int kt = 0; kt < nt; ++kt){
      int cur = kt & 1;
      if (kt + 1 < nt) stage(cur ^ 1, kt + 1);
      int kv0 = kt << 6;
      if (kv0 <= qrow + 15){
        const char* kl = (const char*)&Kbuf[cur][0];
        const char* vl = (const char*)&Vbuf[cur][0];
        bool domask = (kv0 + 63 > qrow);

        f32x4 sf[4];
        #pragma unroll
        for (int hf = 0; hf < 4; ++hf){
          int rl = hf*16 + lrow;
          int sw = rl & 7;
          f32x4 a = {};
          #pragma unroll
          for (int dc = 0; dc < 4; ++dc){
            bf16x8 kf = *(const bf16x8*)(kl + rl*256 + (((lhi + dc*4) ^ sw) << 4));
            a = __builtin_amdgcn_mfma_f32_16x16x32_bf16(qf[dc], kf, a, 0, 0, 0);
          }
          sf[hf] = a;
        }

        float p[4][4], mx[4];
        #pragma unroll
        for (int q = 0; q < 4; ++q){
          float s0 = sf[0][q]*sc2, s1 = sf[1][q]*sc2, s2 = sf[2][q]*sc2, s3 = sf[3][q]*sc2;
          if (domask){
            int qg = qrow + lhi*4 + q;
            if (kv0      + lrow > qg) s0 = -1e30f;
            if (kv0 + 16 + lrow > qg) s1 = -1e30f;
            if (kv0 + 32 + lrow > qg) s2 = -1e30f;
            if (kv0 + 48 + lrow > qg) s3 = -1e30f;
          }
          p[q][0]=s0; p[q][1]=s1; p[q][2]=s2; p[q][3]=s3;
          float m = fmaxf(fmaxf(s0,s1), fmaxf(s2,s3));
          m = fmaxf(m, __shfl_xor(m, 1, 64));
          m = fmaxf(m, __shfl_xor(m, 2, 64));
          m = fmaxf(m, __shfl_xor(m, 4, 64));
          m = fmaxf(m, __shfl_xor(m, 8, 64));
          mx[q] = m;
        }
        float dmax = fmaxf(fmaxf(mx[0]-mr[0], mx[1]-mr[1]), fmaxf(mx[2]-mr[2], mx[3]-mr[3]));
        bool rescale = !__all(dmax <= 8.0f);
        float al[4];
        #pragma unroll
        for (int q = 0; q < 4; ++q){
          if (rescale){
            float mn = fmaxf(mr[q], mx[q]);
            al[q] = fexp2(mr[q] - mn);
            mr[q] = mn;
          } else al[q] = 1.0f;
          p[q][0] = fexp2(p[q][0] - mr[q]);
          p[q][1] = fexp2(p[q][1] - mr[q]);
          p[q][2] = fexp2(p[q][2] - mr[q]);
          p[q][3] = fexp2(p[q][3] - mr[q]);
          float sm = (p[q][0] + p[q][1]) + (p[q][2] + p[q][3]);
          sm += __shfl_xor(sm, 1, 64);
          sm += __shfl_xor(sm, 2, 64);
          sm += __shfl_xor(sm, 4, 64);
          sm += __shfl_xor(sm, 8, 64);
          lr[q] = lr[q]*al[q] + sm;
        }
        if (rescale){
          #pragma unroll
          for (int f = 0; f < 8; ++f)
            #pragma unroll
            for (int q = 0; q < 4; ++q) accO[f][q] *= al[q];
        }

        #pragma unroll
        for (int q = 0; q < 4; ++q){
          int row = lhi*4 + q;
          int rb = row*128, sw = (row & 7) << 4;
          #pragma unroll
          for (int hf = 0; hf < 4; ++hf)
            *(u16*)(pw + rb + ((hf*32 + lrow*2) ^ sw)) = cvt_bf16(p[q][hf]);
        }
        __builtin_amdgcn_sched_barrier(0);
        int rsw = (lrow & 7) << 4;
        bf16x8 pa0 = *(const bf16x8*)(pw + lrow*128 + ((     lhi*16) ^ rsw));
        bf16x8 pa1 = *(const bf16x8*)(pw + lrow*128 + ((64 + lhi*16) ^ rsw));

        #pragma unroll
        for (int f = 0; f < 8; ++f){
          int d = f*16 + lrow;
          int swv = d & 7;
          bf16x8 v0 = *(const bf16x8*)(vl + d*128 + (((lhi    ) ^ swv) << 4));
          bf16x8 v1 = *(const bf16x8*)(vl + d*128 + (((lhi + 4) ^ swv) << 4));
          accO[f] = __builtin_amdgcn_mfma_f32_16x16x32_bf16(pa0, v0, accO[f], 0, 0, 0);
          accO[f] = __builtin_amdgcn_mfma_f32_16x16x32_bf16(pa1, v1, accO[f], 0, 0, 0);
        }
      }
      __syncthreads();
    }

    #pragma unroll
    for (int q = 0; q < 4; ++q){
      float inv = 1.0f / lr[q];
      #pragma unroll
      for (int f = 0; f < 8; ++f){
        int row = b*SS + qrow + lhi*4 + q;
        int col = h*DK + f*16 + lrow;
        O[(size_t)row*D_MODEL + col] = cvt_bf16(accO[f][q] * inv);
      }
    }
    __syncthreads();
  }
}

extern "C" void kernel_launch(void* const* d_in, const int* in_sizes, int n_in,
                              void* d_out, int out_size, void* d_ws, size_t ws_size,
                              hipStream_t stream)
{
  (void)in_sizes; (void)n_in; (void)out_size;
  const float* x  = (const float*)d_in[0];
  const float* wq = (const float*)d_in[2];
  const float* bq = (const float*)d_in[3];
  const float* wk = (const float*)d_in[4];
  const float* bk = (const float*)d_in[5];
  const float* wv = (const float*)d_in[6];
  const float* bv = (const float*)d_in[7];
  const float* wo = (const float*)d_in[8];
  const float* bo = (const float*)d_in[9];
  const float* g1 = (const float*)d_in[10];
  const float* g2 = (const float*)d_in[11];
  const float* w1 = (const float*)d_in[12];
  const float* w3 = (const float*)d_in[13];
  const float* w2 = (const float*)d_in[14];
  float* out = (float*)d_out;

  const size_t MB = 1u << 20;
  const size_t W2T_B = (size_t)D_MODEL * DFF * sizeof(u16);
  const size_t NEED = 152*MB + W2T_B + 32768;
  if (ws_size < NEED) return;
  char* ws = (char*)d_ws;
  u16* bufA  = (u16*)(ws + 0);        // 16 MiB: nbf1 -> aob -> nbf2
  u16* qkv   = (u16*)(ws + 16*MB);    // 48 MiB fused QKV [4096][6144]
  u16* h1    = qkv;                   // [4096][5632], aliases after attn
  u16* wqkvt = (u16*)(ws + 64*MB);    // 24 MiB, dead after QKV GEMM
  u16* w1w3t = (u16*)(ws + 64*MB);    // [11264][2048] (64-108)
  u16* wot   = (u16*)(ws + 88*MB);    // 8 MiB (w1w3 transpose AFTER O-proj)
  u16* vtb   = (u16*)(ws + 96*MB);    // 16 MiB (dead after attn)
  u16* h3    = (u16*)(ws + 108*MB);   // [4096][5632] (108-152)
  float* p0o = (float*)(ws + 16*MB);  // O-proj partials: qkv dead after attn
  float* p1o = (float*)(ws + 108*MB); //   h3 region, consumed before h3 written
  float* p0  = (float*)(ws + 64*MB);  // W2 partials (dead w1w3t / vtb+h3 regions)
  float* p1  = (float*)(ws + 96*MB);
  u16* w2t   = (u16*)(ws + 152*MB);
  float* bqkv = (float*)(ws + 152*MB + W2T_B);
  // fp32 residual x1 lives in d_out

  bool big = true;
  big &= hipFuncSetAttribute((const void*)k_gemm8p<0>, hipFuncAttributeMaxDynamicSharedMemorySize, 131072) == hipSuccess;
  big &= hipFuncSetAttribute((const void*)k_gemm8p<5>, hipFuncAttributeMaxDynamicSharedMemorySize, 131072) == hipSuccess;
  big &= hipFuncSetAttribute((const void*)k_gemm8p<6>, hipFuncAttributeMaxDynamicSharedMemorySize, 131072) == hipSuccess;

  dim3 tb(32, 8);
  k_transpose_w4<<<dim3(64,64,4), tb, 0, stream>>>(wq, wk, wv, wo,
      wqkvt, wqkvt + 2048*2048, wqkvt + 2*2048*2048, wot);
  k_transpose_w<<<dim3(64, DFF/32), tb, 0, stream>>>(w2, w2t, DFF, D_MODEL);
  k_concat3<<<24, 256, 0, stream>>>(bq, bk, bv, bqkv);

  k_rmsnorm<<<MTOK, 256, 0, stream>>>(x, g1, bufA);
  if (big){
    k_gemm8p<0><<<(MTOK/256)*(DQKV/256), 512, 131072, stream>>>(bufA, wqkvt, bqkv, nullptr, qkv, MTOK, DQKV, D_MODEL, D_MODEL, D_MODEL, DQKV);
    k_transpose_v<<<dim3(SS/32, 128), tb, 0, stream>>>(qkv + 4096, vtb, DQKV);
    k_attn<<<dim3(BB*NHEADS*8), 512, 0, stream>>>(qkv, qkv + 2048, vtb, bufA, DQKV);
    // O-proj split-K x2 -> fp32 partials; fused reduce+residual+rmsnorm2 follows
    k_gemm8p<6><<<2*(MTOK/256)*(D_MODEL/256), 512, 131072, stream>>>(bufA, wot, nullptr, (const u16*)p1o, p0o, MTOK, D_MODEL, D_MODEL/2, D_MODEL, D_MODEL, D_MODEL);
    // w1|w3 -> w1w3t (dead wqkvt + wot + vtb): after O-proj & attn
    k_transpose_w13<<<dim3(DFFP/32, 64, 2), tb, 0, stream>>>(w1, w3, w1w3t);
    k_addres_rms<<<MTOK, 256, 0, stream>>>(x, bo, p0o, p1o, g2, out, bufA);
    // combined W1|W3: N=11264, dual output h1/h3, ldc=DFFP
    k_gemm8p<5><<<(MTOK/256)*((2*DFFP)/256), 512, 131072, stream>>>(bufA, w1w3t, nullptr, h3, h1, MTOK, 2*DFFP, D_MODEL, D_MODEL, D_MODEL, DFFP);
    k_silu_mul<<<(MTOK*DFFP/8 + 255)/256, 256, 0, stream>>>(h1, h3, h1, MTOK*DFFP/8);
    // W2 split-K x2 -> fp32 partials, then reduce into residual
    k_gemm8p<6><<<2*(MTOK/256)*(D_MODEL/256), 512, 131072, stream>>>(h1, w2t, nullptr, (const u16*)p1, p0, MTOK, D_MODEL, DFF/2, DFFP, DFF, D_MODEL);
    k_add2<<<2048, 256, 0, stream>>>(out, p0, p1, MTOK*D_MODEL/4);
  } else {
    k_gemm_bt<0><<<(DQKV/128)*(MTOK/128), 256, 0, stream>>>(bufA, wqkvt, bqkv, nullptr, nullptr, qkv, MTOK, DQKV, D_MODEL, D_MODEL, D_MODEL, DQKV);
    k_transpose_v<<<dim3(SS/32, 128), tb, 0, stream>>>(qkv + 4096, vtb, DQKV);
    k_transpose_w13<<<dim3(DFFP/32, 64, 2), tb, 0, stream>>>(w1, w3, w1w3t);
    k_attn<<<dim3(BB*NHEADS*8), 512, 0, stream>>>(qkv, qkv + 2048, vtb, bufA, DQKV);
    k_gemm_bt<1><<<16*32, 256, 0, stream>>>(bufA, wot, bo, x, nullptr, out, MTOK, D_MODEL, D_MODEL, D_MODEL, D_MODEL, D_MODEL);
    k_rmsnorm<<<MTOK, 256, 0, stream>>>(out, g2, bufA);
    k_gemm_bt<2><<<(DFFP/128)*32, 256, 0, stream>>>(bufA, w1w3t, nullptr, nullptr, nullptr, h1, MTOK, DFFP, D_MODEL, D_MODEL, D_MODEL, DFFP);
    k_gemm_bt<2><<<(DFFP/128)*32, 256, 0, stream>>>(bufA, w1w3t + (size_t)DFFP*2048, nullptr, nullptr, nullptr, h3, MTOK, DFFP, D_MODEL, D_MODEL, D_MODEL, DFFP);
    k_silu_mul<<<(MTOK*DFFP/8 + 255)/256, 256, 0, stream>>>(h1, h3, h1, MTOK*DFFP/8);
    k_gemm_bt<3><<<16*32, 256, 0, stream>>>(h1, w2t, nullptr, out, nullptr, out, MTOK, D_MODEL, DFF, DFFP, DFF, D_MODEL);
  }
}

// Round 16
// 655.776 us; speedup vs baseline: 1.0473x; 1.0156x over previous
//
#include <hip/hip_runtime.h>
#include <stdint.h>

typedef unsigned short u16;
typedef __bf16 bf16x8 __attribute__((ext_vector_type(8)));
typedef float f32x4 __attribute__((ext_vector_type(4)));

#define D_MODEL 2048
#define NHEADS 16
#define DK 128
#define DFF 5504
#define DFFP 5632
#define BB 2
#define SS 2048
#define MTOK 4096
#define DQKV 6144

#define AS1 __attribute__((address_space(1)))
#define AS3 __attribute__((address_space(3)))

__device__ __forceinline__ u16 f2bf(float f){
  union { float f; uint32_t u; } v; v.f = f;
  uint32_t r = v.u + 0x7fffu + ((v.u >> 16) & 1u);
  return (u16)(r >> 16);
}
__device__ __forceinline__ float bf2f(u16 u){
  union { uint32_t u; float f; } v; v.u = ((uint32_t)u) << 16;
  return v.f;
}
__device__ __forceinline__ u16 cvt_bf16(float f){
  union { __bf16 h; u16 u; } v; v.h = (__bf16)f; return v.u;
}
__device__ __forceinline__ float fexp2(float x){
#if __has_builtin(__builtin_amdgcn_exp2f)
  return __builtin_amdgcn_exp2f(x);
#else
  return exp2f(x);
#endif
}

// ---- fp32 W[K][Nsrc] -> bf16 Wt[n][K], zero-fill n >= Nsrc ----
__global__ __launch_bounds__(256) void k_transpose_w(const float* __restrict__ W,
                                                     u16* __restrict__ Wt, int K, int Nsrc){
  __shared__ float tile[32][33];
  int n0 = blockIdx.x * 32, k0 = blockIdx.y * 32;
  int tx = threadIdx.x, ty = threadIdx.y;
  #pragma unroll
  for (int r = 0; r < 4; ++r){
    int n = n0 + tx;
    tile[ty + r*8][tx] = (n < Nsrc) ? W[(size_t)(k0 + ty + r*8) * Nsrc + n] : 0.0f;
  }
  __syncthreads();
  #pragma unroll
  for (int r = 0; r < 4; ++r)
    Wt[(size_t)(n0 + ty + r*8) * K + k0 + tx] = f2bf(tile[tx][ty + r*8]);
}

// ---- batched 2048x2048 transpose: z selects among 4 matrices ----
__global__ __launch_bounds__(256) void k_transpose_w4(
    const float* __restrict__ w0s, const float* __restrict__ w1s,
    const float* __restrict__ w2s, const float* __restrict__ w3s,
    u16* __restrict__ d0, u16* __restrict__ d1,
    u16* __restrict__ d2, u16* __restrict__ d3){
  __shared__ float tile[32][33];
  const float* W = blockIdx.z == 0 ? w0s : blockIdx.z == 1 ? w1s : blockIdx.z == 2 ? w2s : w3s;
  u16* Wt = blockIdx.z == 0 ? d0 : blockIdx.z == 1 ? d1 : blockIdx.z == 2 ? d2 : d3;
  int n0 = blockIdx.x * 32, k0 = blockIdx.y * 32;
  int tx = threadIdx.x, ty = threadIdx.y;
  #pragma unroll
  for (int r = 0; r < 4; ++r)
    tile[ty + r*8][tx] = W[(size_t)(k0 + ty + r*8) * D_MODEL + n0 + tx];
  __syncthreads();
  #pragma unroll
  for (int r = 0; r < 4; ++r)
    Wt[(size_t)(n0 + ty + r*8) * D_MODEL + k0 + tx] = f2bf(tile[tx][ty + r*8]);
}

// ---- batched DFFP-row transpose: z=0 -> w1, z=1 -> w3 (zero-pad past DFF) ----
__global__ __launch_bounds__(256) void k_transpose_w13(
    const float* __restrict__ w1s, const float* __restrict__ w3s,
    u16* __restrict__ dst){
  __shared__ float tile[32][33];
  const float* W = blockIdx.z == 0 ? w1s : w3s;
  u16* Wt = dst + (size_t)blockIdx.z * DFFP * D_MODEL;
  int n0 = blockIdx.x * 32, k0 = blockIdx.y * 32;
  int tx = threadIdx.x, ty = threadIdx.y;
  #pragma unroll
  for (int r = 0; r < 4; ++r){
    int n = n0 + tx;
    tile[ty + r*8][tx] = (n < DFF) ? W[(size_t)(k0 + ty + r*8) * DFF + n] : 0.0f;
  }
  __syncthreads();
  #pragma unroll
  for (int r = 0; r < 4; ++r)
    Wt[(size_t)(n0 + ty + r*8) * D_MODEL + k0 + tx] = f2bf(tile[tx][ty + r*8]);
}

// ---- per-head V transpose from fused QKV ----
__global__ __launch_bounds__(256) void k_transpose_v(const u16* __restrict__ V,
                                                     u16* __restrict__ Vt, int ld){
  __shared__ u16 tile[32][33];
  int s0 = blockIdx.x * 32;
  int bh = blockIdx.y >> 2, dt = blockIdx.y & 3;
  int b = bh >> 4, h = bh & 15;
  int tx = threadIdx.x, ty = threadIdx.y;
  #pragma unroll
  for (int r = 0; r < 4; ++r)
    tile[ty + r*8][tx] = V[(size_t)(b*SS + s0 + ty + r*8) * ld + h*DK + dt*32 + tx];
  __syncthreads();
  #pragma unroll
  for (int r = 0; r < 4; ++r)
    Vt[(size_t)(bh*DK + dt*32 + ty + r*8) * SS + s0 + tx] = tile[tx][ty + r*8];
}

__global__ __launch_bounds__(256) void k_concat3(const float* __restrict__ a,
                                                 const float* __restrict__ b,
                                                 const float* __restrict__ c,
                                                 float* __restrict__ o){
  int i = blockIdx.x*256 + threadIdx.x;
  if (i >= DQKV) return;
  o[i] = (i < 2048) ? a[i] : (i < 4096 ? b[i-2048] : c[i-4096]);
}

// ---- RMSNorm: fp32 row -> bf16 row ----
__global__ __launch_bounds__(256) void k_rmsnorm(const float* __restrict__ X,
                                                 const float* __restrict__ g,
                                                 u16* __restrict__ out){
  int row = blockIdx.x, tid = threadIdx.x;
  const float* x = X + (size_t)row * D_MODEL;
  float4 a = ((const float4*)x)[tid*2];
  float4 b = ((const float4*)x)[tid*2+1];
  float ss = a.x*a.x + a.y*a.y + a.z*a.z + a.w*a.w
           + b.x*b.x + b.y*b.y + b.z*b.z + b.w*b.w;
  #pragma unroll
  for (int m = 1; m < 64; m <<= 1) ss += __shfl_xor(ss, m, 64);
  __shared__ float red[4];
  if ((tid & 63) == 0) red[tid >> 6] = ss;
  __syncthreads();
  float tot = red[0] + red[1] + red[2] + red[3];
  float sc = rsqrtf(tot * (1.0f / D_MODEL) + 1e-6f);
  float4 ga = ((const float4*)g)[tid*2];
  float4 gb = ((const float4*)g)[tid*2+1];
  uint32_t w0 = f2bf(a.x*sc*ga.x) | ((uint32_t)f2bf(a.y*sc*ga.y) << 16);
  uint32_t w1 = f2bf(a.z*sc*ga.z) | ((uint32_t)f2bf(a.w*sc*ga.w) << 16);
  uint32_t w2 = f2bf(b.x*sc*gb.x) | ((uint32_t)f2bf(b.y*sc*gb.y) << 16);
  uint32_t w3 = f2bf(b.z*sc*gb.z) | ((uint32_t)f2bf(b.w*sc*gb.w) << 16);
  ((uint4*)(out + (size_t)row * D_MODEL))[tid] = make_uint4(w0, w1, w2, w3);
}

// ---- fused: out = x + bias + p0 [+ p1] ; nrm = rmsnorm(out)*g (bf16) ----
__global__ __launch_bounds__(256) void k_addres_rms(
    const float* __restrict__ X, const float* __restrict__ bias,
    const float* __restrict__ p0, const float* __restrict__ p1,
    const float* __restrict__ g, float* __restrict__ out,
    u16* __restrict__ nrm){
  int row = blockIdx.x, tid = threadIdx.x;
  size_t base = (size_t)row * D_MODEL;
  float4 a  = ((const float4*)(X  + base))[tid*2];
  float4 b  = ((const float4*)(X  + base))[tid*2+1];
  float4 ba = ((const float4*)bias)[tid*2];
  float4 bb = ((const float4*)bias)[tid*2+1];
  float4 pa = ((const float4*)(p0 + base))[tid*2];
  float4 pb = ((const float4*)(p0 + base))[tid*2+1];
  a.x += ba.x + pa.x; a.y += ba.y + pa.y;
  a.z += ba.z + pa.z; a.w += ba.w + pa.w;
  b.x += bb.x + pb.x; b.y += bb.y + pb.y;
  b.z += bb.z + pb.z; b.w += bb.w + pb.w;
  if (p1){
    float4 qa = ((const float4*)(p1 + base))[tid*2];
    float4 qb = ((const float4*)(p1 + base))[tid*2+1];
    a.x += qa.x; a.y += qa.y; a.z += qa.z; a.w += qa.w;
    b.x += qb.x; b.y += qb.y; b.z += qb.z; b.w += qb.w;
  }
  ((float4*)(out + base))[tid*2]   = a;
  ((float4*)(out + base))[tid*2+1] = b;
  float ss = a.x*a.x + a.y*a.y + a.z*a.z + a.w*a.w
           + b.x*b.x + b.y*b.y + b.z*b.z + b.w*b.w;
  #pragma unroll
  for (int m = 1; m < 64; m <<= 1) ss += __shfl_xor(ss, m, 64);
  __shared__ float red[4];
  if ((tid & 63) == 0) red[tid >> 6] = ss;
  __syncthreads();
  float tot = red[0] + red[1] + red[2] + red[3];
  float sc = rsqrtf(tot * (1.0f / D_MODEL) + 1e-6f);
  float4 ga = ((const float4*)g)[tid*2];
  float4 gb = ((const float4*)g)[tid*2+1];
  uint32_t w0 = f2bf(a.x*sc*ga.x) | ((uint32_t)f2bf(a.y*sc*ga.y) << 16);
  uint32_t w1 = f2bf(a.z*sc*ga.z) | ((uint32_t)f2bf(a.w*sc*ga.w) << 16);
  uint32_t w2 = f2bf(b.x*sc*gb.x) | ((uint32_t)f2bf(b.y*sc*gb.y) << 16);
  uint32_t w3 = f2bf(b.z*sc*gb.z) | ((uint32_t)f2bf(b.w*sc*gb.w) << 16);
  ((uint4*)(nrm + base))[tid] = make_uint4(w0, w1, w2, w3);
}

// ---- hg = silu(h1) * h3 (bf16, 8 elems/thread) ----
__global__ __launch_bounds__(256) void k_silu_mul(const u16* __restrict__ a,
                                                  const u16* __restrict__ b,
                                                  u16* __restrict__ o, int n8){
  int i = blockIdx.x * 256 + threadIdx.x;
  if (i >= n8) return;
  uint4 av = ((const uint4*)a)[i];
  uint4 bv = ((const uint4*)b)[i];
  uint32_t aa[4] = {av.x, av.y, av.z, av.w};
  uint32_t bb[4] = {bv.x, bv.y, bv.z, bv.w};
  uint32_t rr[4];
  #pragma unroll
  for (int j = 0; j < 4; ++j){
    float x0 = bf2f((u16)(aa[j] & 0xffff)), x1 = bf2f((u16)(aa[j] >> 16));
    float y0 = bf2f((u16)(bb[j] & 0xffff)), y1 = bf2f((u16)(bb[j] >> 16));
    float r0 = x0 / (1.f + __expf(-x0)) * y0;
    float r1 = x1 / (1.f + __expf(-x1)) * y1;
    rr[j] = f2bf(r0) | ((uint32_t)f2bf(r1) << 16);
  }
  ((uint4*)o)[i] = make_uint4(rr[0], rr[1], rr[2], rr[3]);
}

// ============ 256x256 8-wave GEMM — 8-phase (r12-proven schedule) ============
// EPI 0: bf16 +bias; EPI 5: dual bf16 out (n0<5632 -> Cout, else aux-5632)
template<int EPI>
__global__ __launch_bounds__(512, 2) void k_gemm8p(
    const u16* __restrict__ A, const u16* __restrict__ Bt,
    const float* __restrict__ bias, const u16* __restrict__ aux,
    void* __restrict__ Cout, int M, int N, int K,
    int lda, int ldb, int ldc)
{
  extern __shared__ __align__(16) char smem[];
  const int tid = threadIdx.x;
  const int lane = tid & 63, wid = tid >> 6;
  const int wr = wid >> 2, wc = wid & 3;
  const int lrow = lane & 15, lhi = lane >> 4;

  int nwg = gridDim.x, wg = blockIdx.x;

  int nbx = N >> 8, nbm = M >> 8;
  int xcd = wg & 7, sub = wg >> 3;
  int m0, n0;
  if ((nwg & 7) == 0 && (nbm & 1) == 0 && (nbx & 3) == 0){
    int mh = nbm >> 1;
    int mr = sub % mh, nc = sub / mh;
    m0 = (((xcd & 1) * mh) + mr) << 8;
    n0 = (((xcd >> 1) * (nbx >> 2)) + nc) << 8;
  } else {
    int qq = nwg >> 3, rr2 = nwg & 7;
    int swz = (xcd < rr2 ? xcd*(qq+1) : rr2*(qq+1) + (xcd-rr2)*qq) + sub;
    m0 = (swz / nbx) << 8; n0 = (swz % nbx) << 8;
  }

  const int nk = K >> 6;
  const int hA = wr, hB = wc >> 1;
  const int gA = wc;
  const int gB = (wr << 1) | (wc & 1);

  const u16* aSrc[2][2]; int aDst[2][2];
  const u16* bSrc[2][2]; int bDst[2][2];
  #pragma unroll
  for (int q = 0; q < 2; ++q)
    #pragma unroll
    for (int L = 0; L < 2; ++L){
      int p = q*8192 + gA*2048 + L*1024 + lane*16;
      int row = p >> 7;
      int o = (p & 127) ^ ((row & 7) << 4);
      aSrc[q][L] = A + (size_t)(m0 + hA*128 + row)*lda + (o >> 1);
      aDst[q][L] = hA*16384 + p;
      int pb = q*4096 + (gB >> 1)*8192 + (gB & 1)*2048 + L*1024 + lane*16;
      int rowb = pb >> 7;
      int ob = (pb & 127) ^ ((rowb & 7) << 4);
      bSrc[q][L] = Bt + (size_t)(n0 + hB*128 + rowb)*ldb + (ob >> 1);
      bDst[q][L] = 32768 + hB*16384 + pb;
    }
  const int xo0 = (lhi*16) ^ ((lrow & 7) << 4);
  const int xo1 = (64 + lhi*16) ^ ((lrow & 7) << 4);

  auto stA = [&](int d, int kk, int q){
    #pragma unroll
    for (int L = 0; L < 2; ++L)
      __builtin_amdgcn_global_load_lds(
        (const AS1 void*)(aSrc[q][L] + kk),
        (AS3 void*)(smem + d*65536 + aDst[q][L]), 16, 0, 0);
  };
  auto stB = [&](int d, int kk, int s){
    #pragma unroll
    for (int L = 0; L < 2; ++L)
      __builtin_amdgcn_global_load_lds(
        (const AS1 void*)(bSrc[s][L] + kk),
        (AS3 void*)(smem + d*65536 + bDst[s][L]), 16, 0, 0);
  };
  auto rdA = [&](int d, int rloc, int ks)->bf16x8{
    return *(const bf16x8*)(smem + d*65536 + hA*16384 + rloc*128 + (ks ? xo1 : xo0));
  };
  auto rdB = [&](int d, int rloc, int ks)->bf16x8{
    return *(const bf16x8*)(smem + d*65536 + 32768 + hB*16384 + rloc*128 + (ks ? xo1 : xo0));
  };

  f32x4 acc[8][4] = {};

  stA(0, 0, 0); stB(0, 0, 0); stB(0, 0, 1); stA(0, 0, 1);
  asm volatile("s_waitcnt vmcnt(0)" ::: "memory");
  __builtin_amdgcn_s_barrier();

  for (int t = 0; t < nk; ++t){
    int d = t & 1, dn = d ^ 1, kkn = (t + 1) << 6;
    bool pf = (t + 1 < nk);
    bf16x8 aR[8], bQ0[4], bQ1[4];

    // ---- phase 0: Q00 ----
    #pragma unroll
    for (int ii = 0; ii < 4; ++ii){
      aR[ii*2]   = rdA(d, ii*16 + lrow, 0);
      aR[ii*2+1] = rdA(d, ii*16 + lrow, 1);
    }
    #pragma unroll
    for (int j = 0; j < 2; ++j){
      bQ0[j*2]   = rdB(d, (wc&1)*64 + j*16 + lrow, 0);
      bQ0[j*2+1] = rdB(d, (wc&1)*64 + j*16 + lrow, 1);
    }
    if (pf){ stA(dn, kkn, 0); stB(dn, kkn, 0); }
    __builtin_amdgcn_s_barrier();
    asm volatile("s_waitcnt lgkmcnt(0)" ::: "memory");
    __builtin_amdgcn_sched_barrier(0);
    __builtin_amdgcn_s_setprio(1);
    #pragma unroll
    for (int ii = 0; ii < 4; ++ii)
      #pragma unroll
      for (int j = 0; j < 2; ++j){
        acc[ii][j] = __builtin_amdgcn_mfma_f32_16x16x32_bf16(aR[ii*2],   bQ0[j*2],   acc[ii][j], 0, 0, 0);
        acc[ii][j] = __builtin_amdgcn_mfma_f32_16x16x32_bf16(aR[ii*2+1], bQ0[j*2+1], acc[ii][j], 0, 0, 0);
      }
    __builtin_amdgcn_s_setprio(0);
    if (pf) asm volatile("s_waitcnt vmcnt(6)" ::: "memory");
    else    asm volatile("s_waitcnt vmcnt(2)" ::: "memory");
    __builtin_amdgcn_sched_barrier(0);
    __builtin_amdgcn_s_barrier();

    // ---- phase 1: Q01 ----
    #pragma unroll
    for (int j = 0; j < 2; ++j){
      bQ1[j*2]   = rdB(d, (wc&1)*64 + 32 + j*16 + lrow, 0);
      bQ1[j*2+1] = rdB(d, (wc&1)*64 + 32 + j*16 + lrow, 1);
    }
    if (pf) stB(dn, kkn, 1);
    __builtin_amdgcn_s_barrier();
    asm volatile("s_waitcnt lgkmcnt(0)" ::: "memory");
    __builtin_amdgcn_sched_barrier(0);
    __builtin_amdgcn_s_setprio(1);
    #pragma unroll
    for (int ii = 0; ii < 4; ++ii)
      #pragma unroll
      for (int j = 0; j < 2; ++j){
        acc[ii][2+j] = __builtin_amdgcn_mfma_f32_16x16x32_bf16(aR[ii*2],   bQ1[j*2],   acc[ii][2+j], 0, 0, 0);
        acc[ii][2+j] = __builtin_amdgcn_mfma_f32_16x16x32_bf16(aR[ii*2+1], bQ1[j*2+1], acc[ii][2+j], 0, 0, 0);
      }
    __builtin_amdgcn_s_setprio(0);
    if (pf) asm volatile("s_waitcnt vmcnt(6)" ::: "memory");
    else    asm volatile("s_waitcnt vmcnt(0)" ::: "memory");
    __builtin_amdgcn_sched_barrier(0);
    __builtin_amdgcn_s_barrier();

    // ---- phase 2: Q11 ----
    #pragma unroll
    for (int ii = 0; ii < 4; ++ii){
      aR[ii*2]   = rdA(d, 64 + ii*16 + lrow, 0);
      aR[ii*2+1] = rdA(d, 64 + ii*16 + lrow, 1);
    }
    if (pf) stA(dn, kkn, 1);
    __builtin_amdgcn_s_barrier();
    asm volatile("s_waitcnt lgkmcnt(0)" ::: "memory");
    __builtin_amdgcn_sched_barrier(0);
    __builtin_amdgcn_s_setprio(1);
    #pragma unroll
    for (int ii = 0; ii < 4; ++ii)
      #pragma unroll
      for (int j = 0; j < 2; ++j){
        acc[4+ii][2+j] = __builtin_amdgcn_mfma_f32_16x16x32_bf16(aR[ii*2],   bQ1[j*2],   acc[4+ii][2+j], 0, 0, 0);
        acc[4+ii][2+j] = __builtin_amdgcn_mfma_f32_16x16x32_bf16(aR[ii*2+1], bQ1[j*2+1], acc[4+ii][2+j], 0, 0, 0);
      }
    __builtin_amdgcn_s_setprio(0);
    __builtin_amdgcn_s_barrier();

    // ---- phase 3: Q10 ----
    __builtin_amdgcn_s_setprio(1);
    #pragma unroll
    for (int ii = 0; ii < 4; ++ii)
      #pragma unroll
      for (int j = 0; j < 2; ++j){
        acc[4+ii][j] = __builtin_amdgcn_mfma_f32_16x16x32_bf16(aR[ii*2],   bQ0[j*2],   acc[4+ii][j], 0, 0, 0);
        acc[4+ii][j] = __builtin_amdgcn_mfma_f32_16x16x32_bf16(aR[ii*2+1], bQ0[j*2+1], acc[4+ii][j], 0, 0, 0);
      }
    __builtin_amdgcn_s_setprio(0);
    if (pf) asm volatile("s_waitcnt vmcnt(4)" ::: "memory");
    __builtin_amdgcn_sched_barrier(0);
    __builtin_amdgcn_s_barrier();
  }

  u16* Cw = (u16*)Cout;
  int cofs = 0;
  if constexpr (EPI == 5){
    if (n0 >= 5632){ Cw = (u16*)aux; cofs = 5632; }
  }
  #pragma unroll
  for (int i = 0; i < 8; ++i){
    #pragma unroll
    for (int j = 0; j < 4; ++j){
      int col = n0 + wc*64 + j*16 + lrow;
      float bv = 0.f;
      if constexpr (EPI == 0) bv = bias[col];
      #pragma unroll
      for (int q = 0; q < 4; ++q){
        int row = m0 + wr*128 + i*16 + lhi*4 + q;
        float v = acc[i][j][q] + bv;
        Cw[(size_t)row*ldc + (col - cofs)] = f2bf(v);
      }
    }
  }
}

// ============ 256Mx128N 8-wave GEMM — 2-phase, no split-K (full-round N=2048) ============
// LDS = 2 x (A 32KB + B 16KB) = 96KB. Waves 2M x 4N, per-wave 128x32 out, acc[8][2].
// Per K-tile: P0 reads Aq0(8)+B(4), stages t+1 Aq0+B; P1 reads Aq1(8), stages t+1 Aq1.
// vmcnt FIFO audit: enter P0(t): outstanding Aq1(t)[2]; P0 issues 4 -> 6; P0-end
// vmcnt(4) drains Aq1(t) before P1 reads it; P1 issues 2 -> 6; P1-end vmcnt(2)
// drains Aq0/B(t+1) before next P0 reads them. Never 0 mid-loop.
// EPI 8: fp32 out = acc + res (fused residual); EPI 9: fp32 out = acc.
template<int EPI>
__global__ __launch_bounds__(512, 2) void k_gemm8pn(
    const u16* __restrict__ A, const u16* __restrict__ Bt,
    const float* __restrict__ res, float* __restrict__ Cout,
    int M, int N, int K, int lda, int ldb, int ldc)
{
  extern __shared__ __align__(16) char smem[];
  const int tid = threadIdx.x;
  const int lane = tid & 63, wid = tid >> 6;
  const int wr = wid >> 2, wc = wid & 3;
  const int lrow = lane & 15, lhi = lane >> 4;

  int nwg = gridDim.x, wg = blockIdx.x;
  int nbx = N >> 7, nbm = M >> 8;
  int xcd = wg & 7, sub = wg >> 3;
  int m0, n0;
  if ((nwg & 7) == 0 && (nbm & 1) == 0 && (nbx & 3) == 0){
    int mh = nbm >> 1;
    int mr = sub % mh, nc = sub / mh;
    m0 = (((xcd & 1) * mh) + mr) << 8;
    n0 = (((xcd >> 1) * (nbx >> 2)) + nc) << 7;
  } else {
    int qq = nwg >> 3, rr2 = nwg & 7;
    int swz = (xcd < rr2 ? xcd*(qq+1) : rr2*(qq+1) + (xcd-rr2)*qq) + sub;
    m0 = (swz / nbx) << 8; n0 = (swz % nbx) << 7;
  }

  const int nk = K >> 6;
  const int hA = wr;
  const int gA = wc;

  // A staging identical to 256^2 kernel; B: [128][64] bf16, 1 load/thread/half.
  const u16* aSrc[2][2]; int aDst[2][2];
  #pragma unroll
  for (int q = 0; q < 2; ++q)
    #pragma unroll
    for (int L = 0; L < 2; ++L){
      int p = q*8192 + gA*2048 + L*1024 + lane*16;
      int row = p >> 7;
      int o = (p & 127) ^ ((row & 7) << 4);
      aSrc[q][L] = A + (size_t)(m0 + hA*128 + row)*lda + (o >> 1);
      aDst[q][L] = hA*16384 + p;
    }
  const u16* bSrc[2]; int bDst[2];
  #pragma unroll
  for (int s = 0; s < 2; ++s){
    int p = s*8192 + wid*1024 + lane*16;
    int row = p >> 7;
    int o = (p & 127) ^ ((row & 7) << 4);
    bSrc[s] = Bt + (size_t)(n0 + row)*ldb + (o >> 1);
    bDst[s] = 32768 + p;
  }
  const int xo0 = (lhi*16) ^ ((lrow & 7) << 4);
  const int xo1 = (64 + lhi*16) ^ ((lrow & 7) << 4);

  auto stA = [&](int d, int kk, int q){
    #pragma unroll
    for (int L = 0; L < 2; ++L)
      __builtin_amdgcn_global_load_lds(
        (const AS1 void*)(aSrc[q][L] + kk),
        (AS3 void*)(smem + d*49152 + aDst[q][L]), 16, 0, 0);
  };
  auto stB = [&](int d, int kk){
    #pragma unroll
    for (int s = 0; s < 2; ++s)
      __builtin_amdgcn_global_load_lds(
        (const AS1 void*)(bSrc[s] + kk),
        (AS3 void*)(smem + d*49152 + bDst[s]), 16, 0, 0);
  };
  auto rdA = [&](int d, int rloc, int ks)->bf16x8{
    return *(const bf16x8*)(smem + d*49152 + hA*16384 + rloc*128 + (ks ? xo1 : xo0));
  };
  auto rdB = [&](int d, int rloc, int ks)->bf16x8{
    return *(const bf16x8*)(smem + d*49152 + 32768 + rloc*128 + (ks ? xo1 : xo0));
  };

  f32x4 acc[8][2] = {};

  // prologue: Aq0(2), B(2), Aq1(2)
  stA(0, 0, 0); stB(0, 0); stA(0, 0, 1);
  asm volatile("s_waitcnt vmcnt(0)" ::: "memory");
  __builtin_amdgcn_s_barrier();

  for (int t = 0; t < nk; ++t){
    int d = t & 1, dn = d ^ 1, kkn = (t + 1) << 6;
    bool pf = (t + 1 < nk);
    bf16x8 aR[8], bQ[4];

    // ---- phase 0: rows 0-63 ----
    #pragma unroll
    for (int ii = 0; ii < 4; ++ii){
      aR[ii*2]   = rdA(d, ii*16 + lrow, 0);
      aR[ii*2+1] = rdA(d, ii*16 + lrow, 1);
    }
    #pragma unroll
    for (int j = 0; j < 2; ++j){
      bQ[j*2]   = rdB(d, wc*32 + j*16 + lrow, 0);
      bQ[j*2+1] = rdB(d, wc*32 + j*16 + lrow, 1);
    }
    if (pf){ stA(dn, kkn, 0); stB(dn, kkn); }
    __builtin_amdgcn_s_barrier();
    asm volatile("s_waitcnt lgkmcnt(0)" ::: "memory");
    __builtin_amdgcn_sched_barrier(0);
    __builtin_amdgcn_s_setprio(1);
    #pragma unroll
    for (int ii = 0; ii < 4; ++ii)
      #pragma unroll
      for (int j = 0; j < 2; ++j){
        acc[ii][j] = __builtin_amdgcn_mfma_f32_16x16x32_bf16(aR[ii*2],   bQ[j*2],   acc[ii][j], 0, 0, 0);
        acc[ii][j] = __builtin_amdgcn_mfma_f32_16x16x32_bf16(aR[ii*2+1], bQ[j*2+1], acc[ii][j], 0, 0, 0);
      }
    __builtin_amdgcn_s_setprio(0);
    if (pf) asm volatile("s_waitcnt vmcnt(4)" ::: "memory");
    else    asm volatile("s_waitcnt vmcnt(0)" ::: "memory");
    __builtin_amdgcn_sched_barrier(0);
    __builtin_amdgcn_s_barrier();

    // ---- phase 1: rows 64-127 (reuse bQ) ----
    #pragma unroll
    for (int ii = 0; ii < 4; ++ii){
      aR[ii*2]   = rdA(d, 64 + ii*16 + lrow, 0);
      aR[ii*2+1] = rdA(d, 64 + ii*16 + lrow, 1);
    }
    if (pf) stA(dn, kkn, 1);
    __builtin_amdgcn_s_barrier();
    asm volatile("s_waitcnt lgkmcnt(0)" ::: "memory");
    __builtin_amdgcn_sched_barrier(0);
    __builtin_amdgcn_s_setprio(1);
    #pragma unroll
    for (int ii = 0; ii < 4; ++ii)
      #pragma unroll
      for (int j = 0; j < 2; ++j){
        acc[4+ii][j] = __builtin_amdgcn_mfma_f32_16x16x32_bf16(aR[ii*2],   bQ[j*2],   acc[4+ii][j], 0, 0, 0);
        acc[4+ii][j] = __builtin_amdgcn_mfma_f32_16x16x32_bf16(aR[ii*2+1], bQ[j*2+1], acc[4+ii][j], 0, 0, 0);
      }
    __builtin_amdgcn_s_setprio(0);
    if (pf) asm volatile("s_waitcnt vmcnt(2)" ::: "memory");
    else    asm volatile("s_waitcnt vmcnt(0)" ::: "memory");
    __builtin_amdgcn_sched_barrier(0);
    __builtin_amdgcn_s_barrier();
  }

  #pragma unroll
  for (int i = 0; i < 8; ++i){
    #pragma unroll
    for (int j = 0; j < 2; ++j){
      int col = n0 + wc*32 + j*16 + lrow;
      #pragma unroll
      for (int q = 0; q < 4; ++q){
        int row = m0 + wr*128 + i*16 + lhi*4 + q;
        size_t idx = (size_t)row*ldc + col;
        float v = acc[i][j][q];
        if constexpr (EPI == 8) v += res[idx];
        Cout[idx] = v;
      }
    }
  }
}

// ---- 128x128 GEMM (3-buffer counted vmcnt, row&3 chunk swizzle) — fallback ----
template<int EPI>
__global__ __launch_bounds__(256) void k_gemm_bt(
    const u16* __restrict__ A, const u16* __restrict__ Bt,
    const float* __restrict__ bias, const float* __restrict__ res,
    const u16* __restrict__ aux,
    void* __restrict__ Cout, int M, int N, int K,
    int lda, int ldb, int ldc)
{
  __shared__ __align__(16) u16 As[3][128*32];
  __shared__ __align__(16) u16 Bs[3][128*32];
  int tid = threadIdx.x;

  int nwg = gridDim.x, wg = blockIdx.x;
  int qq = nwg >> 3, rr = nwg & 7;
  int xcd = wg & 7, sub = wg >> 3;
  int swz = (xcd < rr ? xcd*(qq+1) : rr*(qq+1) + (xcd-rr)*qq) + sub;
  int nbx = N >> 7;
  int m0 = (swz / nbx) << 7, n0 = (swz % nbx) << 7;

  int lane = tid & 63, wave = tid >> 6;
  int wr = wave >> 1, wc = wave & 1;
  int lrow = lane & 15, lhi = lane >> 4;
  f32x4 acc[4][4] = {};
  int srow = tid >> 2;
  int schk = tid & 3;
  const int nk = K >> 5;

  auto stage = [&](int slot, int kt){
    int k0 = kt << 5;
    int c = schk ^ (srow & 3);
    #pragma unroll
    for (int cc = 0; cc < 2; ++cc){
      int r = cc*64 + srow;
      __builtin_amdgcn_global_load_lds(
        (const AS1 void*)(A + (size_t)(m0 + r)*lda + k0 + c*8),
        (AS3 void*)(&As[slot][r*32 + schk*8]), 16, 0, 0);
      __builtin_amdgcn_global_load_lds(
        (const AS1 void*)(Bt + (size_t)(n0 + r)*ldb + k0 + c*8),
        (AS3 void*)(&Bs[slot][r*32 + schk*8]), 16, 0, 0);
    }
  };

  stage(0, 0);
  if (nk > 1) stage(1, 1);
  if (nk > 1) asm volatile("s_waitcnt vmcnt(4)" ::: "memory");
  else        asm volatile("s_waitcnt vmcnt(0)" ::: "memory");
  __builtin_amdgcn_s_barrier();

  for (int kt = 0; kt < nk; ++kt){
    int cur = kt % 3;
    if (kt + 2 < nk) stage((kt + 2) % 3, kt + 2);
    int rchk = lhi ^ (lrow & 3);
    bf16x8 af[4], bfv[4];
    #pragma unroll
    for (int i = 0; i < 4; ++i){
      af[i]  = *(const bf16x8*)(&As[cur][(wr*64 + i*16 + lrow)*32 + rchk*8]);
      bfv[i] = *(const bf16x8*)(&Bs[cur][(wc*64 + i*16 + lrow)*32 + rchk*8]);
    }
    #pragma unroll
    for (int i = 0; i < 4; ++i)
      #pragma unroll
      for (int j = 0; j < 4; ++j)
        acc[i][j] = __builtin_amdgcn_mfma_f32_16x16x32_bf16(af[i], bfv[j], acc[i][j], 0, 0, 0);
    if (kt + 2 < nk) asm volatile("s_waitcnt vmcnt(4)" ::: "memory");
    else             asm volatile("s_waitcnt vmcnt(0)" ::: "memory");
    __builtin_amdgcn_s_barrier();
  }

  #pragma unroll
  for (int i = 0; i < 4; ++i){
    #pragma unroll
    for (int j = 0; j < 4; ++j){
      int col = n0 + wc*64 + j*16 + lrow;
      float bv = 0.f;
      if constexpr (EPI == 0 || EPI == 1) bv = bias[col];
      #pragma unroll
      for (int q = 0; q < 4; ++q){
        int row = m0 + wr*64 + i*16 + lhi*4 + q;
        size_t idx = (size_t)row*ldc + col;
        float v = acc[i][j][q] + bv;
        if constexpr (EPI == 1 || EPI == 3) v += res[idx];
        if constexpr (EPI == 4){
          float a0 = bf2f(aux[idx]);
          v = a0 / (1.f + __expf(-a0)) * v;
        }
        if constexpr (EPI == 0 || EPI == 2 || EPI == 4) ((u16*)Cout)[idx] = f2bf(v);
        else ((float*)Cout)[idx] = v;
      }
    }
  }
}

// ---- causal flash attention: paired-qblock load balancing (unchanged) ----
__global__ __launch_bounds__(512) void k_attn(
    const u16* __restrict__ Q, const u16* __restrict__ Kb,
    const u16* __restrict__ Vt, u16* __restrict__ O, int ldq)
{
  int tid = threadIdx.x, lane = tid & 63, wave = tid >> 6;
  int lrow = lane & 15, lhi = lane >> 4;
  int bidx = blockIdx.x;
  int bh = bidx >> 3, j = bidx & 7;
  int b = bh >> 4, h = bh & 15;

  __shared__ __align__(16) u16 Kbuf[2][64*128];
  __shared__ __align__(16) u16 Vbuf[2][128*64];
  __shared__ __align__(16) u16 P_lds[8][16*64];
  char* pw = (char*)&P_lds[wave][0];
  const float sc2 = 0.08838834764831845f * 1.44269504088896340736f;

  auto stage = [&](int bufi, int kt){
    int kv0 = kt << 6;
    char* kd = (char*)&Kbuf[bufi][0];
    char* vd = (char*)&Vbuf[bufi][0];
    #pragma unroll
    for (int L = 0; L < 2; ++L){
      int cid = wave*128 + L*64 + lane;
      int r = cid >> 4, c = cid & 15;
      int cg = c ^ (r & 7);
      __builtin_amdgcn_global_load_lds(
        (const AS1 void*)(Kb + (size_t)(b*SS + kv0 + r)*ldq + h*DK + cg*8),
        (AS3 void*)(kd + wave*2048 + L*1024 + lane*16), 16, 0, 0);
      int dd = cid >> 3, c8 = cid & 7;
      int cv = c8 ^ (dd & 7);
      __builtin_amdgcn_global_load_lds(
        (const AS1 void*)(Vt + (size_t)bh*DK*SS + (size_t)dd*SS + kv0 + cv*8),
        (AS3 void*)(vd + wave*2048 + L*1024 + lane*16), 16, 0, 0);
    }
  };

  #pragma unroll 1
  for (int item = 0; item < 2; ++item){
    int qi = item == 0 ? 15 - j : j;
    int qs = qi * 128;
    int nt = 2*qi + 2;
    int qrow = qs + wave * 16;

    bf16x8 qf[4];
    const u16* qbase = Q + (size_t)(b*SS + qrow + lrow)*ldq + h*DK + lhi*8;
    #pragma unroll
    for (int dc = 0; dc < 4; ++dc) qf[dc] = *(const bf16x8*)(qbase + dc*32);

    f32x4 accO[8] = {};
    float mr[4] = {-1e30f,-1e30f,-1e30f,-1e30f};
    float lr[4] = {0.f,0.f,0.f,0.f};

    stage(0, 0);
    __syncthreads();

    for (int kt = 0; kt < nt; ++kt){
      int cur = kt & 1;
      if (kt + 1 < nt) stage(cur ^ 1, kt + 1);
      int kv0 = kt << 6;
      if (kv0 <= qrow + 15){
        const char* kl = (const char*)&Kbuf[cur][0];
        const char* vl = (const char*)&Vbuf[cur][0];
        bool domask = (kv0 + 63 > qrow);

        f32x4 sf[4];
        #pragma unroll
        for (int hf = 0; hf < 4; ++hf){
          int rl = hf*16 + lrow;
          int sw = rl & 7;
          f32x4 a = {};
          #pragma unroll
          for (int dc = 0; dc < 4; ++dc){
            bf16x8 kf = *(const bf16x8*)(kl + rl*256 + (((lhi + dc*4) ^ sw) << 4));
            a = __builtin_amdgcn_mfma_f32_16x16x32_bf16(qf[dc], kf, a, 0, 0, 0);
          }
          sf[hf] = a;
        }

        float p[4][4], mx[4];
        #pragma unroll
        for (int q = 0; q < 4; ++q){
          float s0 = sf[0][q]*sc2, s1 = sf[1][q]*sc2, s2 = sf[2][q]*sc2, s3 = sf[3][q]*sc2;
          if (domask){
            int qg = qrow + lhi*4 + q;
            if (kv0      + lrow > qg) s0 = -1e30f;
            if (kv0 + 16 + lrow > qg) s1 = -1e30f;
            if (kv0 + 32 + lrow > qg) s2 = -1e30f;
            if (kv0 + 48 + lrow > qg) s3 = -1e30f;
          }
          p[q][0]=s0; p[q][1]=s1; p[q][2]=s2; p[q][3]=s3;
          float m = fmaxf(fmaxf(s0,s1), fmaxf(s2,s3));
          m = fmaxf(m, __shfl_xor(m, 1, 64));
          m = fmaxf(m, __shfl_xor(m, 2, 64));
          m = fmaxf(m, __shfl_xor(m, 4, 64));
          m = fmaxf(m, __shfl_xor(m, 8, 64));
          mx[q] = m;
        }
        float dmax = fmaxf(fmaxf(mx[0]-mr[0], mx[1]-mr[1]), fmaxf(mx[2]-mr[2], mx[3]-mr[3]));
        bool rescale = !__all(dmax <= 8.0f);
        float al[4];
        #pragma unroll
        for (int q = 0; q < 4; ++q){
          if (rescale){
            float mn = fmaxf(mr[q], mx[q]);
            al[q] = fexp2(mr[q] - mn);
            mr[q] = mn;
          } else al[q] = 1.0f;
          p[q][0] = fexp2(p[q][0] - mr[q]);
          p[q][1] = fexp2(p[q][1] - mr[q]);
          p[q][2] = fexp2(p[q][2] - mr[q]);
          p[q][3] = fexp2(p[q][3] - mr[q]);
          float sm = (p[q][0] + p[q][1]) + (p[q][2] + p[q][3]);
          sm += __shfl_xor(sm, 1, 64);
          sm += __shfl_xor(sm, 2, 64);
          sm += __shfl_xor(sm, 4, 64);
          sm += __shfl_xor(sm, 8, 64);
          lr[q] = lr[q]*al[q] + sm;
        }
        if (rescale){
          #pragma unroll
          for (int f = 0; f < 8; ++f)
            #pragma unroll
            for (int q = 0; q < 4; ++q) accO[f][q] *= al[q];
        }

        #pragma unroll
        for (int q = 0; q < 4; ++q){
          int row = lhi*4 + q;
          int rb = row*128, sw = (row & 7) << 4;
          #pragma unroll
          for (int hf = 0; hf < 4; ++hf)
            *(u16*)(pw + rb + ((hf*32 + lrow*2) ^ sw)) = cvt_bf16(p[q][hf]);
        }
        __builtin_amdgcn_sched_barrier(0);
        int rsw = (lrow & 7) << 4;
        bf16x8 pa0 = *(const bf16x8*)(pw + lrow*128 + ((     lhi*16) ^ rsw));
        bf16x8 pa1 = *(const bf16x8*)(pw + lrow*128 + ((64 + lhi*16) ^ rsw));

        #pragma unroll
        for (int f = 0; f < 8; ++f){
          int d = f*16 + lrow;
          int swv = d & 7;
          bf16x8 v0 = *(const bf16x8*)(vl + d*128 + (((lhi    ) ^ swv) << 4));
          bf16x8 v1 = *(const bf16x8*)(vl + d*128 + (((lhi + 4) ^ swv) << 4));
          accO[f] = __builtin_amdgcn_mfma_f32_16x16x32_bf16(pa0, v0, accO[f], 0, 0, 0);
          accO[f] = __builtin_amdgcn_mfma_f32_16x16x32_bf16(pa1, v1, accO[f], 0, 0, 0);
        }
      }
      __syncthreads();
    }

    #pragma unroll
    for (int q = 0; q < 4; ++q){
      float inv = 1.0f / lr[q];
      #pragma unroll
      for (int f = 0; f < 8; ++f){
        int row = b*SS + qrow + lhi*4 + q;
        int col = h*DK + f*16 + lrow;
        O[(size_t)row*D_MODEL + col] = cvt_bf16(accO[f][q] * inv);
      }
    }
    __syncthreads();
  }
}

extern "C" void kernel_launch(void* const* d_in, const int* in_sizes, int n_in,
                              void* d_out, int out_size, void* d_ws, size_t ws_size,
                              hipStream_t stream)
{
  (void)in_sizes; (void)n_in; (void)out_size;
  const float* x  = (const float*)d_in[0];
  const float* wq = (const float*)d_in[2];
  const float* bq = (const float*)d_in[3];
  const float* wk = (const float*)d_in[4];
  const float* bk = (const float*)d_in[5];
  const float* wv = (const float*)d_in[6];
  const float* bv = (const float*)d_in[7];
  const float* wo = (const float*)d_in[8];
  const float* bo = (const float*)d_in[9];
  const float* g1 = (const float*)d_in[10];
  const float* g2 = (const float*)d_in[11];
  const float* w1 = (const float*)d_in[12];
  const float* w3 = (const float*)d_in[13];
  const float* w2 = (const float*)d_in[14];
  float* out = (float*)d_out;

  const size_t MB = 1u << 20;
  const size_t W2T_B = (size_t)D_MODEL * DFF * sizeof(u16);
  const size_t NEED = 152*MB + W2T_B + 32768;
  if (ws_size < NEED) return;
  char* ws = (char*)d_ws;
  u16* bufA  = (u16*)(ws + 0);        // 16 MiB: nbf1 -> aob -> nbf2
  u16* qkv   = (u16*)(ws + 16*MB);    // 48 MiB fused QKV [4096][6144]
  u16* h1    = qkv;                   // [4096][5632], aliases after attn
  u16* wqkvt = (u16*)(ws + 64*MB);    // 24 MiB, dead after QKV GEMM
  u16* w1w3t = (u16*)(ws + 64*MB);    // [11264][2048] (64-108)
  u16* wot   = (u16*)(ws + 88*MB);    // 8 MiB (w1w3 transpose AFTER O-proj)
  u16* vtb   = (u16*)(ws + 96*MB);    // 16 MiB (dead after attn)
  u16* h3    = (u16*)(ws + 108*MB);   // [4096][5632] (108-152)
  float* p0o = (float*)(ws + 16*MB);  // O-proj partial: qkv dead after attn
  u16* w2t   = (u16*)(ws + 152*MB);
  float* bqkv = (float*)(ws + 152*MB + W2T_B);
  // fp32 residual x1 lives in d_out

  bool big = true;
  big &= hipFuncSetAttribute((const void*)k_gemm8p<0>, hipFuncAttributeMaxDynamicSharedMemorySize, 131072) == hipSuccess;
  big &= hipFuncSetAttribute((const void*)k_gemm8p<5>, hipFuncAttributeMaxDynamicSharedMemorySize, 131072) == hipSuccess;
  big &= hipFuncSetAttribute((const void*)k_gemm8pn<8>, hipFuncAttributeMaxDynamicSharedMemorySize, 98304) == hipSuccess;
  big &= hipFuncSetAttribute((const void*)k_gemm8pn<9>, hipFuncAttributeMaxDynamicSharedMemorySize, 98304) == hipSuccess;

  dim3 tb(32, 8);
  k_transpose_w4<<<dim3(64,64,4), tb, 0, stream>>>(wq, wk, wv, wo,
      wqkvt, wqkvt + 2048*2048, wqkvt + 2*2048*2048, wot);
  k_transpose_w<<<dim3(64, DFF/32), tb, 0, stream>>>(w2, w2t, DFF, D_MODEL);
  k_concat3<<<24, 256, 0, stream>>>(bq, bk, bv, bqkv);

  k_rmsnorm<<<MTOK, 256, 0, stream>>>(x, g1, bufA);
  if (big){
    k_gemm8p<0><<<(MTOK/256)*(DQKV/256), 512, 131072, stream>>>(bufA, wqkvt, bqkv, nullptr, qkv, MTOK, DQKV, D_MODEL, D_MODEL, D_MODEL, DQKV);
    k_transpose_v<<<dim3(SS/32, 128), tb, 0, stream>>>(qkv + 4096, vtb, DQKV);
    k_attn<<<dim3(BB*NHEADS*8), 512, 0, stream>>>(qkv, qkv + 2048, vtb, bufA, DQKV);
    // O-proj: 256Mx128N, 256 blocks, no split-K -> single fp32 partial
    k_gemm8pn<9><<<(MTOK/256)*(D_MODEL/128), 512, 98304, stream>>>(bufA, wot, nullptr, p0o, MTOK, D_MODEL, D_MODEL, D_MODEL, D_MODEL, D_MODEL);
    // w1|w3 -> w1w3t (dead wqkvt + wot + vtb): after O-proj & attn
    k_transpose_w13<<<dim3(DFFP/32, 64, 2), tb, 0, stream>>>(w1, w3, w1w3t);
    k_addres_rms<<<MTOK, 256, 0, stream>>>(x, bo, p0o, nullptr, g2, out, bufA);
    // combined W1|W3: N=11264, dual output h1/h3, ldc=DFFP
    k_gemm8p<5><<<(MTOK/256)*((2*DFFP)/256), 512, 131072, stream>>>(bufA, w1w3t, nullptr, h3, h1, MTOK, 2*DFFP, D_MODEL, D_MODEL, D_MODEL, DFFP);
    k_silu_mul<<<(MTOK*DFFP/8 + 255)/256, 256, 0, stream>>>(h1, h3, h1, MTOK*DFFP/8);
    // W2: 256Mx128N, 256 blocks, no split-K, fused residual -> final out
    k_gemm8pn<8><<<(MTOK/256)*(D_MODEL/128), 512, 98304, stream>>>(h1, w2t, out, out, MTOK, D_MODEL, DFF, DFFP, DFF, D_MODEL);
  } else {
    k_gemm_bt<0><<<(DQKV/128)*(MTOK/128), 256, 0, stream>>>(bufA, wqkvt, bqkv, nullptr, nullptr, qkv, MTOK, DQKV, D_MODEL, D_MODEL, D_MODEL, DQKV);
    k_transpose_v<<<dim3(SS/32, 128), tb, 0, stream>>>(qkv + 4096, vtb, DQKV);
    k_transpose_w13<<<dim3(DFFP/32, 64, 2), tb, 0, stream>>>(w1, w3, w1w3t);
    k_attn<<<dim3(BB*NHEADS*8), 512, 0, stream>>>(qkv, qkv + 2048, vtb, bufA, DQKV);
    k_gemm_bt<1><<<16*32, 256, 0, stream>>>(bufA, wot, bo, x, nullptr, out, MTOK, D_MODEL, D_MODEL, D_MODEL, D_MODEL, D_MODEL);
    k_rmsnorm<<<MTOK, 256, 0, stream>>>(out, g2, bufA);
    k_gemm_bt<2><<<(DFFP/128)*32, 256, 0, stream>>>(bufA, w1w3t, nullptr, nullptr, nullptr, h1, MTOK, DFFP, D_MODEL, D_MODEL, D_MODEL, DFFP);
    k_gemm_bt<2><<<(DFFP/128)*32, 256, 0, stream>>>(bufA, w1w3t + (size_t)DFFP*2048, nullptr, nullptr, nullptr, h3, MTOK, DFFP, D_MODEL, D_MODEL, D_MODEL, DFFP);
    k_silu_mul<<<(MTOK*DFFP/8 + 255)/256, 256, 0, stream>>>(h1, h3, h1, MTOK*DFFP/8);
    k_gemm_bt<3><<<16*32, 256, 0, stream>>>(h1, w2t, nullptr, out, nullptr, out, MTOK, D_MODEL, DFF, DFFP, DFF, D_MODEL);
  }
}

// Round 17
// 650.226 us; speedup vs baseline: 1.0562x; 1.0085x over previous
//
#include <hip/hip_runtime.h>
#include <stdint.h>

typedef unsigned short u16;
typedef __bf16 bf16x8 __attribute__((ext_vector_type(8)));
typedef float f32x4 __attribute__((ext_vector_type(4)));

#define D_MODEL 2048
#define NHEADS 16
#define DK 128
#define DFF 5504
#define DFFP 5632
#define BB 2
#define SS 2048
#define MTOK 4096
#define DQKV 6144

#define AS1 __attribute__((address_space(1)))
#define AS3 __attribute__((address_space(3)))

__device__ __forceinline__ u16 f2bf(float f){
  union { float f; uint32_t u; } v; v.f = f;
  uint32_t r = v.u + 0x7fffu + ((v.u >> 16) & 1u);
  return (u16)(r >> 16);
}
__device__ __forceinline__ float bf2f(u16 u){
  union { uint32_t u; float f; } v; v.u = ((uint32_t)u) << 16;
  return v.f;
}
__device__ __forceinline__ u16 cvt_bf16(float f){
  union { __bf16 h; u16 u; } v; v.h = (__bf16)f; return v.u;
}
__device__ __forceinline__ float fexp2(float x){
#if __has_builtin(__builtin_amdgcn_exp2f)
  return __builtin_amdgcn_exp2f(x);
#else
  return exp2f(x);
#endif
}

// ---- fp32 W[K][Nsrc] -> bf16 Wt[n][K], zero-fill n >= Nsrc ----
__global__ __launch_bounds__(256) void k_transpose_w(const float* __restrict__ W,
                                                     u16* __restrict__ Wt, int K, int Nsrc){
  __shared__ float tile[32][33];
  int n0 = blockIdx.x * 32, k0 = blockIdx.y * 32;
  int tx = threadIdx.x, ty = threadIdx.y;
  #pragma unroll
  for (int r = 0; r < 4; ++r){
    int n = n0 + tx;
    tile[ty + r*8][tx] = (n < Nsrc) ? W[(size_t)(k0 + ty + r*8) * Nsrc + n] : 0.0f;
  }
  __syncthreads();
  #pragma unroll
  for (int r = 0; r < 4; ++r)
    Wt[(size_t)(n0 + ty + r*8) * K + k0 + tx] = f2bf(tile[tx][ty + r*8]);
}

// ---- batched 2048x2048 transpose: z selects among 4 matrices ----
__global__ __launch_bounds__(256) void k_transpose_w4(
    const float* __restrict__ w0s, const float* __restrict__ w1s,
    const float* __restrict__ w2s, const float* __restrict__ w3s,
    u16* __restrict__ d0, u16* __restrict__ d1,
    u16* __restrict__ d2, u16* __restrict__ d3){
  __shared__ float tile[32][33];
  const float* W = blockIdx.z == 0 ? w0s : blockIdx.z == 1 ? w1s : blockIdx.z == 2 ? w2s : w3s;
  u16* Wt = blockIdx.z == 0 ? d0 : blockIdx.z == 1 ? d1 : blockIdx.z == 2 ? d2 : d3;
  int n0 = blockIdx.x * 32, k0 = blockIdx.y * 32;
  int tx = threadIdx.x, ty = threadIdx.y;
  #pragma unroll
  for (int r = 0; r < 4; ++r)
    tile[ty + r*8][tx] = W[(size_t)(k0 + ty + r*8) * D_MODEL + n0 + tx];
  __syncthreads();
  #pragma unroll
  for (int r = 0; r < 4; ++r)
    Wt[(size_t)(n0 + ty + r*8) * D_MODEL + k0 + tx] = f2bf(tile[tx][ty + r*8]);
}

// ---- batched DFFP-row transpose: z=0 -> w1, z=1 -> w3 (zero-pad past DFF) ----
__global__ __launch_bounds__(256) void k_transpose_w13(
    const float* __restrict__ w1s, const float* __restrict__ w3s,
    u16* __restrict__ dst){
  __shared__ float tile[32][33];
  const float* W = blockIdx.z == 0 ? w1s : w3s;
  u16* Wt = dst + (size_t)blockIdx.z * DFFP * D_MODEL;
  int n0 = blockIdx.x * 32, k0 = blockIdx.y * 32;
  int tx = threadIdx.x, ty = threadIdx.y;
  #pragma unroll
  for (int r = 0; r < 4; ++r){
    int n = n0 + tx;
    tile[ty + r*8][tx] = (n < DFF) ? W[(size_t)(k0 + ty + r*8) * DFF + n] : 0.0f;
  }
  __syncthreads();
  #pragma unroll
  for (int r = 0; r < 4; ++r)
    Wt[(size_t)(n0 + ty + r*8) * D_MODEL + k0 + tx] = f2bf(tile[tx][ty + r*8]);
}

// ---- per-head V transpose from fused QKV ----
__global__ __launch_bounds__(256) void k_transpose_v(const u16* __restrict__ V,
                                                     u16* __restrict__ Vt, int ld){
  __shared__ u16 tile[32][33];
  int s0 = blockIdx.x * 32;
  int bh = blockIdx.y >> 2, dt = blockIdx.y & 3;
  int b = bh >> 4, h = bh & 15;
  int tx = threadIdx.x, ty = threadIdx.y;
  #pragma unroll
  for (int r = 0; r < 4; ++r)
    tile[ty + r*8][tx] = V[(size_t)(b*SS + s0 + ty + r*8) * ld + h*DK + dt*32 + tx];
  __syncthreads();
  #pragma unroll
  for (int r = 0; r < 4; ++r)
    Vt[(size_t)(bh*DK + dt*32 + ty + r*8) * SS + s0 + tx] = tile[tx][ty + r*8];
}

__global__ __launch_bounds__(256) void k_concat3(const float* __restrict__ a,
                                                 const float* __restrict__ b,
                                                 const float* __restrict__ c,
                                                 float* __restrict__ o){
  int i = blockIdx.x*256 + threadIdx.x;
  if (i >= DQKV) return;
  o[i] = (i < 2048) ? a[i] : (i < 4096 ? b[i-2048] : c[i-4096]);
}

// ---- RMSNorm: fp32 row -> bf16 row ----
__global__ __launch_bounds__(256) void k_rmsnorm(const float* __restrict__ X,
                                                 const float* __restrict__ g,
                                                 u16* __restrict__ out){
  int row = blockIdx.x, tid = threadIdx.x;
  const float* x = X + (size_t)row * D_MODEL;
  float4 a = ((const float4*)x)[tid*2];
  float4 b = ((const float4*)x)[tid*2+1];
  float ss = a.x*a.x + a.y*a.y + a.z*a.z + a.w*a.w
           + b.x*b.x + b.y*b.y + b.z*b.z + b.w*b.w;
  #pragma unroll
  for (int m = 1; m < 64; m <<= 1) ss += __shfl_xor(ss, m, 64);
  __shared__ float red[4];
  if ((tid & 63) == 0) red[tid >> 6] = ss;
  __syncthreads();
  float tot = red[0] + red[1] + red[2] + red[3];
  float sc = rsqrtf(tot * (1.0f / D_MODEL) + 1e-6f);
  float4 ga = ((const float4*)g)[tid*2];
  float4 gb = ((const float4*)g)[tid*2+1];
  uint32_t w0 = f2bf(a.x*sc*ga.x) | ((uint32_t)f2bf(a.y*sc*ga.y) << 16);
  uint32_t w1 = f2bf(a.z*sc*ga.z) | ((uint32_t)f2bf(a.w*sc*ga.w) << 16);
  uint32_t w2 = f2bf(b.x*sc*gb.x) | ((uint32_t)f2bf(b.y*sc*gb.y) << 16);
  uint32_t w3 = f2bf(b.z*sc*gb.z) | ((uint32_t)f2bf(b.w*sc*gb.w) << 16);
  ((uint4*)(out + (size_t)row * D_MODEL))[tid] = make_uint4(w0, w1, w2, w3);
}

// ---- fused: out = x + bias + p0 [+ p1] ; nrm = rmsnorm(out)*g (bf16) ----
__global__ __launch_bounds__(256) void k_addres_rms(
    const float* __restrict__ X, const float* __restrict__ bias,
    const float* __restrict__ p0, const float* __restrict__ p1,
    const float* __restrict__ g, float* __restrict__ out,
    u16* __restrict__ nrm){
  int row = blockIdx.x, tid = threadIdx.x;
  size_t base = (size_t)row * D_MODEL;
  float4 a  = ((const float4*)(X  + base))[tid*2];
  float4 b  = ((const float4*)(X  + base))[tid*2+1];
  float4 ba = ((const float4*)bias)[tid*2];
  float4 bb = ((const float4*)bias)[tid*2+1];
  float4 pa = ((const float4*)(p0 + base))[tid*2];
  float4 pb = ((const float4*)(p0 + base))[tid*2+1];
  a.x += ba.x + pa.x; a.y += ba.y + pa.y;
  a.z += ba.z + pa.z; a.w += ba.w + pa.w;
  b.x += bb.x + pb.x; b.y += bb.y + pb.y;
  b.z += bb.z + pb.z; b.w += bb.w + pb.w;
  if (p1){
    float4 qa = ((const float4*)(p1 + base))[tid*2];
    float4 qb = ((const float4*)(p1 + base))[tid*2+1];
    a.x += qa.x; a.y += qa.y; a.z += qa.z; a.w += qa.w;
    b.x += qb.x; b.y += qb.y; b.z += qb.z; b.w += qb.w;
  }
  ((float4*)(out + base))[tid*2]   = a;
  ((float4*)(out + base))[tid*2+1] = b;
  float ss = a.x*a.x + a.y*a.y + a.z*a.z + a.w*a.w
           + b.x*b.x + b.y*b.y + b.z*b.z + b.w*b.w;
  #pragma unroll
  for (int m = 1; m < 64; m <<= 1) ss += __shfl_xor(ss, m, 64);
  __shared__ float red[4];
  if ((tid & 63) == 0) red[tid >> 6] = ss;
  __syncthreads();
  float tot = red[0] + red[1] + red[2] + red[3];
  float sc = rsqrtf(tot * (1.0f / D_MODEL) + 1e-6f);
  float4 ga = ((const float4*)g)[tid*2];
  float4 gb = ((const float4*)g)[tid*2+1];
  uint32_t w0 = f2bf(a.x*sc*ga.x) | ((uint32_t)f2bf(a.y*sc*ga.y) << 16);
  uint32_t w1 = f2bf(a.z*sc*ga.z) | ((uint32_t)f2bf(a.w*sc*ga.w) << 16);
  uint32_t w2 = f2bf(b.x*sc*gb.x) | ((uint32_t)f2bf(b.y*sc*gb.y) << 16);
  uint32_t w3 = f2bf(b.z*sc*gb.z) | ((uint32_t)f2bf(b.w*sc*gb.w) << 16);
  ((uint4*)(nrm + base))[tid] = make_uint4(w0, w1, w2, w3);
}

// ---- hg = silu(h1) * h3 (bf16, 8 elems/thread) ----
__global__ __launch_bounds__(256) void k_silu_mul(const u16* __restrict__ a,
                                                  const u16* __restrict__ b,
                                                  u16* __restrict__ o, int n8){
  int i = blockIdx.x * 256 + threadIdx.x;
  if (i >= n8) return;
  uint4 av = ((const uint4*)a)[i];
  uint4 bv = ((const uint4*)b)[i];
  uint32_t aa[4] = {av.x, av.y, av.z, av.w};
  uint32_t bb[4] = {bv.x, bv.y, bv.z, bv.w};
  uint32_t rr[4];
  #pragma unroll
  for (int j = 0; j < 4; ++j){
    float x0 = bf2f((u16)(aa[j] & 0xffff)), x1 = bf2f((u16)(aa[j] >> 16));
    float y0 = bf2f((u16)(bb[j] & 0xffff)), y1 = bf2f((u16)(bb[j] >> 16));
    float r0 = x0 / (1.f + __expf(-x0)) * y0;
    float r1 = x1 / (1.f + __expf(-x1)) * y1;
    rr[j] = f2bf(r0) | ((uint32_t)f2bf(r1) << 16);
  }
  ((uint4*)o)[i] = make_uint4(rr[0], rr[1], rr[2], rr[3]);
}

// ============ 256x256 8-wave GEMM — 8-phase (r12-proven schedule) ============
// EPI 5: dual bf16 out (n0<5632 -> Cout, else aux-5632)
template<int EPI>
__global__ __launch_bounds__(512, 2) void k_gemm8p(
    const u16* __restrict__ A, const u16* __restrict__ Bt,
    const float* __restrict__ bias, const u16* __restrict__ aux,
    void* __restrict__ Cout, int M, int N, int K,
    int lda, int ldb, int ldc)
{
  extern __shared__ __align__(16) char smem[];
  const int tid = threadIdx.x;
  const int lane = tid & 63, wid = tid >> 6;
  const int wr = wid >> 2, wc = wid & 3;
  const int lrow = lane & 15, lhi = lane >> 4;

  int nwg = gridDim.x, wg = blockIdx.x;

  int nbx = N >> 8, nbm = M >> 8;
  int xcd = wg & 7, sub = wg >> 3;
  int m0, n0;
  if ((nwg & 7) == 0 && (nbm & 1) == 0 && (nbx & 3) == 0){
    int mh = nbm >> 1;
    int mr = sub % mh, nc = sub / mh;
    m0 = (((xcd & 1) * mh) + mr) << 8;
    n0 = (((xcd >> 1) * (nbx >> 2)) + nc) << 8;
  } else {
    int qq = nwg >> 3, rr2 = nwg & 7;
    int swz = (xcd < rr2 ? xcd*(qq+1) : rr2*(qq+1) + (xcd-rr2)*qq) + sub;
    m0 = (swz / nbx) << 8; n0 = (swz % nbx) << 8;
  }

  const int nk = K >> 6;
  const int hA = wr, hB = wc >> 1;
  const int gA = wc;
  const int gB = (wr << 1) | (wc & 1);

  const u16* aSrc[2][2]; int aDst[2][2];
  const u16* bSrc[2][2]; int bDst[2][2];
  #pragma unroll
  for (int q = 0; q < 2; ++q)
    #pragma unroll
    for (int L = 0; L < 2; ++L){
      int p = q*8192 + gA*2048 + L*1024 + lane*16;
      int row = p >> 7;
      int o = (p & 127) ^ ((row & 7) << 4);
      aSrc[q][L] = A + (size_t)(m0 + hA*128 + row)*lda + (o >> 1);
      aDst[q][L] = hA*16384 + p;
      int pb = q*4096 + (gB >> 1)*8192 + (gB & 1)*2048 + L*1024 + lane*16;
      int rowb = pb >> 7;
      int ob = (pb & 127) ^ ((rowb & 7) << 4);
      bSrc[q][L] = Bt + (size_t)(n0 + hB*128 + rowb)*ldb + (ob >> 1);
      bDst[q][L] = 32768 + hB*16384 + pb;
    }
  const int xo0 = (lhi*16) ^ ((lrow & 7) << 4);
  const int xo1 = (64 + lhi*16) ^ ((lrow & 7) << 4);

  auto stA = [&](int d, int kk, int q){
    #pragma unroll
    for (int L = 0; L < 2; ++L)
      __builtin_amdgcn_global_load_lds(
        (const AS1 void*)(aSrc[q][L] + kk),
        (AS3 void*)(smem + d*65536 + aDst[q][L]), 16, 0, 0);
  };
  auto stB = [&](int d, int kk, int s){
    #pragma unroll
    for (int L = 0; L < 2; ++L)
      __builtin_amdgcn_global_load_lds(
        (const AS1 void*)(bSrc[s][L] + kk),
        (AS3 void*)(smem + d*65536 + bDst[s][L]), 16, 0, 0);
  };
  auto rdA = [&](int d, int rloc, int ks)->bf16x8{
    return *(const bf16x8*)(smem + d*65536 + hA*16384 + rloc*128 + (ks ? xo1 : xo0));
  };
  auto rdB = [&](int d, int rloc, int ks)->bf16x8{
    return *(const bf16x8*)(smem + d*65536 + 32768 + hB*16384 + rloc*128 + (ks ? xo1 : xo0));
  };

  f32x4 acc[8][4] = {};

  stA(0, 0, 0); stB(0, 0, 0); stB(0, 0, 1); stA(0, 0, 1);
  asm volatile("s_waitcnt vmcnt(0)" ::: "memory");
  __builtin_amdgcn_s_barrier();

  for (int t = 0; t < nk; ++t){
    int d = t & 1, dn = d ^ 1, kkn = (t + 1) << 6;
    bool pf = (t + 1 < nk);
    bf16x8 aR[8], bQ0[4], bQ1[4];

    // ---- phase 0: Q00 ----
    #pragma unroll
    for (int ii = 0; ii < 4; ++ii){
      aR[ii*2]   = rdA(d, ii*16 + lrow, 0);
      aR[ii*2+1] = rdA(d, ii*16 + lrow, 1);
    }
    #pragma unroll
    for (int j = 0; j < 2; ++j){
      bQ0[j*2]   = rdB(d, (wc&1)*64 + j*16 + lrow, 0);
      bQ0[j*2+1] = rdB(d, (wc&1)*64 + j*16 + lrow, 1);
    }
    if (pf){ stA(dn, kkn, 0); stB(dn, kkn, 0); }
    __builtin_amdgcn_s_barrier();
    asm volatile("s_waitcnt lgkmcnt(0)" ::: "memory");
    __builtin_amdgcn_sched_barrier(0);
    __builtin_amdgcn_s_setprio(1);
    #pragma unroll
    for (int ii = 0; ii < 4; ++ii)
      #pragma unroll
      for (int j = 0; j < 2; ++j){
        acc[ii][j] = __builtin_amdgcn_mfma_f32_16x16x32_bf16(aR[ii*2],   bQ0[j*2],   acc[ii][j], 0, 0, 0);
        acc[ii][j] = __builtin_amdgcn_mfma_f32_16x16x32_bf16(aR[ii*2+1], bQ0[j*2+1], acc[ii][j], 0, 0, 0);
      }
    __builtin_amdgcn_s_setprio(0);
    if (pf) asm volatile("s_waitcnt vmcnt(6)" ::: "memory");
    else    asm volatile("s_waitcnt vmcnt(2)" ::: "memory");
    __builtin_amdgcn_sched_barrier(0);
    __builtin_amdgcn_s_barrier();

    // ---- phase 1: Q01 ----
    #pragma unroll
    for (int j = 0; j < 2; ++j){
      bQ1[j*2]   = rdB(d, (wc&1)*64 + 32 + j*16 + lrow, 0);
      bQ1[j*2+1] = rdB(d, (wc&1)*64 + 32 + j*16 + lrow, 1);
    }
    if (pf) stB(dn, kkn, 1);
    __builtin_amdgcn_s_barrier();
    asm volatile("s_waitcnt lgkmcnt(0)" ::: "memory");
    __builtin_amdgcn_sched_barrier(0);
    __builtin_amdgcn_s_setprio(1);
    #pragma unroll
    for (int ii = 0; ii < 4; ++ii)
      #pragma unroll
      for (int j = 0; j < 2; ++j){
        acc[ii][2+j] = __builtin_amdgcn_mfma_f32_16x16x32_bf16(aR[ii*2],   bQ1[j*2],   acc[ii][2+j], 0, 0, 0);
        acc[ii][2+j] = __builtin_amdgcn_mfma_f32_16x16x32_bf16(aR[ii*2+1], bQ1[j*2+1], acc[ii][2+j], 0, 0, 0);
      }
    __builtin_amdgcn_s_setprio(0);
    if (pf) asm volatile("s_waitcnt vmcnt(6)" ::: "memory");
    else    asm volatile("s_waitcnt vmcnt(0)" ::: "memory");
    __builtin_amdgcn_sched_barrier(0);
    __builtin_amdgcn_s_barrier();

    // ---- phase 2: Q11 ----
    #pragma unroll
    for (int ii = 0; ii < 4; ++ii){
      aR[ii*2]   = rdA(d, 64 + ii*16 + lrow, 0);
      aR[ii*2+1] = rdA(d, 64 + ii*16 + lrow, 1);
    }
    if (pf) stA(dn, kkn, 1);
    __builtin_amdgcn_s_barrier();
    asm volatile("s_waitcnt lgkmcnt(0)" ::: "memory");
    __builtin_amdgcn_sched_barrier(0);
    __builtin_amdgcn_s_setprio(1);
    #pragma unroll
    for (int ii = 0; ii < 4; ++ii)
      #pragma unroll
      for (int j = 0; j < 2; ++j){
        acc[4+ii][2+j] = __builtin_amdgcn_mfma_f32_16x16x32_bf16(aR[ii*2],   bQ1[j*2],   acc[4+ii][2+j], 0, 0, 0);
        acc[4+ii][2+j] = __builtin_amdgcn_mfma_f32_16x16x32_bf16(aR[ii*2+1], bQ1[j*2+1], acc[4+ii][2+j], 0, 0, 0);
      }
    __builtin_amdgcn_s_setprio(0);
    __builtin_amdgcn_s_barrier();

    // ---- phase 3: Q10 ----
    __builtin_amdgcn_s_setprio(1);
    #pragma unroll
    for (int ii = 0; ii < 4; ++ii)
      #pragma unroll
      for (int j = 0; j < 2; ++j){
        acc[4+ii][j] = __builtin_amdgcn_mfma_f32_16x16x32_bf16(aR[ii*2],   bQ0[j*2],   acc[4+ii][j], 0, 0, 0);
        acc[4+ii][j] = __builtin_amdgcn_mfma_f32_16x16x32_bf16(aR[ii*2+1], bQ0[j*2+1], acc[4+ii][j], 0, 0, 0);
      }
    __builtin_amdgcn_s_setprio(0);
    if (pf) asm volatile("s_waitcnt vmcnt(4)" ::: "memory");
    __builtin_amdgcn_sched_barrier(0);
    __builtin_amdgcn_s_barrier();
  }

  u16* Cw = (u16*)Cout;
  int cofs = 0;
  if constexpr (EPI == 5){
    if (n0 >= 5632){ Cw = (u16*)aux; cofs = 5632; }
  }
  #pragma unroll
  for (int i = 0; i < 8; ++i){
    #pragma unroll
    for (int j = 0; j < 4; ++j){
      int col = n0 + wc*64 + j*16 + lrow;
      float bv = 0.f;
      if constexpr (EPI == 0) bv = bias[col];
      #pragma unroll
      for (int q = 0; q < 4; ++q){
        int row = m0 + wr*128 + i*16 + lhi*4 + q;
        float v = acc[i][j][q] + bv;
        Cw[(size_t)row*ldc + (col - cofs)] = f2bf(v);
      }
    }
  }
}

// ============ 256Mx128N 8-wave GEMM — 2-phase, full-round grids ============
// EPI 8: fp32 out = acc + res; EPI 9: fp32 out = acc; EPI 10: bf16 out = acc + bias.
template<int EPI>
__global__ __launch_bounds__(512, 2) void k_gemm8pn(
    const u16* __restrict__ A, const u16* __restrict__ Bt,
    const float* __restrict__ bias, const float* __restrict__ res,
    void* __restrict__ Cout,
    int M, int N, int K, int lda, int ldb, int ldc)
{
  extern __shared__ __align__(16) char smem[];
  const int tid = threadIdx.x;
  const int lane = tid & 63, wid = tid >> 6;
  const int wr = wid >> 2, wc = wid & 3;
  const int lrow = lane & 15, lhi = lane >> 4;

  int nwg = gridDim.x, wg = blockIdx.x;
  int nbx = N >> 7, nbm = M >> 8;
  int xcd = wg & 7, sub = wg >> 3;
  int m0, n0;
  if ((nwg & 7) == 0 && (nbm & 1) == 0 && (nbx & 3) == 0){
    int mh = nbm >> 1;
    int mr = sub % mh, nc = sub / mh;
    m0 = (((xcd & 1) * mh) + mr) << 8;
    n0 = (((xcd >> 1) * (nbx >> 2)) + nc) << 7;
  } else {
    int qq = nwg >> 3, rr2 = nwg & 7;
    int swz = (xcd < rr2 ? xcd*(qq+1) : rr2*(qq+1) + (xcd-rr2)*qq) + sub;
    m0 = (swz / nbx) << 8; n0 = (swz % nbx) << 7;
  }

  const int nk = K >> 6;
  const int hA = wr;
  const int gA = wc;

  const u16* aSrc[2][2]; int aDst[2][2];
  #pragma unroll
  for (int q = 0; q < 2; ++q)
    #pragma unroll
    for (int L = 0; L < 2; ++L){
      int p = q*8192 + gA*2048 + L*1024 + lane*16;
      int row = p >> 7;
      int o = (p & 127) ^ ((row & 7) << 4);
      aSrc[q][L] = A + (size_t)(m0 + hA*128 + row)*lda + (o >> 1);
      aDst[q][L] = hA*16384 + p;
    }
  const u16* bSrc[2]; int bDst[2];
  #pragma unroll
  for (int s = 0; s < 2; ++s){
    int p = s*8192 + wid*1024 + lane*16;
    int row = p >> 7;
    int o = (p & 127) ^ ((row & 7) << 4);
    bSrc[s] = Bt + (size_t)(n0 + row)*ldb + (o >> 1);
    bDst[s] = 32768 + p;
  }
  const int xo0 = (lhi*16) ^ ((lrow & 7) << 4);
  const int xo1 = (64 + lhi*16) ^ ((lrow & 7) << 4);

  auto stA = [&](int d, int kk, int q){
    #pragma unroll
    for (int L = 0; L < 2; ++L)
      __builtin_amdgcn_global_load_lds(
        (const AS1 void*)(aSrc[q][L] + kk),
        (AS3 void*)(smem + d*49152 + aDst[q][L]), 16, 0, 0);
  };
  auto stB = [&](int d, int kk){
    #pragma unroll
    for (int s = 0; s < 2; ++s)
      __builtin_amdgcn_global_load_lds(
        (const AS1 void*)(bSrc[s] + kk),
        (AS3 void*)(smem + d*49152 + bDst[s]), 16, 0, 0);
  };
  auto rdA = [&](int d, int rloc, int ks)->bf16x8{
    return *(const bf16x8*)(smem + d*49152 + hA*16384 + rloc*128 + (ks ? xo1 : xo0));
  };
  auto rdB = [&](int d, int rloc, int ks)->bf16x8{
    return *(const bf16x8*)(smem + d*49152 + 32768 + rloc*128 + (ks ? xo1 : xo0));
  };

  f32x4 acc[8][2] = {};

  stA(0, 0, 0); stB(0, 0); stA(0, 0, 1);
  asm volatile("s_waitcnt vmcnt(0)" ::: "memory");
  __builtin_amdgcn_s_barrier();

  for (int t = 0; t < nk; ++t){
    int d = t & 1, dn = d ^ 1, kkn = (t + 1) << 6;
    bool pf = (t + 1 < nk);
    bf16x8 aR[8], bQ[4];

    // ---- phase 0: rows 0-63 ----
    #pragma unroll
    for (int ii = 0; ii < 4; ++ii){
      aR[ii*2]   = rdA(d, ii*16 + lrow, 0);
      aR[ii*2+1] = rdA(d, ii*16 + lrow, 1);
    }
    #pragma unroll
    for (int j = 0; j < 2; ++j){
      bQ[j*2]   = rdB(d, wc*32 + j*16 + lrow, 0);
      bQ[j*2+1] = rdB(d, wc*32 + j*16 + lrow, 1);
    }
    if (pf){ stA(dn, kkn, 0); stB(dn, kkn); }
    __builtin_amdgcn_s_barrier();
    asm volatile("s_waitcnt lgkmcnt(0)" ::: "memory");
    __builtin_amdgcn_sched_barrier(0);
    __builtin_amdgcn_s_setprio(1);
    #pragma unroll
    for (int ii = 0; ii < 4; ++ii)
      #pragma unroll
      for (int j = 0; j < 2; ++j){
        acc[ii][j] = __builtin_amdgcn_mfma_f32_16x16x32_bf16(aR[ii*2],   bQ[j*2],   acc[ii][j], 0, 0, 0);
        acc[ii][j] = __builtin_amdgcn_mfma_f32_16x16x32_bf16(aR[ii*2+1], bQ[j*2+1], acc[ii][j], 0, 0, 0);
      }
    __builtin_amdgcn_s_setprio(0);
    if (pf) asm volatile("s_waitcnt vmcnt(4)" ::: "memory");
    else    asm volatile("s_waitcnt vmcnt(0)" ::: "memory");
    __builtin_amdgcn_sched_barrier(0);
    __builtin_amdgcn_s_barrier();

    // ---- phase 1: rows 64-127 (reuse bQ) ----
    #pragma unroll
    for (int ii = 0; ii < 4; ++ii){
      aR[ii*2]   = rdA(d, 64 + ii*16 + lrow, 0);
      aR[ii*2+1] = rdA(d, 64 + ii*16 + lrow, 1);
    }
    if (pf) stA(dn, kkn, 1);
    __builtin_amdgcn_s_barrier();
    asm volatile("s_waitcnt lgkmcnt(0)" ::: "memory");
    __builtin_amdgcn_sched_barrier(0);
    __builtin_amdgcn_s_setprio(1);
    #pragma unroll
    for (int ii = 0; ii < 4; ++ii)
      #pragma unroll
      for (int j = 0; j < 2; ++j){
        acc[4+ii][j] = __builtin_amdgcn_mfma_f32_16x16x32_bf16(aR[ii*2],   bQ[j*2],   acc[4+ii][j], 0, 0, 0);
        acc[4+ii][j] = __builtin_amdgcn_mfma_f32_16x16x32_bf16(aR[ii*2+1], bQ[j*2+1], acc[4+ii][j], 0, 0, 0);
      }
    __builtin_amdgcn_s_setprio(0);
    if (pf) asm volatile("s_waitcnt vmcnt(2)" ::: "memory");
    else    asm volatile("s_waitcnt vmcnt(0)" ::: "memory");
    __builtin_amdgcn_sched_barrier(0);
    __builtin_amdgcn_s_barrier();
  }

  #pragma unroll
  for (int i = 0; i < 8; ++i){
    #pragma unroll
    for (int j = 0; j < 2; ++j){
      int col = n0 + wc*32 + j*16 + lrow;
      #pragma unroll
      for (int q = 0; q < 4; ++q){
        int row = m0 + wr*128 + i*16 + lhi*4 + q;
        size_t idx = (size_t)row*ldc + col;
        if constexpr (EPI == 10){
          ((u16*)Cout)[idx] = f2bf(acc[i][j][q] + bias[col]);
        } else {
          float v = acc[i][j][q];
          if constexpr (EPI == 8) v += res[idx];
          ((float*)Cout)[idx] = v;
        }
      }
    }
  }
}

// ---- 128x128 GEMM (3-buffer counted vmcnt, row&3 chunk swizzle) — fallback ----
template<int EPI>
__global__ __launch_bounds__(256) void k_gemm_bt(
    const u16* __restrict__ A, const u16* __restrict__ Bt,
    const float* __restrict__ bias, const float* __restrict__ res,
    const u16* __restrict__ aux,
    void* __restrict__ Cout, int M, int N, int K,
    int lda, int ldb, int ldc)
{
  __shared__ __align__(16) u16 As[3][128*32];
  __shared__ __align__(16) u16 Bs[3][128*32];
  int tid = threadIdx.x;

  int nwg = gridDim.x, wg = blockIdx.x;
  int qq = nwg >> 3, rr = nwg & 7;
  int xcd = wg & 7, sub = wg >> 3;
  int swz = (xcd < rr ? xcd*(qq+1) : rr*(qq+1) + (xcd-rr)*qq) + sub;
  int nbx = N >> 7;
  int m0 = (swz / nbx) << 7, n0 = (swz % nbx) << 7;

  int lane = tid & 63, wave = tid >> 6;
  int wr = wave >> 1, wc = wave & 1;
  int lrow = lane & 15, lhi = lane >> 4;
  f32x4 acc[4][4] = {};
  int srow = tid >> 2;
  int schk = tid & 3;
  const int nk = K >> 5;

  auto stage = [&](int slot, int kt){
    int k0 = kt << 5;
    int c = schk ^ (srow & 3);
    #pragma unroll
    for (int cc = 0; cc < 2; ++cc){
      int r = cc*64 + srow;
      __builtin_amdgcn_global_load_lds(
        (const AS1 void*)(A + (size_t)(m0 + r)*lda + k0 + c*8),
        (AS3 void*)(&As[slot][r*32 + schk*8]), 16, 0, 0);
      __builtin_amdgcn_global_load_lds(
        (const AS1 void*)(Bt + (size_t)(n0 + r)*ldb + k0 + c*8),
        (AS3 void*)(&Bs[slot][r*32 + schk*8]), 16, 0, 0);
    }
  };

  stage(0, 0);
  if (nk > 1) stage(1, 1);
  if (nk > 1) asm volatile("s_waitcnt vmcnt(4)" ::: "memory");
  else        asm volatile("s_waitcnt vmcnt(0)" ::: "memory");
  __builtin_amdgcn_s_barrier();

  for (int kt = 0; kt < nk; ++kt){
    int cur = kt % 3;
    if (kt + 2 < nk) stage((kt + 2) % 3, kt + 2);
    int rchk = lhi ^ (lrow & 3);
    bf16x8 af[4], bfv[4];
    #pragma unroll
    for (int i = 0; i < 4; ++i){
      af[i]  = *(const bf16x8*)(&As[cur][(wr*64 + i*16 + lrow)*32 + rchk*8]);
      bfv[i] = *(const bf16x8*)(&Bs[cur][(wc*64 + i*16 + lrow)*32 + rchk*8]);
    }
    #pragma unroll
    for (int i = 0; i < 4; ++i)
      #pragma unroll
      for (int j = 0; j < 4; ++j)
        acc[i][j] = __builtin_amdgcn_mfma_f32_16x16x32_bf16(af[i], bfv[j], acc[i][j], 0, 0, 0);
    if (kt + 2 < nk) asm volatile("s_waitcnt vmcnt(4)" ::: "memory");
    else             asm volatile("s_waitcnt vmcnt(0)" ::: "memory");
    __builtin_amdgcn_s_barrier();
  }

  #pragma unroll
  for (int i = 0; i < 4; ++i){
    #pragma unroll
    for (int j = 0; j < 4; ++j){
      int col = n0 + wc*64 + j*16 + lrow;
      float bv = 0.f;
      if constexpr (EPI == 0 || EPI == 1) bv = bias[col];
      #pragma unroll
      for (int q = 0; q < 4; ++q){
        int row = m0 + wr*64 + i*16 + lhi*4 + q;
        size_t idx = (size_t)row*ldc + col;
        float v = acc[i][j][q] + bv;
        if constexpr (EPI == 1 || EPI == 3) v += res[idx];
        if constexpr (EPI == 4){
          float a0 = bf2f(aux[idx]);
          v = a0 / (1.f + __expf(-a0)) * v;
        }
        if constexpr (EPI == 0 || EPI == 2 || EPI == 4) ((u16*)Cout)[idx] = f2bf(v);
        else ((float*)Cout)[idx] = v;
      }
    }
  }
}

// ---- causal flash attention: paired-qblock load balancing (unchanged) ----
__global__ __launch_bounds__(512) void k_attn(
    const u16* __restrict__ Q, const u16* __restrict__ Kb,
    const u16* __restrict__ Vt, u16* __restrict__ O, int ldq)
{
  int tid = threadIdx.x, lane = tid & 63, wave = tid >> 6;
  int lrow = lane & 15, lhi = lane >> 4;
  int bidx = blockIdx.x;
  int bh = bidx >> 3, j = bidx & 7;
  int b = bh >> 4, h = bh & 15;

  __shared__ __align__(16) u16 Kbuf[2][64*128];
  __shared__ __align__(16) u16 Vbuf[2][128*64];
  __shared__ __align__(16) u16 P_lds[8][16*64];
  char* pw = (char*)&P_lds[wave][0];
  const float sc2 = 0.08838834764831845f * 1.44269504088896340736f;

  auto stage = [&](int bufi, int kt){
    int kv0 = kt << 6;
    char* kd = (char*)&Kbuf[bufi][0];
    char* vd = (char*)&Vbuf[bufi][0];
    #pragma unroll
    for (int L = 0; L < 2; ++L){
      int cid = wave*128 + L*64 + lane;
      int r = cid >> 4, c = cid & 15;
      int cg = c ^ (r & 7);
      __builtin_amdgcn_global_load_lds(
        (const AS1 void*)(Kb + (size_t)(b*SS + kv0 + r)*ldq + h*DK + cg*8),
        (AS3 void*)(kd + wave*2048 + L*1024 + lane*16), 16, 0, 0);
      int dd = cid >> 3, c8 = cid & 7;
      int cv = c8 ^ (dd & 7);
      __builtin_amdgcn_global_load_lds(
        (const AS1 void*)(Vt + (size_t)bh*DK*SS + (size_t)dd*SS + kv0 + cv*8),
        (AS3 void*)(vd + wave*2048 + L*1024 + lane*16), 16, 0, 0);
    }
  };

  #pragma unroll 1
  for (int item = 0; item < 2; ++item){
    int qi = item == 0 ? 15 - j : j;
    int qs = qi * 128;
    int nt = 2*qi + 2;
    int qrow = qs + wave * 16;

    bf16x8 qf[4];
    const u16* qbase = Q + (size_t)(b*SS + qrow + lrow)*ldq + h*DK + lhi*8;
    #pragma unroll
    for (int dc = 0; dc < 4; ++dc) qf[dc] = *(const bf16x8*)(qbase + dc*32);

    f32x4 accO[8] = {};
    float mr[4] = {-1e30f,-1e30f,-1e30f,-1e30f};
    float lr[4] = {0.f,0.f,0.f,0.f};

    stage(0, 0);
    __syncthreads();

    for (int kt = 0; kt < nt; ++kt){
      int cur = kt & 1;
      if (kt + 1 < nt) stage(cur ^ 1, kt + 1);
      int kv0 = kt << 6;
      if (kv0 <= qrow + 15){
        const char* kl = (const char*)&Kbuf[cur][0];
        const char* vl = (const char*)&Vbuf[cur][0];
        bool domask = (kv0 + 63 > qrow);

        f32x4 sf[4];
        #pragma unroll
        for (int hf = 0; hf < 4; ++hf){
          int rl = hf*16 + lrow;
          int sw = rl & 7;
          f32x4 a = {};
          #pragma unroll
          for (int dc = 0; dc < 4; ++dc){
            bf16x8 kf = *(const bf16x8*)(kl + rl*256 + (((lhi + dc*4) ^ sw) << 4));
            a = __builtin_amdgcn_mfma_f32_16x16x32_bf16(qf[dc], kf, a, 0, 0, 0);
          }
          sf[hf] = a;
        }

        float p[4][4], mx[4];
        #pragma unroll
        for (int q = 0; q < 4; ++q){
          float s0 = sf[0][q]*sc2, s1 = sf[1][q]*sc2, s2 = sf[2][q]*sc2, s3 = sf[3][q]*sc2;
          if (domask){
            int qg = qrow + lhi*4 + q;
            if (kv0      + lrow > qg) s0 = -1e30f;
            if (kv0 + 16 + lrow > qg) s1 = -1e30f;
            if (kv0 + 32 + lrow > qg) s2 = -1e30f;
            if (kv0 + 48 + lrow > qg) s3 = -1e30f;
          }
          p[q][0]=s0; p[q][1]=s1; p[q][2]=s2; p[q][3]=s3;
          float m = fmaxf(fmaxf(s0,s1), fmaxf(s2,s3));
          m = fmaxf(m, __shfl_xor(m, 1, 64));
          m = fmaxf(m, __shfl_xor(m, 2, 64));
          m = fmaxf(m, __shfl_xor(m, 4, 64));
          m = fmaxf(m, __shfl_xor(m, 8, 64));
          mx[q] = m;
        }
        float dmax = fmaxf(fmaxf(mx[0]-mr[0], mx[1]-mr[1]), fmaxf(mx[2]-mr[2], mx[3]-mr[3]));
        bool rescale = !__all(dmax <= 8.0f);
        float al[4];
        #pragma unroll
        for (int q = 0; q < 4; ++q){
          if (rescale){
            float mn = fmaxf(mr[q], mx[q]);
            al[q] = fexp2(mr[q] - mn);
            mr[q] = mn;
          } else al[q] = 1.0f;
          p[q][0] = fexp2(p[q][0] - mr[q]);
          p[q][1] = fexp2(p[q][1] - mr[q]);
          p[q][2] = fexp2(p[q][2] - mr[q]);
          p[q][3] = fexp2(p[q][3] - mr[q]);
          float sm = (p[q][0] + p[q][1]) + (p[q][2] + p[q][3]);
          sm += __shfl_xor(sm, 1, 64);
          sm += __shfl_xor(sm, 2, 64);
          sm += __shfl_xor(sm, 4, 64);
          sm += __shfl_xor(sm, 8, 64);
          lr[q] = lr[q]*al[q] + sm;
        }
        if (rescale){
          #pragma unroll
          for (int f = 0; f < 8; ++f)
            #pragma unroll
            for (int q = 0; q < 4; ++q) accO[f][q] *= al[q];
        }

        #pragma unroll
        for (int q = 0; q < 4; ++q){
          int row = lhi*4 + q;
          int rb = row*128, sw = (row & 7) << 4;
          #pragma unroll
          for (int hf = 0; hf < 4; ++hf)
            *(u16*)(pw + rb + ((hf*32 + lrow*2) ^ sw)) = cvt_bf16(p[q][hf]);
        }
        __builtin_amdgcn_sched_barrier(0);
        int rsw = (lrow & 7) << 4;
        bf16x8 pa0 = *(const bf16x8*)(pw + lrow*128 + ((     lhi*16) ^ rsw));
        bf16x8 pa1 = *(const bf16x8*)(pw + lrow*128 + ((64 + lhi*16) ^ rsw));

        #pragma unroll
        for (int f = 0; f < 8; ++f){
          int d = f*16 + lrow;
          int swv = d & 7;
          bf16x8 v0 = *(const bf16x8*)(vl + d*128 + (((lhi    ) ^ swv) << 4));
          bf16x8 v1 = *(const bf16x8*)(vl + d*128 + (((lhi + 4) ^ swv) << 4));
          accO[f] = __builtin_amdgcn_mfma_f32_16x16x32_bf16(pa0, v0, accO[f], 0, 0, 0);
          accO[f] = __builtin_amdgcn_mfma_f32_16x16x32_bf16(pa1, v1, accO[f], 0, 0, 0);
        }
      }
      __syncthreads();
    }

    #pragma unroll
    for (int q = 0; q < 4; ++q){
      float inv = 1.0f / lr[q];
      #pragma unroll
      for (int f = 0; f < 8; ++f){
        int row = b*SS + qrow + lhi*4 + q;
        int col = h*DK + f*16 + lrow;
        O[(size_t)row*D_MODEL + col] = cvt_bf16(accO[f][q] * inv);
      }
    }
    __syncthreads();
  }
}

extern "C" void kernel_launch(void* const* d_in, const int* in_sizes, int n_in,
                              void* d_out, int out_size, void* d_ws, size_t ws_size,
                              hipStream_t stream)
{
  (void)in_sizes; (void)n_in; (void)out_size;
  const float* x  = (const float*)d_in[0];
  const float* wq = (const float*)d_in[2];
  const float* bq = (const float*)d_in[3];
  const float* wk = (const float*)d_in[4];
  const float* bk = (const float*)d_in[5];
  const float* wv = (const float*)d_in[6];
  const float* bv = (const float*)d_in[7];
  const float* wo = (const float*)d_in[8];
  const float* bo = (const float*)d_in[9];
  const float* g1 = (const float*)d_in[10];
  const float* g2 = (const float*)d_in[11];
  const float* w1 = (const float*)d_in[12];
  const float* w3 = (const float*)d_in[13];
  const float* w2 = (const float*)d_in[14];
  float* out = (float*)d_out;

  const size_t MB = 1u << 20;
  const size_t W2T_B = (size_t)D_MODEL * DFF * sizeof(u16);
  const size_t NEED = 152*MB + W2T_B + 32768;
  if (ws_size < NEED) return;
  char* ws = (char*)d_ws;
  u16* bufA  = (u16*)(ws + 0);        // 16 MiB: nbf1 -> aob -> nbf2
  u16* qkv   = (u16*)(ws + 16*MB);    // 48 MiB fused QKV [4096][6144]
  u16* h1    = qkv;                   // [4096][5632], aliases after attn
  u16* wqkvt = (u16*)(ws + 64*MB);    // 24 MiB, dead after QKV GEMM
  u16* w1w3t = (u16*)(ws + 64*MB);    // [11264][2048] (64-108)
  u16* wot   = (u16*)(ws + 88*MB);    // 8 MiB (w1w3 transpose AFTER O-proj)
  u16* vtb   = (u16*)(ws + 96*MB);    // 16 MiB (dead after attn)
  u16* h3    = (u16*)(ws + 108*MB);   // [4096][5632] (108-152)
  float* p0o = (float*)(ws + 16*MB);  // O-proj partial: qkv dead after attn
  u16* w2t   = (u16*)(ws + 152*MB);
  float* bqkv = (float*)(ws + 152*MB + W2T_B);
  // fp32 residual x1 lives in d_out

  bool big = true;
  big &= hipFuncSetAttribute((const void*)k_gemm8p<5>,  hipFuncAttributeMaxDynamicSharedMemorySize, 131072) == hipSuccess;
  big &= hipFuncSetAttribute((const void*)k_gemm8pn<8>, hipFuncAttributeMaxDynamicSharedMemorySize, 98304) == hipSuccess;
  big &= hipFuncSetAttribute((const void*)k_gemm8pn<9>, hipFuncAttributeMaxDynamicSharedMemorySize, 98304) == hipSuccess;
  big &= hipFuncSetAttribute((const void*)k_gemm8pn<10>, hipFuncAttributeMaxDynamicSharedMemorySize, 98304) == hipSuccess;

  dim3 tb(32, 8);
  k_transpose_w4<<<dim3(64,64,4), tb, 0, stream>>>(wq, wk, wv, wo,
      wqkvt, wqkvt + 2048*2048, wqkvt + 2*2048*2048, wot);
  k_transpose_w<<<dim3(64, DFF/32), tb, 0, stream>>>(w2, w2t, DFF, D_MODEL);
  k_concat3<<<24, 256, 0, stream>>>(bq, bk, bv, bqkv);

  k_rmsnorm<<<MTOK, 256, 0, stream>>>(x, g1, bufA);
  if (big){
    // QKV: 256Mx128N, 768 blocks = 3 full rounds (100% packing), bf16 + bias
    k_gemm8pn<10><<<(MTOK/256)*(DQKV/128), 512, 98304, stream>>>(bufA, wqkvt, bqkv, nullptr, qkv, MTOK, DQKV, D_MODEL, D_MODEL, D_MODEL, DQKV);
    k_transpose_v<<<dim3(SS/32, 128), tb, 0, stream>>>(qkv + 4096, vtb, DQKV);
    k_attn<<<dim3(BB*NHEADS*8), 512, 0, stream>>>(qkv, qkv + 2048, vtb, bufA, DQKV);
    // O-proj: 256Mx128N, 256 blocks -> single fp32 partial
    k_gemm8pn<9><<<(MTOK/256)*(D_MODEL/128), 512, 98304, stream>>>(bufA, wot, nullptr, nullptr, p0o, MTOK, D_MODEL, D_MODEL, D_MODEL, D_MODEL, D_MODEL);
    // w1|w3 -> w1w3t (dead wqkvt + wot + vtb): after O-proj & attn
    k_transpose_w13<<<dim3(DFFP/32, 64, 2), tb, 0, stream>>>(w1, w3, w1w3t);
    k_addres_rms<<<MTOK, 256, 0, stream>>>(x, bo, p0o, nullptr, g2, out, bufA);
    // combined W1|W3: N=11264, dual output h1/h3, ldc=DFFP
    k_gemm8p<5><<<(MTOK/256)*((2*DFFP)/256), 512, 131072, stream>>>(bufA, w1w3t, nullptr, h3, h1, MTOK, 2*DFFP, D_MODEL, D_MODEL, D_MODEL, DFFP);
    k_silu_mul<<<(MTOK*DFFP/8 + 255)/256, 256, 0, stream>>>(h1, h3, h1, MTOK*DFFP/8);
    // W2: 256Mx128N, 256 blocks, fused residual -> final out
    k_gemm8pn<8><<<(MTOK/256)*(D_MODEL/128), 512, 98304, stream>>>(h1, w2t, nullptr, out, out, MTOK, D_MODEL, DFF, DFFP, DFF, D_MODEL);
  } else {
    k_gemm_bt<0><<<(DQKV/128)*(MTOK/128), 256, 0, stream>>>(bufA, wqkvt, bqkv, nullptr, nullptr, qkv, MTOK, DQKV, D_MODEL, D_MODEL, D_MODEL, DQKV);
    k_transpose_v<<<dim3(SS/32, 128), tb, 0, stream>>>(qkv + 4096, vtb, DQKV);
    k_transpose_w13<<<dim3(DFFP/32, 64, 2), tb, 0, stream>>>(w1, w3, w1w3t);
    k_attn<<<dim3(BB*NHEADS*8), 512, 0, stream>>>(qkv, qkv + 2048, vtb, bufA, DQKV);
    k_gemm_bt<1><<<16*32, 256, 0, stream>>>(bufA, wot, bo, x, nullptr, out, MTOK, D_MODEL, D_MODEL, D_MODEL, D_MODEL, D_MODEL);
    k_rmsnorm<<<MTOK, 256, 0, stream>>>(out, g2, bufA);
    k_gemm_bt<2><<<(DFFP/128)*32, 256, 0, stream>>>(bufA, w1w3t, nullptr, nullptr, nullptr, h1, MTOK, DFFP, D_MODEL, D_MODEL, D_MODEL, DFFP);
    k_gemm_bt<2><<<(DFFP/128)*32, 256, 0, stream>>>(bufA, w1w3t + (size_t)DFFP*2048, nullptr, nullptr, nullptr, h3, MTOK, DFFP, D_MODEL, D_MODEL, D_MODEL, DFFP);
    k_silu_mul<<<(MTOK*DFFP/8 + 255)/256, 256, 0, stream>>>(h1, h3, h1, MTOK*DFFP/8);
    k_gemm_bt<3><<<16*32, 256, 0, stream>>>(h1, w2t, nullptr, out, nullptr, out, MTOK, D_MODEL, DFF, DFFP, DFF, D_MODEL);
  }
}

// Round 18
// 640.219 us; speedup vs baseline: 1.0727x; 1.0156x over previous
//
#include <hip/hip_runtime.h>
#include <stdint.h>

typedef unsigned short u16;
typedef __bf16 bf16x8 __attribute__((ext_vector_type(8)));
typedef float f32x4 __attribute__((ext_vector_type(4)));

#define D_MODEL 2048
#define NHEADS 16
#define DK 128
#define DFF 5504
#define DFFP 5632
#define BB 2
#define SS 2048
#define MTOK 4096
#define DQKV 6144

#define AS1 __attribute__((address_space(1)))
#define AS3 __attribute__((address_space(3)))

__device__ __forceinline__ u16 f2bf(float f){
  union { float f; uint32_t u; } v; v.f = f;
  uint32_t r = v.u + 0x7fffu + ((v.u >> 16) & 1u);
  return (u16)(r >> 16);
}
__device__ __forceinline__ float bf2f(u16 u){
  union { uint32_t u; float f; } v; v.u = ((uint32_t)u) << 16;
  return v.f;
}
__device__ __forceinline__ u16 cvt_bf16(float f){
  union { __bf16 h; u16 u; } v; v.h = (__bf16)f; return v.u;
}
__device__ __forceinline__ float fexp2(float x){
#if __has_builtin(__builtin_amdgcn_exp2f)
  return __builtin_amdgcn_exp2f(x);
#else
  return exp2f(x);
#endif
}

// ---- fp32 W[K][Nsrc] -> bf16 Wt[n][K], zero-fill n >= Nsrc ----
__global__ __launch_bounds__(256) void k_transpose_w(const float* __restrict__ W,
                                                     u16* __restrict__ Wt, int K, int Nsrc){
  __shared__ float tile[32][33];
  int n0 = blockIdx.x * 32, k0 = blockIdx.y * 32;
  int tx = threadIdx.x, ty = threadIdx.y;
  #pragma unroll
  for (int r = 0; r < 4; ++r){
    int n = n0 + tx;
    tile[ty + r*8][tx] = (n < Nsrc) ? W[(size_t)(k0 + ty + r*8) * Nsrc + n] : 0.0f;
  }
  __syncthreads();
  #pragma unroll
  for (int r = 0; r < 4; ++r)
    Wt[(size_t)(n0 + ty + r*8) * K + k0 + tx] = f2bf(tile[tx][ty + r*8]);
}

// ---- batched 2048x2048 transpose: z selects among 4 matrices ----
__global__ __launch_bounds__(256) void k_transpose_w4(
    const float* __restrict__ w0s, const float* __restrict__ w1s,
    const float* __restrict__ w2s, const float* __restrict__ w3s,
    u16* __restrict__ d0, u16* __restrict__ d1,
    u16* __restrict__ d2, u16* __restrict__ d3){
  __shared__ float tile[32][33];
  const float* W = blockIdx.z == 0 ? w0s : blockIdx.z == 1 ? w1s : blockIdx.z == 2 ? w2s : w3s;
  u16* Wt = blockIdx.z == 0 ? d0 : blockIdx.z == 1 ? d1 : blockIdx.z == 2 ? d2 : d3;
  int n0 = blockIdx.x * 32, k0 = blockIdx.y * 32;
  int tx = threadIdx.x, ty = threadIdx.y;
  #pragma unroll
  for (int r = 0; r < 4; ++r)
    tile[ty + r*8][tx] = W[(size_t)(k0 + ty + r*8) * D_MODEL + n0 + tx];
  __syncthreads();
  #pragma unroll
  for (int r = 0; r < 4; ++r)
    Wt[(size_t)(n0 + ty + r*8) * D_MODEL + k0 + tx] = f2bf(tile[tx][ty + r*8]);
}

// ---- interleaved w1|w3 transpose: w1 col r -> phys row (r>>7)*256+(r&127); w3 -> +128 ----
__global__ __launch_bounds__(256) void k_transpose_w13i(
    const float* __restrict__ w1s, const float* __restrict__ w3s,
    u16* __restrict__ dst){
  __shared__ float tile[32][33];
  const float* W = blockIdx.z == 0 ? w1s : w3s;
  int half = blockIdx.z << 7;
  int n0 = blockIdx.x * 32, k0 = blockIdx.y * 32;
  int tx = threadIdx.x, ty = threadIdx.y;
  #pragma unroll
  for (int r = 0; r < 4; ++r){
    int n = n0 + tx;
    tile[ty + r*8][tx] = (n < DFF) ? W[(size_t)(k0 + ty + r*8) * DFF + n] : 0.0f;
  }
  __syncthreads();
  #pragma unroll
  for (int r = 0; r < 4; ++r){
    int nr = n0 + ty + r*8;
    int pr = ((nr >> 7) << 8) + half + (nr & 127);
    dst[(size_t)pr * D_MODEL + k0 + tx] = f2bf(tile[tx][ty + r*8]);
  }
}

// ---- per-head V transpose from fused QKV ----
__global__ __launch_bounds__(256) void k_transpose_v(const u16* __restrict__ V,
                                                     u16* __restrict__ Vt, int ld){
  __shared__ u16 tile[32][33];
  int s0 = blockIdx.x * 32;
  int bh = blockIdx.y >> 2, dt = blockIdx.y & 3;
  int b = bh >> 4, h = bh & 15;
  int tx = threadIdx.x, ty = threadIdx.y;
  #pragma unroll
  for (int r = 0; r < 4; ++r)
    tile[ty + r*8][tx] = V[(size_t)(b*SS + s0 + ty + r*8) * ld + h*DK + dt*32 + tx];
  __syncthreads();
  #pragma unroll
  for (int r = 0; r < 4; ++r)
    Vt[(size_t)(bh*DK + dt*32 + ty + r*8) * SS + s0 + tx] = tile[tx][ty + r*8];
}

__global__ __launch_bounds__(256) void k_concat3(const float* __restrict__ a,
                                                 const float* __restrict__ b,
                                                 const float* __restrict__ c,
                                                 float* __restrict__ o){
  int i = blockIdx.x*256 + threadIdx.x;
  if (i >= DQKV) return;
  o[i] = (i < 2048) ? a[i] : (i < 4096 ? b[i-2048] : c[i-4096]);
}

// ---- RMSNorm: fp32 row -> bf16 row ----
__global__ __launch_bounds__(256) void k_rmsnorm(const float* __restrict__ X,
                                                 const float* __restrict__ g,
                                                 u16* __restrict__ out){
  int row = blockIdx.x, tid = threadIdx.x;
  const float* x = X + (size_t)row * D_MODEL;
  float4 a = ((const float4*)x)[tid*2];
  float4 b = ((const float4*)x)[tid*2+1];
  float ss = a.x*a.x + a.y*a.y + a.z*a.z + a.w*a.w
           + b.x*b.x + b.y*b.y + b.z*b.z + b.w*b.w;
  #pragma unroll
  for (int m = 1; m < 64; m <<= 1) ss += __shfl_xor(ss, m, 64);
  __shared__ float red[4];
  if ((tid & 63) == 0) red[tid >> 6] = ss;
  __syncthreads();
  float tot = red[0] + red[1] + red[2] + red[3];
  float sc = rsqrtf(tot * (1.0f / D_MODEL) + 1e-6f);
  float4 ga = ((const float4*)g)[tid*2];
  float4 gb = ((const float4*)g)[tid*2+1];
  uint32_t w0 = f2bf(a.x*sc*ga.x) | ((uint32_t)f2bf(a.y*sc*ga.y) << 16);
  uint32_t w1 = f2bf(a.z*sc*ga.z) | ((uint32_t)f2bf(a.w*sc*ga.w) << 16);
  uint32_t w2 = f2bf(b.x*sc*gb.x) | ((uint32_t)f2bf(b.y*sc*gb.y) << 16);
  uint32_t w3 = f2bf(b.z*sc*gb.z) | ((uint32_t)f2bf(b.w*sc*gb.w) << 16);
  ((uint4*)(out + (size_t)row * D_MODEL))[tid] = make_uint4(w0, w1, w2, w3);
}

// ---- fused: out = x + bias + p0 ; nrm = rmsnorm(out)*g (bf16) ----
__global__ __launch_bounds__(256) void k_addres_rms(
    const float* __restrict__ X, const float* __restrict__ bias,
    const float* __restrict__ p0, const float* __restrict__ g,
    float* __restrict__ out, u16* __restrict__ nrm){
  int row = blockIdx.x, tid = threadIdx.x;
  size_t base = (size_t)row * D_MODEL;
  float4 a  = ((const float4*)(X  + base))[tid*2];
  float4 b  = ((const float4*)(X  + base))[tid*2+1];
  float4 ba = ((const float4*)bias)[tid*2];
  float4 bb = ((const float4*)bias)[tid*2+1];
  float4 pa = ((const float4*)(p0 + base))[tid*2];
  float4 pb = ((const float4*)(p0 + base))[tid*2+1];
  a.x += ba.x + pa.x; a.y += ba.y + pa.y;
  a.z += ba.z + pa.z; a.w += ba.w + pa.w;
  b.x += bb.x + pb.x; b.y += bb.y + pb.y;
  b.z += bb.z + pb.z; b.w += bb.w + pb.w;
  ((float4*)(out + base))[tid*2]   = a;
  ((float4*)(out + base))[tid*2+1] = b;
  float ss = a.x*a.x + a.y*a.y + a.z*a.z + a.w*a.w
           + b.x*b.x + b.y*b.y + b.z*b.z + b.w*b.w;
  #pragma unroll
  for (int m = 1; m < 64; m <<= 1) ss += __shfl_xor(ss, m, 64);
  __shared__ float red[4];
  if ((tid & 63) == 0) red[tid >> 6] = ss;
  __syncthreads();
  float tot = red[0] + red[1] + red[2] + red[3];
  float sc = rsqrtf(tot * (1.0f / D_MODEL) + 1e-6f);
  float4 ga = ((const float4*)g)[tid*2];
  float4 gb = ((const float4*)g)[tid*2+1];
  uint32_t w0 = f2bf(a.x*sc*ga.x) | ((uint32_t)f2bf(a.y*sc*ga.y) << 16);
  uint32_t w1 = f2bf(a.z*sc*ga.z) | ((uint32_t)f2bf(a.w*sc*ga.w) << 16);
  uint32_t w2 = f2bf(b.x*sc*gb.x) | ((uint32_t)f2bf(b.y*sc*gb.y) << 16);
  uint32_t w3 = f2bf(b.z*sc*gb.z) | ((uint32_t)f2bf(b.w*sc*gb.w) << 16);
  ((uint4*)(nrm + base))[tid] = make_uint4(w0, w1, w2, w3);
}

// ============ 256x256 8-wave GEMM — 8-phase (r12-proven schedule) ============
// EPI 11: interleaved W1|W3 -> fused silu(h1)*h3 bf16 out via LDS exchange
template<int EPI>
__global__ __launch_bounds__(512, 2) void k_gemm8p(
    const u16* __restrict__ A, const u16* __restrict__ Bt,
    const float* __restrict__ bias, const u16* __restrict__ aux,
    void* __restrict__ Cout, int M, int N, int K,
    int lda, int ldb, int ldc)
{
  extern __shared__ __align__(16) char smem[];
  const int tid = threadIdx.x;
  const int lane = tid & 63, wid = tid >> 6;
  const int wr = wid >> 2, wc = wid & 3;
  const int lrow = lane & 15, lhi = lane >> 4;

  int nwg = gridDim.x, wg = blockIdx.x;

  int nbx = N >> 8, nbm = M >> 8;
  int xcd = wg & 7, sub = wg >> 3;
  int m0, n0;
  if ((nwg & 7) == 0 && (nbm & 1) == 0 && (nbx & 3) == 0){
    int mh = nbm >> 1;
    int mr = sub % mh, nc = sub / mh;
    m0 = (((xcd & 1) * mh) + mr) << 8;
    n0 = (((xcd >> 1) * (nbx >> 2)) + nc) << 8;
  } else {
    int qq = nwg >> 3, rr2 = nwg & 7;
    int swz = (xcd < rr2 ? xcd*(qq+1) : rr2*(qq+1) + (xcd-rr2)*qq) + sub;
    m0 = (swz / nbx) << 8; n0 = (swz % nbx) << 8;
  }

  const int nk = K >> 6;
  const int hA = wr, hB = wc >> 1;
  const int gA = wc;
  const int gB = (wr << 1) | (wc & 1);

  const u16* aSrc[2][2]; int aDst[2][2];
  const u16* bSrc[2][2]; int bDst[2][2];
  #pragma unroll
  for (int q = 0; q < 2; ++q)
    #pragma unroll
    for (int L = 0; L < 2; ++L){
      int p = q*8192 + gA*2048 + L*1024 + lane*16;
      int row = p >> 7;
      int o = (p & 127) ^ ((row & 7) << 4);
      aSrc[q][L] = A + (size_t)(m0 + hA*128 + row)*lda + (o >> 1);
      aDst[q][L] = hA*16384 + p;
      int pb = q*4096 + (gB >> 1)*8192 + (gB & 1)*2048 + L*1024 + lane*16;
      int rowb = pb >> 7;
      int ob = (pb & 127) ^ ((rowb & 7) << 4);
      bSrc[q][L] = Bt + (size_t)(n0 + hB*128 + rowb)*ldb + (ob >> 1);
      bDst[q][L] = 32768 + hB*16384 + pb;
    }
  const int xo0 = (lhi*16) ^ ((lrow & 7) << 4);
  const int xo1 = (64 + lhi*16) ^ ((lrow & 7) << 4);

  auto stA = [&](int d, int kk, int q){
    #pragma unroll
    for (int L = 0; L < 2; ++L)
      __builtin_amdgcn_global_load_lds(
        (const AS1 void*)(aSrc[q][L] + kk),
        (AS3 void*)(smem + d*65536 + aDst[q][L]), 16, 0, 0);
  };
  auto stB = [&](int d, int kk, int s){
    #pragma unroll
    for (int L = 0; L < 2; ++L)
      __builtin_amdgcn_global_load_lds(
        (const AS1 void*)(bSrc[s][L] + kk),
        (AS3 void*)(smem + d*65536 + bDst[s][L]), 16, 0, 0);
  };
  auto rdA = [&](int d, int rloc, int ks)->bf16x8{
    return *(const bf16x8*)(smem + d*65536 + hA*16384 + rloc*128 + (ks ? xo1 : xo0));
  };
  auto rdB = [&](int d, int rloc, int ks)->bf16x8{
    return *(const bf16x8*)(smem + d*65536 + 32768 + hB*16384 + rloc*128 + (ks ? xo1 : xo0));
  };

  f32x4 acc[8][4] = {};

  stA(0, 0, 0); stB(0, 0, 0); stB(0, 0, 1); stA(0, 0, 1);
  asm volatile("s_waitcnt vmcnt(0)" ::: "memory");
  __builtin_amdgcn_s_barrier();

  for (int t = 0; t < nk; ++t){
    int d = t & 1, dn = d ^ 1, kkn = (t + 1) << 6;
    bool pf = (t + 1 < nk);
    bf16x8 aR[8], bQ0[4], bQ1[4];

    // ---- phase 0: Q00 ----
    #pragma unroll
    for (int ii = 0; ii < 4; ++ii){
      aR[ii*2]   = rdA(d, ii*16 + lrow, 0);
      aR[ii*2+1] = rdA(d, ii*16 + lrow, 1);
    }
    #pragma unroll
    for (int j = 0; j < 2; ++j){
      bQ0[j*2]   = rdB(d, (wc&1)*64 + j*16 + lrow, 0);
      bQ0[j*2+1] = rdB(d, (wc&1)*64 + j*16 + lrow, 1);
    }
    if (pf){ stA(dn, kkn, 0); stB(dn, kkn, 0); }
    __builtin_amdgcn_s_barrier();
    asm volatile("s_waitcnt lgkmcnt(0)" ::: "memory");
    __builtin_amdgcn_sched_barrier(0);
    __builtin_amdgcn_s_setprio(1);
    #pragma unroll
    for (int ii = 0; ii < 4; ++ii)
      #pragma unroll
      for (int j = 0; j < 2; ++j){
        acc[ii][j] = __builtin_amdgcn_mfma_f32_16x16x32_bf16(aR[ii*2],   bQ0[j*2],   acc[ii][j], 0, 0, 0);
        acc[ii][j] = __builtin_amdgcn_mfma_f32_16x16x32_bf16(aR[ii*2+1], bQ0[j*2+1], acc[ii][j], 0, 0, 0);
      }
    __builtin_amdgcn_s_setprio(0);
    if (pf) asm volatile("s_waitcnt vmcnt(6)" ::: "memory");
    else    asm volatile("s_waitcnt vmcnt(2)" ::: "memory");
    __builtin_amdgcn_sched_barrier(0);
    __builtin_amdgcn_s_barrier();

    // ---- phase 1: Q01 ----
    #pragma unroll
    for (int j = 0; j < 2; ++j){
      bQ1[j*2]   = rdB(d, (wc&1)*64 + 32 + j*16 + lrow, 0);
      bQ1[j*2+1] = rdB(d, (wc&1)*64 + 32 + j*16 + lrow, 1);
    }
    if (pf) stB(dn, kkn, 1);
    __builtin_amdgcn_s_barrier();
    asm volatile("s_waitcnt lgkmcnt(0)" ::: "memory");
    __builtin_amdgcn_sched_barrier(0);
    __builtin_amdgcn_s_setprio(1);
    #pragma unroll
    for (int ii = 0; ii < 4; ++ii)
      #pragma unroll
      for (int j = 0; j < 2; ++j){
        acc[ii][2+j] = __builtin_amdgcn_mfma_f32_16x16x32_bf16(aR[ii*2],   bQ1[j*2],   acc[ii][2+j], 0, 0, 0);
        acc[ii][2+j] = __builtin_amdgcn_mfma_f32_16x16x32_bf16(aR[ii*2+1], bQ1[j*2+1], acc[ii][2+j], 0, 0, 0);
      }
    __builtin_amdgcn_s_setprio(0);
    if (pf) asm volatile("s_waitcnt vmcnt(6)" ::: "memory");
    else    asm volatile("s_waitcnt vmcnt(0)" ::: "memory");
    __builtin_amdgcn_sched_barrier(0);
    __builtin_amdgcn_s_barrier();

    // ---- phase 2: Q11 ----
    #pragma unroll
    for (int ii = 0; ii < 4; ++ii){
      aR[ii*2]   = rdA(d, 64 + ii*16 + lrow, 0);
      aR[ii*2+1] = rdA(d, 64 + ii*16 + lrow, 1);
    }
    if (pf) stA(dn, kkn, 1);
    __builtin_amdgcn_s_barrier();
    asm volatile("s_waitcnt lgkmcnt(0)" ::: "memory");
    __builtin_amdgcn_sched_barrier(0);
    __builtin_amdgcn_s_setprio(1);
    #pragma unroll
    for (int ii = 0; ii < 4; ++ii)
      #pragma unroll
      for (int j = 0; j < 2; ++j){
        acc[4+ii][2+j] = __builtin_amdgcn_mfma_f32_16x16x32_bf16(aR[ii*2],   bQ1[j*2],   acc[4+ii][2+j], 0, 0, 0);
        acc[4+ii][2+j] = __builtin_amdgcn_mfma_f32_16x16x32_bf16(aR[ii*2+1], bQ1[j*2+1], acc[4+ii][2+j], 0, 0, 0);
      }
    __builtin_amdgcn_s_setprio(0);
    __builtin_amdgcn_s_barrier();

    // ---- phase 3: Q10 ----
    __builtin_amdgcn_s_setprio(1);
    #pragma unroll
    for (int ii = 0; ii < 4; ++ii)
      #pragma unroll
      for (int j = 0; j < 2; ++j){
        acc[4+ii][j] = __builtin_amdgcn_mfma_f32_16x16x32_bf16(aR[ii*2],   bQ0[j*2],   acc[4+ii][j], 0, 0, 0);
        acc[4+ii][j] = __builtin_amdgcn_mfma_f32_16x16x32_bf16(aR[ii*2+1], bQ0[j*2+1], acc[4+ii][j], 0, 0, 0);
      }
    __builtin_amdgcn_s_setprio(0);
    if (pf) asm volatile("s_waitcnt vmcnt(4)" ::: "memory");
    __builtin_amdgcn_sched_barrier(0);
    __builtin_amdgcn_s_barrier();
  }

  if constexpr (EPI == 11){
    // block cols 0-127 = h1, 128-255 = h3 of hg cols [n0/2, n0/2+128)
    float* hl = (float*)smem;   // [256][128] fp32 = 128 KB (K-loop LDS dead after final barrier)
    if (wc >= 2){
      #pragma unroll
      for (int i = 0; i < 8; ++i)
        #pragma unroll
        for (int j = 0; j < 4; ++j){
          int col = (wc - 2)*64 + j*16 + lrow;
          #pragma unroll
          for (int q = 0; q < 4; ++q){
            int row = wr*128 + i*16 + lhi*4 + q;
            hl[row*128 + col] = acc[i][j][q];
          }
        }
    }
    __builtin_amdgcn_s_barrier();
    if (wc < 2){
      u16* hg = (u16*)Cout;
      int cbase = (n0 >> 1);
      #pragma unroll
      for (int i = 0; i < 8; ++i)
        #pragma unroll
        for (int j = 0; j < 4; ++j){
          int col = wc*64 + j*16 + lrow;
          #pragma unroll
          for (int q = 0; q < 4; ++q){
            int row = wr*128 + i*16 + lhi*4 + q;
            float h1v = acc[i][j][q];
            float h3v = hl[row*128 + col];
            float v = h1v / (1.f + __expf(-h1v)) * h3v;
            hg[(size_t)(m0 + row)*ldc + cbase + col] = f2bf(v);
          }
        }
    }
    return;
  }
  // generic bf16 epilogue (unused EPI values)
  u16* Cw = (u16*)Cout;
  #pragma unroll
  for (int i = 0; i < 8; ++i){
    #pragma unroll
    for (int j = 0; j < 4; ++j){
      int col = n0 + wc*64 + j*16 + lrow;
      float bv = 0.f;
      if constexpr (EPI == 0) bv = bias[col];
      #pragma unroll
      for (int q = 0; q < 4; ++q){
        int row = m0 + wr*128 + i*16 + lhi*4 + q;
        Cw[(size_t)row*ldc + col] = f2bf(acc[i][j][q] + bv);
      }
    }
  }
}

// ============ 256Mx128N 8-wave GEMM — 2-phase, full-round grids ============
// EPI 8: fp32 out = acc + res; EPI 9: fp32 out = acc; EPI 10: bf16 out = acc + bias.
template<int EPI>
__global__ __launch_bounds__(512, 2) void k_gemm8pn(
    const u16* __restrict__ A, const u16* __restrict__ Bt,
    const float* __restrict__ bias, const float* __restrict__ res,
    void* __restrict__ Cout,
    int M, int N, int K, int lda, int ldb, int ldc)
{
  extern __shared__ __align__(16) char smem[];
  const int tid = threadIdx.x;
  const int lane = tid & 63, wid = tid >> 6;
  const int wr = wid >> 2, wc = wid & 3;
  const int lrow = lane & 15, lhi = lane >> 4;

  int nwg = gridDim.x, wg = blockIdx.x;
  int nbx = N >> 7, nbm = M >> 8;
  int xcd = wg & 7, sub = wg >> 3;
  int m0, n0;
  if ((nwg & 7) == 0 && (nbm & 1) == 0 && (nbx & 3) == 0){
    int mh = nbm >> 1;
    int mr = sub % mh, nc = sub / mh;
    m0 = (((xcd & 1) * mh) + mr) << 8;
    n0 = (((xcd >> 1) * (nbx >> 2)) + nc) << 7;
  } else {
    int qq = nwg >> 3, rr2 = nwg & 7;
    int swz = (xcd < rr2 ? xcd*(qq+1) : rr2*(qq+1) + (xcd-rr2)*qq) + sub;
    m0 = (swz / nbx) << 8; n0 = (swz % nbx) << 7;
  }

  const int nk = K >> 6;
  const int hA = wr;
  const int gA = wc;

  const u16* aSrc[2][2]; int aDst[2][2];
  #pragma unroll
  for (int q = 0; q < 2; ++q)
    #pragma unroll
    for (int L = 0; L < 2; ++L){
      int p = q*8192 + gA*2048 + L*1024 + lane*16;
      int row = p >> 7;
      int o = (p & 127) ^ ((row & 7) << 4);
      aSrc[q][L] = A + (size_t)(m0 + hA*128 + row)*lda + (o >> 1);
      aDst[q][L] = hA*16384 + p;
    }
  const u16* bSrc[2]; int bDst[2];
  #pragma unroll
  for (int s = 0; s < 2; ++s){
    int p = s*8192 + wid*1024 + lane*16;
    int row = p >> 7;
    int o = (p & 127) ^ ((row & 7) << 4);
    bSrc[s] = Bt + (size_t)(n0 + row)*ldb + (o >> 1);
    bDst[s] = 32768 + p;
  }
  const int xo0 = (lhi*16) ^ ((lrow & 7) << 4);
  const int xo1 = (64 + lhi*16) ^ ((lrow & 7) << 4);

  auto stA = [&](int d, int kk, int q){
    #pragma unroll
    for (int L = 0; L < 2; ++L)
      __builtin_amdgcn_global_load_lds(
        (const AS1 void*)(aSrc[q][L] + kk),
        (AS3 void*)(smem + d*49152 + aDst[q][L]), 16, 0, 0);
  };
  auto stB = [&](int d, int kk){
    #pragma unroll
    for (int s = 0; s < 2; ++s)
      __builtin_amdgcn_global_load_lds(
        (const AS1 void*)(bSrc[s] + kk),
        (AS3 void*)(smem + d*49152 + bDst[s]), 16, 0, 0);
  };
  auto rdA = [&](int d, int rloc, int ks)->bf16x8{
    return *(const bf16x8*)(smem + d*49152 + hA*16384 + rloc*128 + (ks ? xo1 : xo0));
  };
  auto rdB = [&](int d, int rloc, int ks)->bf16x8{
    return *(const bf16x8*)(smem + d*49152 + 32768 + rloc*128 + (ks ? xo1 : xo0));
  };

  f32x4 acc[8][2] = {};

  stA(0, 0, 0); stB(0, 0); stA(0, 0, 1);
  asm volatile("s_waitcnt vmcnt(0)" ::: "memory");
  __builtin_amdgcn_s_barrier();

  for (int t = 0; t < nk; ++t){
    int d = t & 1, dn = d ^ 1, kkn = (t + 1) << 6;
    bool pf = (t + 1 < nk);
    bf16x8 aR[8], bQ[4];

    // ---- phase 0: rows 0-63 ----
    #pragma unroll
    for (int ii = 0; ii < 4; ++ii){
      aR[ii*2]   = rdA(d, ii*16 + lrow, 0);
      aR[ii*2+1] = rdA(d, ii*16 + lrow, 1);
    }
    #pragma unroll
    for (int j = 0; j < 2; ++j){
      bQ[j*2]   = rdB(d, wc*32 + j*16 + lrow, 0);
      bQ[j*2+1] = rdB(d, wc*32 + j*16 + lrow, 1);
    }
    if (pf){ stA(dn, kkn, 0); stB(dn, kkn); }
    __builtin_amdgcn_s_barrier();
    asm volatile("s_waitcnt lgkmcnt(0)" ::: "memory");
    __builtin_amdgcn_sched_barrier(0);
    __builtin_amdgcn_s_setprio(1);
    #pragma unroll
    for (int ii = 0; ii < 4; ++ii)
      #pragma unroll
      for (int j = 0; j < 2; ++j){
        acc[ii][j] = __builtin_amdgcn_mfma_f32_16x16x32_bf16(aR[ii*2],   bQ[j*2],   acc[ii][j], 0, 0, 0);
        acc[ii][j] = __builtin_amdgcn_mfma_f32_16x16x32_bf16(aR[ii*2+1], bQ[j*2+1], acc[ii][j], 0, 0, 0);
      }
    __builtin_amdgcn_s_setprio(0);
    if (pf) asm volatile("s_waitcnt vmcnt(4)" ::: "memory");
    else    asm volatile("s_waitcnt vmcnt(0)" ::: "memory");
    __builtin_amdgcn_sched_barrier(0);
    __builtin_amdgcn_s_barrier();

    // ---- phase 1: rows 64-127 (reuse bQ) ----
    #pragma unroll
    for (int ii = 0; ii < 4; ++ii){
      aR[ii*2]   = rdA(d, 64 + ii*16 + lrow, 0);
      aR[ii*2+1] = rdA(d, 64 + ii*16 + lrow, 1);
    }
    if (pf) stA(dn, kkn, 1);
    __builtin_amdgcn_s_barrier();
    asm volatile("s_waitcnt lgkmcnt(0)" ::: "memory");
    __builtin_amdgcn_sched_barrier(0);
    __builtin_amdgcn_s_setprio(1);
    #pragma unroll
    for (int ii = 0; ii < 4; ++ii)
      #pragma unroll
      for (int j = 0; j < 2; ++j){
        acc[4+ii][j] = __builtin_amdgcn_mfma_f32_16x16x32_bf16(aR[ii*2],   bQ[j*2],   acc[4+ii][j], 0, 0, 0);
        acc[4+ii][j] = __builtin_amdgcn_mfma_f32_16x16x32_bf16(aR[ii*2+1], bQ[j*2+1], acc[4+ii][j], 0, 0, 0);
      }
    __builtin_amdgcn_s_setprio(0);
    if (pf) asm volatile("s_waitcnt vmcnt(2)" ::: "memory");
    else    asm volatile("s_waitcnt vmcnt(0)" ::: "memory");
    __builtin_amdgcn_sched_barrier(0);
    __builtin_amdgcn_s_barrier();
  }

  #pragma unroll
  for (int i = 0; i < 8; ++i){
    #pragma unroll
    for (int j = 0; j < 2; ++j){
      int col = n0 + wc*32 + j*16 + lrow;
      #pragma unroll
      for (int q = 0; q < 4; ++q){
        int row = m0 + wr*128 + i*16 + lhi*4 + q;
        size_t idx = (size_t)row*ldc + col;
        if constexpr (EPI == 10){
          ((u16*)Cout)[idx] = f2bf(acc[i][j][q] + bias[col]);
        } else {
          float v = acc[i][j][q];
          if constexpr (EPI == 8) v += res[idx];
          ((float*)Cout)[idx] = v;
        }
      }
    }
  }
}

// ---- causal flash attention: paired-qblock load balancing (unchanged) ----
__global__ __launch_bounds__(512) void k_attn(
    const u16* __restrict__ Q, const u16* __restrict__ Kb,
    const u16* __restrict__ Vt, u16* __restrict__ O, int ldq)
{
  int tid = threadIdx.x, lane = tid & 63, wave = tid >> 6;
  int lrow = lane & 15, lhi = lane >> 4;
  int bidx = blockIdx.x;
  int bh = bidx >> 3, j = bidx & 7;
  int b = bh >> 4, h = bh & 15;

  __shared__ __align__(16) u16 Kbuf[2][64*128];
  __shared__ __align__(16) u16 Vbuf[2][128*64];
  __shared__ __align__(16) u16 P_lds[8][16*64];
  char* pw = (char*)&P_lds[wave][0];
  const float sc2 = 0.08838834764831845f * 1.44269504088896340736f;

  auto stage = [&](int bufi, int kt){
    int kv0 = kt << 6;
    char* kd = (char*)&Kbuf[bufi][0];
    char* vd = (char*)&Vbuf[bufi][0];
    #pragma unroll
    for (int L = 0; L < 2; ++L){
      int cid = wave*128 + L*64 + lane;
      int r = cid >> 4, c = cid & 15;
      int cg = c ^ (r & 7);
      __builtin_amdgcn_global_load_lds(
        (const AS1 void*)(Kb + (size_t)(b*SS + kv0 + r)*ldq + h*DK + cg*8),
        (AS3 void*)(kd + wave*2048 + L*1024 + lane*16), 16, 0, 0);
      int dd = cid >> 3, c8 = cid & 7;
      int cv = c8 ^ (dd & 7);
      __builtin_amdgcn_global_load_lds(
        (const AS1 void*)(Vt + (size_t)bh*DK*SS + (size_t)dd*SS + kv0 + cv*8),
        (AS3 void*)(vd + wave*2048 + L*1024 + lane*16), 16, 0, 0);
    }
  };

  #pragma unroll 1
  for (int item = 0; item < 2; ++item){
    int qi = item == 0 ? 15 - j : j;
    int qs = qi * 128;
    int nt = 2*qi + 2;
    int qrow = qs + wave * 16;

    bf16x8 qf[4];
    const u16* qbase = Q + (size_t)(b*SS + qrow + lrow)*ldq + h*DK + lhi*8;
    #pragma unroll
    for (int dc = 0; dc < 4; ++dc) qf[dc] = *(const bf16x8*)(qbase + dc*32);

    f32x4 accO[8] = {};
    float mr[4] = {-1e30f,-1e30f,-1e30f,-1e30f};
    float lr[4] = {0.f,0.f,0.f,0.f};

    stage(0, 0);
    __syncthreads();

    for (int kt = 0; kt < nt; ++kt){
      int cur = kt & 1;
      if (kt + 1 < nt) stage(cur ^ 1, kt + 1);
      int kv0 = kt << 6;
      if (kv0 <= qrow + 15){
        const char* kl = (const char*)&Kbuf[cur][0];
        const char* vl = (const char*)&Vbuf[cur][0];
        bool domask = (kv0 + 63 > qrow);

        f32x4 sf[4];
        #pragma unroll
        for (int hf = 0; hf < 4; ++hf){
          int rl = hf*16 + lrow;
          int sw = rl & 7;
          f32x4 a = {};
          #pragma unroll
          for (int dc = 0; dc < 4; ++dc){
            bf16x8 kf = *(const bf16x8*)(kl + rl*256 + (((lhi + dc*4) ^ sw) << 4));
            a = __builtin_amdgcn_mfma_f32_16x16x32_bf16(qf[dc], kf, a, 0, 0, 0);
          }
          sf[hf] = a;
        }

        float p[4][4], mx[4];
        #pragma unroll
        for (int q = 0; q < 4; ++q){
          float s0 = sf[0][q]*sc2, s1 = sf[1][q]*sc2, s2 = sf[2][q]*sc2, s3 = sf[3][q]*sc2;
          if (domask){
            int qg = qrow + lhi*4 + q;
            if (kv0      + lrow > qg) s0 = -1e30f;
            if (kv0 + 16 + lrow > qg) s1 = -1e30f;
            if (kv0 + 32 + lrow > qg) s2 = -1e30f;
            if (kv0 + 48 + lrow > qg) s3 = -1e30f;
          }
          p[q][0]=s0; p[q][1]=s1; p[q][2]=s2; p[q][3]=s3;
          float m = fmaxf(fmaxf(s0,s1), fmaxf(s2,s3));
          m = fmaxf(m, __shfl_xor(m, 1, 64));
          m = fmaxf(m, __shfl_xor(m, 2, 64));
          m = fmaxf(m, __shfl_xor(m, 4, 64));
          m = fmaxf(m, __shfl_xor(m, 8, 64));
          mx[q] = m;
        }
        float dmax = fmaxf(fmaxf(mx[0]-mr[0], mx[1]-mr[1]), fmaxf(mx[2]-mr[2], mx[3]-mr[3]));
        bool rescale = !__all(dmax <= 8.0f);
        float al[4];
        #pragma unroll
        for (int q = 0; q < 4; ++q){
          if (rescale){
            float mn = fmaxf(mr[q], mx[q]);
            al[q] = fexp2(mr[q] - mn);
            mr[q] = mn;
          } else al[q] = 1.0f;
          p[q][0] = fexp2(p[q][0] - mr[q]);
          p[q][1] = fexp2(p[q][1] - mr[q]);
          p[q][2] = fexp2(p[q][2] - mr[q]);
          p[q][3] = fexp2(p[q][3] - mr[q]);
          float sm = (p[q][0] + p[q][1]) + (p[q][2] + p[q][3]);
          sm += __shfl_xor(sm, 1, 64);
          sm += __shfl_xor(sm, 2, 64);
          sm += __shfl_xor(sm, 4, 64);
          sm += __shfl_xor(sm, 8, 64);
          lr[q] = lr[q]*al[q] + sm;
        }
        if (rescale){
          #pragma unroll
          for (int f = 0; f < 8; ++f)
            #pragma unroll
            for (int q = 0; q < 4; ++q) accO[f][q] *= al[q];
        }

        #pragma unroll
        for (int q = 0; q < 4; ++q){
          int row = lhi*4 + q;
          int rb = row*128, sw = (row & 7) << 4;
          #pragma unroll
          for (int hf = 0; hf < 4; ++hf)
            *(u16*)(pw + rb + ((hf*32 + lrow*2) ^ sw)) = cvt_bf16(p[q][hf]);
        }
        __builtin_amdgcn_sched_barrier(0);
        int rsw = (lrow & 7) << 4;
        bf16x8 pa0 = *(const bf16x8*)(pw + lrow*128 + ((     lhi*16) ^ rsw));
        bf16x8 pa1 = *(const bf16x8*)(pw + lrow*128 + ((64 + lhi*16) ^ rsw));

        #pragma unroll
        for (int f = 0; f < 8; ++f){
          int d = f*16 + lrow;
          int swv = d & 7;
          bf16x8 v0 = *(const bf16x8*)(vl + d*128 + (((lhi    ) ^ swv) << 4));
          bf16x8 v1 = *(const bf16x8*)(vl + d*128 + (((lhi + 4) ^ swv) << 4));
          accO[f] = __builtin_amdgcn_mfma_f32_16x16x32_bf16(pa0, v0, accO[f], 0, 0, 0);
          accO[f] = __builtin_amdgcn_mfma_f32_16x16x32_bf16(pa1, v1, accO[f], 0, 0, 0);
        }
      }
      __syncthreads();
    }

    #pragma unroll
    for (int q = 0; q < 4; ++q){
      float inv = 1.0f / lr[q];
      #pragma unroll
      for (int f = 0; f < 8; ++f){
        int row = b*SS + qrow + lhi*4 + q;
        int col = h*DK + f*16 + lrow;
        O[(size_t)row*D_MODEL + col] = cvt_bf16(accO[f][q] * inv);
      }
    }
    __syncthreads();
  }
}

extern "C" void kernel_launch(void* const* d_in, const int* in_sizes, int n_in,
                              void* d_out, int out_size, void* d_ws, size_t ws_size,
                              hipStream_t stream)
{
  (void)in_sizes; (void)n_in; (void)out_size;
  const float* x  = (const float*)d_in[0];
  const float* wq = (const float*)d_in[2];
  const float* bq = (const float*)d_in[3];
  const float* wk = (const float*)d_in[4];
  const float* bk = (const float*)d_in[5];
  const float* wv = (const float*)d_in[6];
  const float* bv = (const float*)d_in[7];
  const float* wo = (const float*)d_in[8];
  const float* bo = (const float*)d_in[9];
  const float* g1 = (const float*)d_in[10];
  const float* g2 = (const float*)d_in[11];
  const float* w1 = (const float*)d_in[12];
  const float* w3 = (const float*)d_in[13];
  const float* w2 = (const float*)d_in[14];
  float* out = (float*)d_out;

  const size_t MB = 1u << 20;
  const size_t W2T_B = (size_t)D_MODEL * DFF * sizeof(u16);
  const size_t NEED = 152*MB + W2T_B + 32768;
  if (ws_size < NEED) return;
  char* ws = (char*)d_ws;
  u16* bufA  = (u16*)(ws + 0);        // 16 MiB: nbf1 -> aob -> nbf2
  u16* qkv   = (u16*)(ws + 16*MB);    // 48 MiB fused QKV [4096][6144]
  u16* h1    = qkv;                   // hg [4096][5632], aliases after attn
  u16* wqkvt = (u16*)(ws + 64*MB);    // 24 MiB, dead after QKV GEMM
  u16* w1w3t = (u16*)(ws + 64*MB);    // [11264][2048] interleaved (64-108)
  u16* wot   = (u16*)(ws + 88*MB);    // 8 MiB (w1w3 transpose AFTER O-proj)
  u16* vtb   = (u16*)(ws + 96*MB);    // 16 MiB (dead after attn)
  float* p0o = (float*)(ws + 16*MB);  // O-proj partial: qkv dead after attn
  u16* w2t   = (u16*)(ws + 152*MB);
  float* bqkv = (float*)(ws + 152*MB + W2T_B);
  // fp32 residual x1 lives in d_out

  hipFuncSetAttribute((const void*)k_gemm8p<11>, hipFuncAttributeMaxDynamicSharedMemorySize, 131072);
  hipFuncSetAttribute((const void*)k_gemm8pn<8>, hipFuncAttributeMaxDynamicSharedMemorySize, 98304);
  hipFuncSetAttribute((const void*)k_gemm8pn<9>, hipFuncAttributeMaxDynamicSharedMemorySize, 98304);
  hipFuncSetAttribute((const void*)k_gemm8pn<10>, hipFuncAttributeMaxDynamicSharedMemorySize, 98304);

  dim3 tb(32, 8);
  k_transpose_w4<<<dim3(64,64,4), tb, 0, stream>>>(wq, wk, wv, wo,
      wqkvt, wqkvt + 2048*2048, wqkvt + 2*2048*2048, wot);
  k_transpose_w<<<dim3(64, DFF/32), tb, 0, stream>>>(w2, w2t, DFF, D_MODEL);
  k_concat3<<<24, 256, 0, stream>>>(bq, bk, bv, bqkv);

  k_rmsnorm<<<MTOK, 256, 0, stream>>>(x, g1, bufA);
  // QKV: 256Mx128N, 768 blocks = 3 full rounds, bf16 + bias
  k_gemm8pn<10><<<(MTOK/256)*(DQKV/128), 512, 98304, stream>>>(bufA, wqkvt, bqkv, nullptr, qkv, MTOK, DQKV, D_MODEL, D_MODEL, D_MODEL, DQKV);
  k_transpose_v<<<dim3(SS/32, 128), tb, 0, stream>>>(qkv + 4096, vtb, DQKV);
  k_attn<<<dim3(BB*NHEADS*8), 512, 0, stream>>>(qkv, qkv + 2048, vtb, bufA, DQKV);
  // O-proj: 256Mx128N, 256 blocks -> single fp32 partial
  k_gemm8pn<9><<<(MTOK/256)*(D_MODEL/128), 512, 98304, stream>>>(bufA, wot, nullptr, nullptr, p0o, MTOK, D_MODEL, D_MODEL, D_MODEL, D_MODEL, D_MODEL);
  // w1|w3 interleaved -> w1w3t (dead wqkvt + wot + vtb): after O-proj & attn
  k_transpose_w13i<<<dim3(DFFP/32, 64, 2), tb, 0, stream>>>(w1, w3, w1w3t);
  k_addres_rms<<<MTOK, 256, 0, stream>>>(x, bo, p0o, g2, out, bufA);
  // W1|W3 interleaved, fused silu(h1)*h3 epilogue -> hg (bf16) directly
  k_gemm8p<11><<<(MTOK/256)*((2*DFFP)/256), 512, 131072, stream>>>(bufA, w1w3t, nullptr, nullptr, h1, MTOK, 2*DFFP, D_MODEL, D_MODEL, D_MODEL, DFFP);
  // W2: 256Mx128N, 256 blocks, fused residual -> final out
  k_gemm8pn<8><<<(MTOK/256)*(D_MODEL/128), 512, 98304, stream>>>(h1, w2t, nullptr, out, out, MTOK, D_MODEL, DFF, DFFP, DFF, D_MODEL);
}

// Round 19
// 626.311 us; speedup vs baseline: 1.0966x; 1.0222x over previous
//
#include <hip/hip_runtime.h>
#include <stdint.h>

typedef unsigned short u16;
typedef __bf16 bf16x8 __attribute__((ext_vector_type(8)));
typedef float f32x4 __attribute__((ext_vector_type(4)));

#define D_MODEL 2048
#define NHEADS 16
#define DK 128
#define DFF 5504
#define DFFP 5632
#define BB 2
#define SS 2048
#define MTOK 4096
#define DQKV 6144

#define AS1 __attribute__((address_space(1)))
#define AS3 __attribute__((address_space(3)))

__device__ __forceinline__ u16 f2bf(float f){
  union { float f; uint32_t u; } v; v.f = f;
  uint32_t r = v.u + 0x7fffu + ((v.u >> 16) & 1u);
  return (u16)(r >> 16);
}
__device__ __forceinline__ float bf2f(u16 u){
  union { uint32_t u; float f; } v; v.u = ((uint32_t)u) << 16;
  return v.f;
}
__device__ __forceinline__ u16 cvt_bf16(float f){
  union { __bf16 h; u16 u; } v; v.h = (__bf16)f; return v.u;
}
__device__ __forceinline__ float fexp2(float x){
#if __has_builtin(__builtin_amdgcn_exp2f)
  return __builtin_amdgcn_exp2f(x);
#else
  return exp2f(x);
#endif
}

// ---- fp32 W[K][Nsrc] -> bf16 Wt[n][K], zero-fill n >= Nsrc ----
__global__ __launch_bounds__(256) void k_transpose_w(const float* __restrict__ W,
                                                     u16* __restrict__ Wt, int K, int Nsrc){
  __shared__ float tile[32][33];
  int n0 = blockIdx.x * 32, k0 = blockIdx.y * 32;
  int tx = threadIdx.x, ty = threadIdx.y;
  #pragma unroll
  for (int r = 0; r < 4; ++r){
    int n = n0 + tx;
    tile[ty + r*8][tx] = (n < Nsrc) ? W[(size_t)(k0 + ty + r*8) * Nsrc + n] : 0.0f;
  }
  __syncthreads();
  #pragma unroll
  for (int r = 0; r < 4; ++r)
    Wt[(size_t)(n0 + ty + r*8) * K + k0 + tx] = f2bf(tile[tx][ty + r*8]);
}

// ---- batched 2048x2048 transpose: z selects among 4 matrices ----
__global__ __launch_bounds__(256) void k_transpose_w4(
    const float* __restrict__ w0s, const float* __restrict__ w1s,
    const float* __restrict__ w2s, const float* __restrict__ w3s,
    u16* __restrict__ d0, u16* __restrict__ d1,
    u16* __restrict__ d2, u16* __restrict__ d3){
  __shared__ float tile[32][33];
  const float* W = blockIdx.z == 0 ? w0s : blockIdx.z == 1 ? w1s : blockIdx.z == 2 ? w2s : w3s;
  u16* Wt = blockIdx.z == 0 ? d0 : blockIdx.z == 1 ? d1 : blockIdx.z == 2 ? d2 : d3;
  int n0 = blockIdx.x * 32, k0 = blockIdx.y * 32;
  int tx = threadIdx.x, ty = threadIdx.y;
  #pragma unroll
  for (int r = 0; r < 4; ++r)
    tile[ty + r*8][tx] = W[(size_t)(k0 + ty + r*8) * D_MODEL + n0 + tx];
  __syncthreads();
  #pragma unroll
  for (int r = 0; r < 4; ++r)
    Wt[(size_t)(n0 + ty + r*8) * D_MODEL + k0 + tx] = f2bf(tile[tx][ty + r*8]);
}

// ---- 32-col interleaved w1|w3 transpose: w1 col r -> phys (r>>5)*64+(r&31); w3 -> +32 ----
// Makes each 64-phys-row wave slice = 32 h1 cols + 32 h3 cols of the SAME logical cols,
// so the silu(h1)*h3 epilogue is pure register math (no LDS exchange).
__global__ __launch_bounds__(256) void k_transpose_w13i(
    const float* __restrict__ w1s, const float* __restrict__ w3s,
    u16* __restrict__ dst){
  __shared__ float tile[32][33];
  const float* W = blockIdx.z == 0 ? w1s : w3s;
  int half = blockIdx.z << 5;   // 0 or 32
  int n0 = blockIdx.x * 32, k0 = blockIdx.y * 32;
  int tx = threadIdx.x, ty = threadIdx.y;
  #pragma unroll
  for (int r = 0; r < 4; ++r){
    int n = n0 + tx;
    tile[ty + r*8][tx] = (n < DFF) ? W[(size_t)(k0 + ty + r*8) * DFF + n] : 0.0f;
  }
  __syncthreads();
  #pragma unroll
  for (int r = 0; r < 4; ++r){
    int nr = n0 + ty + r*8;
    int pr = ((nr >> 5) << 6) + half + (nr & 31);
    dst[(size_t)pr * D_MODEL + k0 + tx] = f2bf(tile[tx][ty + r*8]);
  }
}

// ---- per-head V transpose from fused QKV ----
__global__ __launch_bounds__(256) void k_transpose_v(const u16* __restrict__ V,
                                                     u16* __restrict__ Vt, int ld){
  __shared__ u16 tile[32][33];
  int s0 = blockIdx.x * 32;
  int bh = blockIdx.y >> 2, dt = blockIdx.y & 3;
  int b = bh >> 4, h = bh & 15;
  int tx = threadIdx.x, ty = threadIdx.y;
  #pragma unroll
  for (int r = 0; r < 4; ++r)
    tile[ty + r*8][tx] = V[(size_t)(b*SS + s0 + ty + r*8) * ld + h*DK + dt*32 + tx];
  __syncthreads();
  #pragma unroll
  for (int r = 0; r < 4; ++r)
    Vt[(size_t)(bh*DK + dt*32 + ty + r*8) * SS + s0 + tx] = tile[tx][ty + r*8];
}

__global__ __launch_bounds__(256) void k_concat3(const float* __restrict__ a,
                                                 const float* __restrict__ b,
                                                 const float* __restrict__ c,
                                                 float* __restrict__ o){
  int i = blockIdx.x*256 + threadIdx.x;
  if (i >= DQKV) return;
  o[i] = (i < 2048) ? a[i] : (i < 4096 ? b[i-2048] : c[i-4096]);
}

// ---- RMSNorm: fp32 row -> bf16 row ----
__global__ __launch_bounds__(256) void k_rmsnorm(const float* __restrict__ X,
                                                 const float* __restrict__ g,
                                                 u16* __restrict__ out){
  int row = blockIdx.x, tid = threadIdx.x;
  const float* x = X + (size_t)row * D_MODEL;
  float4 a = ((const float4*)x)[tid*2];
  float4 b = ((const float4*)x)[tid*2+1];
  float ss = a.x*a.x + a.y*a.y + a.z*a.z + a.w*a.w
           + b.x*b.x + b.y*b.y + b.z*b.z + b.w*b.w;
  #pragma unroll
  for (int m = 1; m < 64; m <<= 1) ss += __shfl_xor(ss, m, 64);
  __shared__ float red[4];
  if ((tid & 63) == 0) red[tid >> 6] = ss;
  __syncthreads();
  float tot = red[0] + red[1] + red[2] + red[3];
  float sc = rsqrtf(tot * (1.0f / D_MODEL) + 1e-6f);
  float4 ga = ((const float4*)g)[tid*2];
  float4 gb = ((const float4*)g)[tid*2+1];
  uint32_t w0 = f2bf(a.x*sc*ga.x) | ((uint32_t)f2bf(a.y*sc*ga.y) << 16);
  uint32_t w1 = f2bf(a.z*sc*ga.z) | ((uint32_t)f2bf(a.w*sc*ga.w) << 16);
  uint32_t w2 = f2bf(b.x*sc*gb.x) | ((uint32_t)f2bf(b.y*sc*gb.y) << 16);
  uint32_t w3 = f2bf(b.z*sc*gb.z) | ((uint32_t)f2bf(b.w*sc*gb.w) << 16);
  ((uint4*)(out + (size_t)row * D_MODEL))[tid] = make_uint4(w0, w1, w2, w3);
}

// ---- fused: out = x + bias + p0 ; nrm = rmsnorm(out)*g (bf16) ----
__global__ __launch_bounds__(256) void k_addres_rms(
    const float* __restrict__ X, const float* __restrict__ bias,
    const float* __restrict__ p0, const float* __restrict__ g,
    float* __restrict__ out, u16* __restrict__ nrm){
  int row = blockIdx.x, tid = threadIdx.x;
  size_t base = (size_t)row * D_MODEL;
  float4 a  = ((const float4*)(X  + base))[tid*2];
  float4 b  = ((const float4*)(X  + base))[tid*2+1];
  float4 ba = ((const float4*)bias)[tid*2];
  float4 bb = ((const float4*)bias)[tid*2+1];
  float4 pa = ((const float4*)(p0 + base))[tid*2];
  float4 pb = ((const float4*)(p0 + base))[tid*2+1];
  a.x += ba.x + pa.x; a.y += ba.y + pa.y;
  a.z += ba.z + pa.z; a.w += ba.w + pa.w;
  b.x += bb.x + pb.x; b.y += bb.y + pb.y;
  b.z += bb.z + pb.z; b.w += bb.w + pb.w;
  ((float4*)(out + base))[tid*2]   = a;
  ((float4*)(out + base))[tid*2+1] = b;
  float ss = a.x*a.x + a.y*a.y + a.z*a.z + a.w*a.w
           + b.x*b.x + b.y*b.y + b.z*b.z + b.w*b.w;
  #pragma unroll
  for (int m = 1; m < 64; m <<= 1) ss += __shfl_xor(ss, m, 64);
  __shared__ float red[4];
  if ((tid & 63) == 0) red[tid >> 6] = ss;
  __syncthreads();
  float tot = red[0] + red[1] + red[2] + red[3];
  float sc = rsqrtf(tot * (1.0f / D_MODEL) + 1e-6f);
  float4 ga = ((const float4*)g)[tid*2];
  float4 gb = ((const float4*)g)[tid*2+1];
  uint32_t w0 = f2bf(a.x*sc*ga.x) | ((uint32_t)f2bf(a.y*sc*ga.y) << 16);
  uint32_t w1 = f2bf(a.z*sc*ga.z) | ((uint32_t)f2bf(a.w*sc*ga.w) << 16);
  uint32_t w2 = f2bf(b.x*sc*gb.x) | ((uint32_t)f2bf(b.y*sc*gb.y) << 16);
  uint32_t w3 = f2bf(b.z*sc*gb.z) | ((uint32_t)f2bf(b.w*sc*gb.w) << 16);
  ((uint4*)(nrm + base))[tid] = make_uint4(w0, w1, w2, w3);
}

// ============ 256x256 8-wave GEMM — 8-phase (r12-proven schedule) ============
// EPI 11: 32-col-interleaved W1|W3 -> fused silu(h1)*h3 bf16 out, pure register epilogue
template<int EPI>
__global__ __launch_bounds__(512, 2) void k_gemm8p(
    const u16* __restrict__ A, const u16* __restrict__ Bt,
    const float* __restrict__ bias, const u16* __restrict__ aux,
    void* __restrict__ Cout, int M, int N, int K,
    int lda, int ldb, int ldc)
{
  extern __shared__ __align__(16) char smem[];
  const int tid = threadIdx.x;
  const int lane = tid & 63, wid = tid >> 6;
  const int wr = wid >> 2, wc = wid & 3;
  const int lrow = lane & 15, lhi = lane >> 4;

  int nwg = gridDim.x, wg = blockIdx.x;

  int nbx = N >> 8, nbm = M >> 8;
  int xcd = wg & 7, sub = wg >> 3;
  int m0, n0;
  if ((nwg & 7) == 0 && (nbm & 1) == 0 && (nbx & 3) == 0){
    int mh = nbm >> 1;
    int mr = sub % mh, nc = sub / mh;
    m0 = (((xcd & 1) * mh) + mr) << 8;
    n0 = (((xcd >> 1) * (nbx >> 2)) + nc) << 8;
  } else {
    int qq = nwg >> 3, rr2 = nwg & 7;
    int swz = (xcd < rr2 ? xcd*(qq+1) : rr2*(qq+1) + (xcd-rr2)*qq) + sub;
    m0 = (swz / nbx) << 8; n0 = (swz % nbx) << 8;
  }

  const int nk = K >> 6;
  const int hA = wr, hB = wc >> 1;
  const int gA = wc;
  const int gB = (wr << 1) | (wc & 1);

  const u16* aSrc[2][2]; int aDst[2][2];
  const u16* bSrc[2][2]; int bDst[2][2];
  #pragma unroll
  for (int q = 0; q < 2; ++q)
    #pragma unroll
    for (int L = 0; L < 2; ++L){
      int p = q*8192 + gA*2048 + L*1024 + lane*16;
      int row = p >> 7;
      int o = (p & 127) ^ ((row & 7) << 4);
      aSrc[q][L] = A + (size_t)(m0 + hA*128 + row)*lda + (o >> 1);
      aDst[q][L] = hA*16384 + p;
      int pb = q*4096 + (gB >> 1)*8192 + (gB & 1)*2048 + L*1024 + lane*16;
      int rowb = pb >> 7;
      int ob = (pb & 127) ^ ((rowb & 7) << 4);
      bSrc[q][L] = Bt + (size_t)(n0 + hB*128 + rowb)*ldb + (ob >> 1);
      bDst[q][L] = 32768 + hB*16384 + pb;
    }
  const int xo0 = (lhi*16) ^ ((lrow & 7) << 4);
  const int xo1 = (64 + lhi*16) ^ ((lrow & 7) << 4);

  auto stA = [&](int d, int kk, int q){
    #pragma unroll
    for (int L = 0; L < 2; ++L)
      __builtin_amdgcn_global_load_lds(
        (const AS1 void*)(aSrc[q][L] + kk),
        (AS3 void*)(smem + d*65536 + aDst[q][L]), 16, 0, 0);
  };
  auto stB = [&](int d, int kk, int s){
    #pragma unroll
    for (int L = 0; L < 2; ++L)
      __builtin_amdgcn_global_load_lds(
        (const AS1 void*)(bSrc[s][L] + kk),
        (AS3 void*)(smem + d*65536 + bDst[s][L]), 16, 0, 0);
  };
  auto rdA = [&](int d, int rloc, int ks)->bf16x8{
    return *(const bf16x8*)(smem + d*65536 + hA*16384 + rloc*128 + (ks ? xo1 : xo0));
  };
  auto rdB = [&](int d, int rloc, int ks)->bf16x8{
    return *(const bf16x8*)(smem + d*65536 + 32768 + hB*16384 + rloc*128 + (ks ? xo1 : xo0));
  };

  f32x4 acc[8][4] = {};

  stA(0, 0, 0); stB(0, 0, 0); stB(0, 0, 1); stA(0, 0, 1);
  asm volatile("s_waitcnt vmcnt(0)" ::: "memory");
  __builtin_amdgcn_s_barrier();

  for (int t = 0; t < nk; ++t){
    int d = t & 1, dn = d ^ 1, kkn = (t + 1) << 6;
    bool pf = (t + 1 < nk);
    bf16x8 aR[8], bQ0[4], bQ1[4];

    // ---- phase 0: Q00 ----
    #pragma unroll
    for (int ii = 0; ii < 4; ++ii){
      aR[ii*2]   = rdA(d, ii*16 + lrow, 0);
      aR[ii*2+1] = rdA(d, ii*16 + lrow, 1);
    }
    #pragma unroll
    for (int j = 0; j < 2; ++j){
      bQ0[j*2]   = rdB(d, (wc&1)*64 + j*16 + lrow, 0);
      bQ0[j*2+1] = rdB(d, (wc&1)*64 + j*16 + lrow, 1);
    }
    if (pf){ stA(dn, kkn, 0); stB(dn, kkn, 0); }
    __builtin_amdgcn_s_barrier();
    asm volatile("s_waitcnt lgkmcnt(0)" ::: "memory");
    __builtin_amdgcn_sched_barrier(0);
    __builtin_amdgcn_s_setprio(1);
    #pragma unroll
    for (int ii = 0; ii < 4; ++ii)
      #pragma unroll
      for (int j = 0; j < 2; ++j){
        acc[ii][j] = __builtin_amdgcn_mfma_f32_16x16x32_bf16(aR[ii*2],   bQ0[j*2],   acc[ii][j], 0, 0, 0);
        acc[ii][j] = __builtin_amdgcn_mfma_f32_16x16x32_bf16(aR[ii*2+1], bQ0[j*2+1], acc[ii][j], 0, 0, 0);
      }
    __builtin_amdgcn_s_setprio(0);
    if (pf) asm volatile("s_waitcnt vmcnt(6)" ::: "memory");
    else    asm volatile("s_waitcnt vmcnt(2)" ::: "memory");
    __builtin_amdgcn_sched_barrier(0);
    __builtin_amdgcn_s_barrier();

    // ---- phase 1: Q01 ----
    #pragma unroll
    for (int j = 0; j < 2; ++j){
      bQ1[j*2]   = rdB(d, (wc&1)*64 + 32 + j*16 + lrow, 0);
      bQ1[j*2+1] = rdB(d, (wc&1)*64 + 32 + j*16 + lrow, 1);
    }
    if (pf) stB(dn, kkn, 1);
    __builtin_amdgcn_s_barrier();
    asm volatile("s_waitcnt lgkmcnt(0)" ::: "memory");
    __builtin_amdgcn_sched_barrier(0);
    __builtin_amdgcn_s_setprio(1);
    #pragma unroll
    for (int ii = 0; ii < 4; ++ii)
      #pragma unroll
      for (int j = 0; j < 2; ++j){
        acc[ii][2+j] = __builtin_amdgcn_mfma_f32_16x16x32_bf16(aR[ii*2],   bQ1[j*2],   acc[ii][2+j], 0, 0, 0);
        acc[ii][2+j] = __builtin_amdgcn_mfma_f32_16x16x32_bf16(aR[ii*2+1], bQ1[j*2+1], acc[ii][2+j], 0, 0, 0);
      }
    __builtin_amdgcn_s_setprio(0);
    if (pf) asm volatile("s_waitcnt vmcnt(6)" ::: "memory");
    else    asm volatile("s_waitcnt vmcnt(0)" ::: "memory");
    __builtin_amdgcn_sched_barrier(0);
    __builtin_amdgcn_s_barrier();

    // ---- phase 2: Q11 ----
    #pragma unroll
    for (int ii = 0; ii < 4; ++ii){
      aR[ii*2]   = rdA(d, 64 + ii*16 + lrow, 0);
      aR[ii*2+1] = rdA(d, 64 + ii*16 + lrow, 1);
    }
    if (pf) stA(dn, kkn, 1);
    __builtin_amdgcn_s_barrier();
    asm volatile("s_waitcnt lgkmcnt(0)" ::: "memory");
    __builtin_amdgcn_sched_barrier(0);
    __builtin_amdgcn_s_setprio(1);
    #pragma unroll
    for (int ii = 0; ii < 4; ++ii)
      #pragma unroll
      for (int j = 0; j < 2; ++j){
        acc[4+ii][2+j] = __builtin_amdgcn_mfma_f32_16x16x32_bf16(aR[ii*2],   bQ1[j*2],   acc[4+ii][2+j], 0, 0, 0);
        acc[4+ii][2+j] = __builtin_amdgcn_mfma_f32_16x16x32_bf16(aR[ii*2+1], bQ1[j*2+1], acc[4+ii][2+j], 0, 0, 0);
      }
    __builtin_amdgcn_s_setprio(0);
    __builtin_amdgcn_s_barrier();

    // ---- phase 3: Q10 ----
    __builtin_amdgcn_s_setprio(1);
    #pragma unroll
    for (int ii = 0; ii < 4; ++ii)
      #pragma unroll
      for (int j = 0; j < 2; ++j){
        acc[4+ii][j] = __builtin_amdgcn_mfma_f32_16x16x32_bf16(aR[ii*2],   bQ0[j*2],   acc[4+ii][j], 0, 0, 0);
        acc[4+ii][j] = __builtin_amdgcn_mfma_f32_16x16x32_bf16(aR[ii*2+1], bQ0[j*2+1], acc[4+ii][j], 0, 0, 0);
      }
    __builtin_amdgcn_s_setprio(0);
    if (pf) asm volatile("s_waitcnt vmcnt(4)" ::: "memory");
    __builtin_amdgcn_sched_barrier(0);
    __builtin_amdgcn_s_barrier();
  }

  if constexpr (EPI == 11){
    // 32-col interleave: wave's acc[i][j] (j<2) = h1, acc[i][j+2] = h3 of SAME
    // logical hg col (n0/2 + wc*32 + j*16 + lrow). Pure register epilogue.
    u16* hg = (u16*)Cout;
    int cbase = (n0 >> 1) + wc*32;
    #pragma unroll
    for (int i = 0; i < 8; ++i)
      #pragma unroll
      for (int j = 0; j < 2; ++j){
        int col = cbase + j*16 + lrow;
        #pragma unroll
        for (int q = 0; q < 4; ++q){
          int row = m0 + wr*128 + i*16 + lhi*4 + q;
          float h1v = acc[i][j][q];
          float h3v = acc[i][j+2][q];
          float v = h1v / (1.f + __expf(-h1v)) * h3v;
          hg[(size_t)row*ldc + col] = f2bf(v);
        }
      }
    return;
  }
  // generic bf16 epilogue (unused EPI values)
  u16* Cw = (u16*)Cout;
  #pragma unroll
  for (int i = 0; i < 8; ++i){
    #pragma unroll
    for (int j = 0; j < 4; ++j){
      int col = n0 + wc*64 + j*16 + lrow;
      float bv = 0.f;
      if constexpr (EPI == 0) bv = bias[col];
      #pragma unroll
      for (int q = 0; q < 4; ++q){
        int row = m0 + wr*128 + i*16 + lhi*4 + q;
        Cw[(size_t)row*ldc + col] = f2bf(acc[i][j][q] + bv);
      }
    }
  }
}

// ============ 256Mx128N 8-wave GEMM — 2-phase, full-round grids ============
// EPI 8: fp32 out = acc + res; EPI 9: fp32 out = acc; EPI 10: bf16 out = acc + bias.
template<int EPI>
__global__ __launch_bounds__(512, 2) void k_gemm8pn(
    const u16* __restrict__ A, const u16* __restrict__ Bt,
    const float* __restrict__ bias, const float* __restrict__ res,
    void* __restrict__ Cout,
    int M, int N, int K, int lda, int ldb, int ldc)
{
  extern __shared__ __align__(16) char smem[];
  const int tid = threadIdx.x;
  const int lane = tid & 63, wid = tid >> 6;
  const int wr = wid >> 2, wc = wid & 3;
  const int lrow = lane & 15, lhi = lane >> 4;

  int nwg = gridDim.x, wg = blockIdx.x;
  int nbx = N >> 7, nbm = M >> 8;
  int xcd = wg & 7, sub = wg >> 3;
  int m0, n0;
  if ((nwg & 7) == 0 && (nbm & 1) == 0 && (nbx & 3) == 0){
    int mh = nbm >> 1;
    int mr = sub % mh, nc = sub / mh;
    m0 = (((xcd & 1) * mh) + mr) << 8;
    n0 = (((xcd >> 1) * (nbx >> 2)) + nc) << 7;
  } else {
    int qq = nwg >> 3, rr2 = nwg & 7;
    int swz = (xcd < rr2 ? xcd*(qq+1) : rr2*(qq+1) + (xcd-rr2)*qq) + sub;
    m0 = (swz / nbx) << 8; n0 = (swz % nbx) << 7;
  }

  const int nk = K >> 6;
  const int hA = wr;
  const int gA = wc;

  const u16* aSrc[2][2]; int aDst[2][2];
  #pragma unroll
  for (int q = 0; q < 2; ++q)
    #pragma unroll
    for (int L = 0; L < 2; ++L){
      int p = q*8192 + gA*2048 + L*1024 + lane*16;
      int row = p >> 7;
      int o = (p & 127) ^ ((row & 7) << 4);
      aSrc[q][L] = A + (size_t)(m0 + hA*128 + row)*lda + (o >> 1);
      aDst[q][L] = hA*16384 + p;
    }
  const u16* bSrc[2]; int bDst[2];
  #pragma unroll
  for (int s = 0; s < 2; ++s){
    int p = s*8192 + wid*1024 + lane*16;
    int row = p >> 7;
    int o = (p & 127) ^ ((row & 7) << 4);
    bSrc[s] = Bt + (size_t)(n0 + row)*ldb + (o >> 1);
    bDst[s] = 32768 + p;
  }
  const int xo0 = (lhi*16) ^ ((lrow & 7) << 4);
  const int xo1 = (64 + lhi*16) ^ ((lrow & 7) << 4);

  auto stA = [&](int d, int kk, int q){
    #pragma unroll
    for (int L = 0; L < 2; ++L)
      __builtin_amdgcn_global_load_lds(
        (const AS1 void*)(aSrc[q][L] + kk),
        (AS3 void*)(smem + d*49152 + aDst[q][L]), 16, 0, 0);
  };
  auto stB = [&](int d, int kk){
    #pragma unroll
    for (int s = 0; s < 2; ++s)
      __builtin_amdgcn_global_load_lds(
        (const AS1 void*)(bSrc[s] + kk),
        (AS3 void*)(smem + d*49152 + bDst[s]), 16, 0, 0);
  };
  auto rdA = [&](int d, int rloc, int ks)->bf16x8{
    return *(const bf16x8*)(smem + d*49152 + hA*16384 + rloc*128 + (ks ? xo1 : xo0));
  };
  auto rdB = [&](int d, int rloc, int ks)->bf16x8{
    return *(const bf16x8*)(smem + d*49152 + 32768 + rloc*128 + (ks ? xo1 : xo0));
  };

  f32x4 acc[8][2] = {};

  stA(0, 0, 0); stB(0, 0); stA(0, 0, 1);
  asm volatile("s_waitcnt vmcnt(0)" ::: "memory");
  __builtin_amdgcn_s_barrier();

  for (int t = 0; t < nk; ++t){
    int d = t & 1, dn = d ^ 1, kkn = (t + 1) << 6;
    bool pf = (t + 1 < nk);
    bf16x8 aR[8], bQ[4];

    // ---- phase 0: rows 0-63 ----
    #pragma unroll
    for (int ii = 0; ii < 4; ++ii){
      aR[ii*2]   = rdA(d, ii*16 + lrow, 0);
      aR[ii*2+1] = rdA(d, ii*16 + lrow, 1);
    }
    #pragma unroll
    for (int j = 0; j < 2; ++j){
      bQ[j*2]   = rdB(d, wc*32 + j*16 + lrow, 0);
      bQ[j*2+1] = rdB(d, wc*32 + j*16 + lrow, 1);
    }
    if (pf){ stA(dn, kkn, 0); stB(dn, kkn); }
    __builtin_amdgcn_s_barrier();
    asm volatile("s_waitcnt lgkmcnt(0)" ::: "memory");
    __builtin_amdgcn_sched_barrier(0);
    __builtin_amdgcn_s_setprio(1);
    #pragma unroll
    for (int ii = 0; ii < 4; ++ii)
      #pragma unroll
      for (int j = 0; j < 2; ++j){
        acc[ii][j] = __builtin_amdgcn_mfma_f32_16x16x32_bf16(aR[ii*2],   bQ[j*2],   acc[ii][j], 0, 0, 0);
        acc[ii][j] = __builtin_amdgcn_mfma_f32_16x16x32_bf16(aR[ii*2+1], bQ[j*2+1], acc[ii][j], 0, 0, 0);
      }
    __builtin_amdgcn_s_setprio(0);
    if (pf) asm volatile("s_waitcnt vmcnt(4)" ::: "memory");
    else    asm volatile("s_waitcnt vmcnt(0)" ::: "memory");
    __builtin_amdgcn_sched_barrier(0);
    __builtin_amdgcn_s_barrier();

    // ---- phase 1: rows 64-127 (reuse bQ) ----
    #pragma unroll
    for (int ii = 0; ii < 4; ++ii){
      aR[ii*2]   = rdA(d, 64 + ii*16 + lrow, 0);
      aR[ii*2+1] = rdA(d, 64 + ii*16 + lrow, 1);
    }
    if (pf) stA(dn, kkn, 1);
    __builtin_amdgcn_s_barrier();
    asm volatile("s_waitcnt lgkmcnt(0)" ::: "memory");
    __builtin_amdgcn_sched_barrier(0);
    __builtin_amdgcn_s_setprio(1);
    #pragma unroll
    for (int ii = 0; ii < 4; ++ii)
      #pragma unroll
      for (int j = 0; j < 2; ++j){
        acc[4+ii][j] = __builtin_amdgcn_mfma_f32_16x16x32_bf16(aR[ii*2],   bQ[j*2],   acc[4+ii][j], 0, 0, 0);
        acc[4+ii][j] = __builtin_amdgcn_mfma_f32_16x16x32_bf16(aR[ii*2+1], bQ[j*2+1], acc[4+ii][j], 0, 0, 0);
      }
    __builtin_amdgcn_s_setprio(0);
    if (pf) asm volatile("s_waitcnt vmcnt(2)" ::: "memory");
    else    asm volatile("s_waitcnt vmcnt(0)" ::: "memory");
    __builtin_amdgcn_sched_barrier(0);
    __builtin_amdgcn_s_barrier();
  }

  #pragma unroll
  for (int i = 0; i < 8; ++i){
    #pragma unroll
    for (int j = 0; j < 2; ++j){
      int col = n0 + wc*32 + j*16 + lrow;
      #pragma unroll
      for (int q = 0; q < 4; ++q){
        int row = m0 + wr*128 + i*16 + lhi*4 + q;
        size_t idx = (size_t)row*ldc + col;
        if constexpr (EPI == 10){
          ((u16*)Cout)[idx] = f2bf(acc[i][j][q] + bias[col]);
        } else {
          float v = acc[i][j][q];
          if constexpr (EPI == 8) v += res[idx];
          ((float*)Cout)[idx] = v;
        }
      }
    }
  }
}

// ---- causal flash attention: paired-qblock load balancing (unchanged) ----
__global__ __launch_bounds__(512) void k_attn(
    const u16* __restrict__ Q, const u16* __restrict__ Kb,
    const u16* __restrict__ Vt, u16* __restrict__ O, int ldq)
{
  int tid = threadIdx.x, lane = tid & 63, wave = tid >> 6;
  int lrow = lane & 15, lhi = lane >> 4;
  int bidx = blockIdx.x;
  int bh = bidx >> 3, j = bidx & 7;
  int b = bh >> 4, h = bh & 15;

  __shared__ __align__(16) u16 Kbuf[2][64*128];
  __shared__ __align__(16) u16 Vbuf[2][128*64];
  __shared__ __align__(16) u16 P_lds[8][16*64];
  char* pw = (char*)&P_lds[wave][0];
  const float sc2 = 0.08838834764831845f * 1.44269504088896340736f;

  auto stage = [&](int bufi, int kt){
    int kv0 = kt << 6;
    char* kd = (char*)&Kbuf[bufi][0];
    char* vd = (char*)&Vbuf[bufi][0];
    #pragma unroll
    for (int L = 0; L < 2; ++L){
      int cid = wave*128 + L*64 + lane;
      int r = cid >> 4, c = cid & 15;
      int cg = c ^ (r & 7);
      __builtin_amdgcn_global_load_lds(
        (const AS1 void*)(Kb + (size_t)(b*SS + kv0 + r)*ldq + h*DK + cg*8),
        (AS3 void*)(kd + wave*2048 + L*1024 + lane*16), 16, 0, 0);
      int dd = cid >> 3, c8 = cid & 7;
      int cv = c8 ^ (dd & 7);
      __builtin_amdgcn_global_load_lds(
        (const AS1 void*)(Vt + (size_t)bh*DK*SS + (size_t)dd*SS + kv0 + cv*8),
        (AS3 void*)(vd + wave*2048 + L*1024 + lane*16), 16, 0, 0);
    }
  };

  #pragma unroll 1
  for (int item = 0; item < 2; ++item){
    int qi = item == 0 ? 15 - j : j;
    int qs = qi * 128;
    int nt = 2*qi + 2;
    int qrow = qs + wave * 16;

    bf16x8 qf[4];
    const u16* qbase = Q + (size_t)(b*SS + qrow + lrow)*ldq + h*DK + lhi*8;
    #pragma unroll
    for (int dc = 0; dc < 4; ++dc) qf[dc] = *(const bf16x8*)(qbase + dc*32);

    f32x4 accO[8] = {};
    float mr[4] = {-1e30f,-1e30f,-1e30f,-1e30f};
    float lr[4] = {0.f,0.f,0.f,0.f};

    stage(0, 0);
    __syncthreads();

    for (int kt = 0; kt < nt; ++kt){
      int cur = kt & 1;
      if (kt + 1 < nt) stage(cur ^ 1, kt + 1);
      int kv0 = kt << 6;
      if (kv0 <= qrow + 15){
        const char* kl = (const char*)&Kbuf[cur][0];
        const char* vl = (const char*)&Vbuf[cur][0];
        bool domask = (kv0 + 63 > qrow);

        f32x4 sf[4];
        #pragma unroll
        for (int hf = 0; hf < 4; ++hf){
          int rl = hf*16 + lrow;
          int sw = rl & 7;
          f32x4 a = {};
          #pragma unroll
          for (int dc = 0; dc < 4; ++dc){
            bf16x8 kf = *(const bf16x8*)(kl + rl*256 + (((lhi + dc*4) ^ sw) << 4));
            a = __builtin_amdgcn_mfma_f32_16x16x32_bf16(qf[dc], kf, a, 0, 0, 0);
          }
          sf[hf] = a;
        }

        float p[4][4], mx[4];
        #pragma unroll
        for (int q = 0; q < 4; ++q){
          float s0 = sf[0][q]*sc2, s1 = sf[1][q]*sc2, s2 = sf[2][q]*sc2, s3 = sf[3][q]*sc2;
          if (domask){
            int qg = qrow + lhi*4 + q;
            if (kv0      + lrow > qg) s0 = -1e30f;
            if (kv0 + 16 + lrow > qg) s1 = -1e30f;
            if (kv0 + 32 + lrow > qg) s2 = -1e30f;
            if (kv0 + 48 + lrow > qg) s3 = -1e30f;
          }
          p[q][0]=s0; p[q][1]=s1; p[q][2]=s2; p[q][3]=s3;
          float m = fmaxf(fmaxf(s0,s1), fmaxf(s2,s3));
          m = fmaxf(m, __shfl_xor(m, 1, 64));
          m = fmaxf(m, __shfl_xor(m, 2, 64));
          m = fmaxf(m, __shfl_xor(m, 4, 64));
          m = fmaxf(m, __shfl_xor(m, 8, 64));
          mx[q] = m;
        }
        float dmax = fmaxf(fmaxf(mx[0]-mr[0], mx[1]-mr[1]), fmaxf(mx[2]-mr[2], mx[3]-mr[3]));
        bool rescale = !__all(dmax <= 8.0f);
        float al[4];
        #pragma unroll
        for (int q = 0; q < 4; ++q){
          if (rescale){
            float mn = fmaxf(mr[q], mx[q]);
            al[q] = fexp2(mr[q] - mn);
            mr[q] = mn;
          } else al[q] = 1.0f;
          p[q][0] = fexp2(p[q][0] - mr[q]);
          p[q][1] = fexp2(p[q][1] - mr[q]);
          p[q][2] = fexp2(p[q][2] - mr[q]);
          p[q][3] = fexp2(p[q][3] - mr[q]);
          float sm = (p[q][0] + p[q][1]) + (p[q][2] + p[q][3]);
          sm += __shfl_xor(sm, 1, 64);
          sm += __shfl_xor(sm, 2, 64);
          sm += __shfl_xor(sm, 4, 64);
          sm += __shfl_xor(sm, 8, 64);
          lr[q] = lr[q]*al[q] + sm;
        }
        if (rescale){
          #pragma unroll
          for (int f = 0; f < 8; ++f)
            #pragma unroll
            for (int q = 0; q < 4; ++q) accO[f][q] *= al[q];
        }

        #pragma unroll
        for (int q = 0; q < 4; ++q){
          int row = lhi*4 + q;
          int rb = row*128, sw = (row & 7) << 4;
          #pragma unroll
          for (int hf = 0; hf < 4; ++hf)
            *(u16*)(pw + rb + ((hf*32 + lrow*2) ^ sw)) = cvt_bf16(p[q][hf]);
        }
        __builtin_amdgcn_sched_barrier(0);
        int rsw = (lrow & 7) << 4;
        bf16x8 pa0 = *(const bf16x8*)(pw + lrow*128 + ((     lhi*16) ^ rsw));
        bf16x8 pa1 = *(const bf16x8*)(pw + lrow*128 + ((64 + lhi*16) ^ rsw));

        #pragma unroll
        for (int f = 0; f < 8; ++f){
          int d = f*16 + lrow;
          int swv = d & 7;
          bf16x8 v0 = *(const bf16x8*)(vl + d*128 + (((lhi    ) ^ swv) << 4));
          bf16x8 v1 = *(const bf16x8*)(vl + d*128 + (((lhi + 4) ^ swv) << 4));
          accO[f] = __builtin_amdgcn_mfma_f32_16x16x32_bf16(pa0, v0, accO[f], 0, 0, 0);
          accO[f] = __builtin_amdgcn_mfma_f32_16x16x32_bf16(pa1, v1, accO[f], 0, 0, 0);
        }
      }
      __syncthreads();
    }

    #pragma unroll
    for (int q = 0; q < 4; ++q){
      float inv = 1.0f / lr[q];
      #pragma unroll
      for (int f = 0; f < 8; ++f){
        int row = b*SS + qrow + lhi*4 + q;
        int col = h*DK + f*16 + lrow;
        O[(size_t)row*D_MODEL + col] = cvt_bf16(accO[f][q] * inv);
      }
    }
    __syncthreads();
  }
}

extern "C" void kernel_launch(void* const* d_in, const int* in_sizes, int n_in,
                              void* d_out, int out_size, void* d_ws, size_t ws_size,
                              hipStream_t stream)
{
  (void)in_sizes; (void)n_in; (void)out_size;
  const float* x  = (const float*)d_in[0];
  const float* wq = (const float*)d_in[2];
  const float* bq = (const float*)d_in[3];
  const float* wk = (const float*)d_in[4];
  const float* bk = (const float*)d_in[5];
  const float* wv = (const float*)d_in[6];
  const float* bv = (const float*)d_in[7];
  const float* wo = (const float*)d_in[8];
  const float* bo = (const float*)d_in[9];
  const float* g1 = (const float*)d_in[10];
  const float* g2 = (const float*)d_in[11];
  const float* w1 = (const float*)d_in[12];
  const float* w3 = (const float*)d_in[13];
  const float* w2 = (const float*)d_in[14];
  float* out = (float*)d_out;

  const size_t MB = 1u << 20;
  const size_t W2T_B = (size_t)D_MODEL * DFF * sizeof(u16);
  const size_t NEED = 152*MB + W2T_B + 32768;
  if (ws_size < NEED) return;
  char* ws = (char*)d_ws;
  u16* bufA  = (u16*)(ws + 0);        // 16 MiB: nbf1 -> aob -> nbf2
  u16* qkv   = (u16*)(ws + 16*MB);    // 48 MiB fused QKV [4096][6144]
  u16* h1    = qkv;                   // hg [4096][5632], aliases after attn
  u16* wqkvt = (u16*)(ws + 64*MB);    // 24 MiB, dead after QKV GEMM
  u16* w1w3t = (u16*)(ws + 64*MB);    // [11264][2048] interleaved (64-108)
  u16* wot   = (u16*)(ws + 88*MB);    // 8 MiB (w1w3 transpose AFTER O-proj)
  u16* vtb   = (u16*)(ws + 96*MB);    // 16 MiB (dead after attn)
  float* p0o = (float*)(ws + 16*MB);  // O-proj partial: qkv dead after attn
  u16* w2t   = (u16*)(ws + 152*MB);
  float* bqkv = (float*)(ws + 152*MB + W2T_B);
  // fp32 residual x1 lives in d_out

  hipFuncSetAttribute((const void*)k_gemm8p<11>, hipFuncAttributeMaxDynamicSharedMemorySize, 131072);
  hipFuncSetAttribute((const void*)k_gemm8pn<8>, hipFuncAttributeMaxDynamicSharedMemorySize, 98304);
  hipFuncSetAttribute((const void*)k_gemm8pn<9>, hipFuncAttributeMaxDynamicSharedMemorySize, 98304);
  hipFuncSetAttribute((const void*)k_gemm8pn<10>, hipFuncAttributeMaxDynamicSharedMemorySize, 98304);

  dim3 tb(32, 8);
  k_transpose_w4<<<dim3(64,64,4), tb, 0, stream>>>(wq, wk, wv, wo,
      wqkvt, wqkvt + 2048*2048, wqkvt + 2*2048*2048, wot);
  k_transpose_w<<<dim3(64, DFF/32), tb, 0, stream>>>(w2, w2t, DFF, D_MODEL);
  k_concat3<<<24, 256, 0, stream>>>(bq, bk, bv, bqkv);

  k_rmsnorm<<<MTOK, 256, 0, stream>>>(x, g1, bufA);
  // QKV: 256Mx128N, 768 blocks = 3 full rounds, bf16 + bias
  k_gemm8pn<10><<<(MTOK/256)*(DQKV/128), 512, 98304, stream>>>(bufA, wqkvt, bqkv, nullptr, qkv, MTOK, DQKV, D_MODEL, D_MODEL, D_MODEL, DQKV);
  k_transpose_v<<<dim3(SS/32, 128), tb, 0, stream>>>(qkv + 4096, vtb, DQKV);
  k_attn<<<dim3(BB*NHEADS*8), 512, 0, stream>>>(qkv, qkv + 2048, vtb, bufA, DQKV);
  // O-proj: 256Mx128N, 256 blocks -> single fp32 partial
  k_gemm8pn<9><<<(MTOK/256)*(D_MODEL/128), 512, 98304, stream>>>(bufA, wot, nullptr, nullptr, p0o, MTOK, D_MODEL, D_MODEL, D_MODEL, D_MODEL, D_MODEL);
  // w1|w3 32-col interleaved -> w1w3t (dead wqkvt + wot + vtb): after O-proj & attn
  k_transpose_w13i<<<dim3(DFFP/32, 64, 2), tb, 0, stream>>>(w1, w3, w1w3t);
  k_addres_rms<<<MTOK, 256, 0, stream>>>(x, bo, p0o, g2, out, bufA);
  // W1|W3 interleaved, pure-register silu(h1)*h3 epilogue -> hg (bf16) directly
  k_gemm8p<11><<<(MTOK/256)*((2*DFFP)/256), 512, 131072, stream>>>(bufA, w1w3t, nullptr, nullptr, h1, MTOK, 2*DFFP, D_MODEL, D_MODEL, D_MODEL, DFFP);
  // W2: 256Mx128N, 256 blocks, fused residual -> final out
  k_gemm8pn<8><<<(MTOK/256)*(D_MODEL/128), 512, 98304, stream>>>(h1, w2t, nullptr, out, out, MTOK, D_MODEL, DFF, DFFP, DFF, D_MODEL);
}

// Round 20
// 618.562 us; speedup vs baseline: 1.1103x; 1.0125x over previous
//
#include <hip/hip_runtime.h>
#include <stdint.h>

typedef unsigned short u16;
typedef __bf16 bf16x8 __attribute__((ext_vector_type(8)));
typedef float f32x4 __attribute__((ext_vector_type(4)));

#define D_MODEL 2048
#define NHEADS 16
#define DK 128
#define DFF 5504
#define DFFP 5632
#define BB 2
#define SS 2048
#define MTOK 4096
#define DQKV 6144

#define AS1 __attribute__((address_space(1)))
#define AS3 __attribute__((address_space(3)))

__device__ __forceinline__ u16 f2bf(float f){
  union { float f; uint32_t u; } v; v.f = f;
  uint32_t r = v.u + 0x7fffu + ((v.u >> 16) & 1u);
  return (u16)(r >> 16);
}
__device__ __forceinline__ float bf2f(u16 u){
  union { uint32_t u; float f; } v; v.u = ((uint32_t)u) << 16;
  return v.f;
}
__device__ __forceinline__ u16 cvt_bf16(float f){
  union { __bf16 h; u16 u; } v; v.h = (__bf16)f; return v.u;
}
__device__ __forceinline__ float fexp2(float x){
#if __has_builtin(__builtin_amdgcn_exp2f)
  return __builtin_amdgcn_exp2f(x);
#else
  return exp2f(x);
#endif
}

// ---- fp32 W[K][Nsrc] -> bf16 Wt[n][K], zero-fill n >= Nsrc ----
__global__ __launch_bounds__(256) void k_transpose_w(const float* __restrict__ W,
                                                     u16* __restrict__ Wt, int K, int Nsrc){
  __shared__ float tile[32][33];
  int n0 = blockIdx.x * 32, k0 = blockIdx.y * 32;
  int tx = threadIdx.x, ty = threadIdx.y;
  #pragma unroll
  for (int r = 0; r < 4; ++r){
    int n = n0 + tx;
    tile[ty + r*8][tx] = (n < Nsrc) ? W[(size_t)(k0 + ty + r*8) * Nsrc + n] : 0.0f;
  }
  __syncthreads();
  #pragma unroll
  for (int r = 0; r < 4; ++r)
    Wt[(size_t)(n0 + ty + r*8) * K + k0 + tx] = f2bf(tile[tx][ty + r*8]);
}

// ---- batched 2048x2048 transpose: z selects among 4 matrices ----
__global__ __launch_bounds__(256) void k_transpose_w4(
    const float* __restrict__ w0s, const float* __restrict__ w1s,
    const float* __restrict__ w2s, const float* __restrict__ w3s,
    u16* __restrict__ d0, u16* __restrict__ d1,
    u16* __restrict__ d2, u16* __restrict__ d3){
  __shared__ float tile[32][33];
  const float* W = blockIdx.z == 0 ? w0s : blockIdx.z == 1 ? w1s : blockIdx.z == 2 ? w2s : w3s;
  u16* Wt = blockIdx.z == 0 ? d0 : blockIdx.z == 1 ? d1 : blockIdx.z == 2 ? d2 : d3;
  int n0 = blockIdx.x * 32, k0 = blockIdx.y * 32;
  int tx = threadIdx.x, ty = threadIdx.y;
  #pragma unroll
  for (int r = 0; r < 4; ++r)
    tile[ty + r*8][tx] = W[(size_t)(k0 + ty + r*8) * D_MODEL + n0 + tx];
  __syncthreads();
  #pragma unroll
  for (int r = 0; r < 4; ++r)
    Wt[(size_t)(n0 + ty + r*8) * D_MODEL + k0 + tx] = f2bf(tile[tx][ty + r*8]);
}

// ---- 32-col interleaved w1|w3 transpose: w1 col r -> phys (r>>5)*64+(r&31); w3 -> +32 ----
__global__ __launch_bounds__(256) void k_transpose_w13i(
    const float* __restrict__ w1s, const float* __restrict__ w3s,
    u16* __restrict__ dst){
  __shared__ float tile[32][33];
  const float* W = blockIdx.z == 0 ? w1s : w3s;
  int half = blockIdx.z << 5;   // 0 or 32
  int n0 = blockIdx.x * 32, k0 = blockIdx.y * 32;
  int tx = threadIdx.x, ty = threadIdx.y;
  #pragma unroll
  for (int r = 0; r < 4; ++r){
    int n = n0 + tx;
    tile[ty + r*8][tx] = (n < DFF) ? W[(size_t)(k0 + ty + r*8) * DFF + n] : 0.0f;
  }
  __syncthreads();
  #pragma unroll
  for (int r = 0; r < 4; ++r){
    int nr = n0 + ty + r*8;
    int pr = ((nr >> 5) << 6) + half + (nr & 31);
    dst[(size_t)pr * D_MODEL + k0 + tx] = f2bf(tile[tx][ty + r*8]);
  }
}

// ---- per-head V transpose from fused QKV ----
__global__ __launch_bounds__(256) void k_transpose_v(const u16* __restrict__ V,
                                                     u16* __restrict__ Vt, int ld){
  __shared__ u16 tile[32][33];
  int s0 = blockIdx.x * 32;
  int bh = blockIdx.y >> 2, dt = blockIdx.y & 3;
  int b = bh >> 4, h = bh & 15;
  int tx = threadIdx.x, ty = threadIdx.y;
  #pragma unroll
  for (int r = 0; r < 4; ++r)
    tile[ty + r*8][tx] = V[(size_t)(b*SS + s0 + ty + r*8) * ld + h*DK + dt*32 + tx];
  __syncthreads();
  #pragma unroll
  for (int r = 0; r < 4; ++r)
    Vt[(size_t)(bh*DK + dt*32 + ty + r*8) * SS + s0 + tx] = tile[tx][ty + r*8];
}

__global__ __launch_bounds__(256) void k_concat3(const float* __restrict__ a,
                                                 const float* __restrict__ b,
                                                 const float* __restrict__ c,
                                                 float* __restrict__ o){
  int i = blockIdx.x*256 + threadIdx.x;
  if (i >= DQKV) return;
  o[i] = (i < 2048) ? a[i] : (i < 4096 ? b[i-2048] : c[i-4096]);
}

// ---- RMSNorm: fp32 row -> bf16 row ----
__global__ __launch_bounds__(256) void k_rmsnorm(const float* __restrict__ X,
                                                 const float* __restrict__ g,
                                                 u16* __restrict__ out){
  int row = blockIdx.x, tid = threadIdx.x;
  const float* x = X + (size_t)row * D_MODEL;
  float4 a = ((const float4*)x)[tid*2];
  float4 b = ((const float4*)x)[tid*2+1];
  float ss = a.x*a.x + a.y*a.y + a.z*a.z + a.w*a.w
           + b.x*b.x + b.y*b.y + b.z*b.z + b.w*b.w;
  #pragma unroll
  for (int m = 1; m < 64; m <<= 1) ss += __shfl_xor(ss, m, 64);
  __shared__ float red[4];
  if ((tid & 63) == 0) red[tid >> 6] = ss;
  __syncthreads();
  float tot = red[0] + red[1] + red[2] + red[3];
  float sc = rsqrtf(tot * (1.0f / D_MODEL) + 1e-6f);
  float4 ga = ((const float4*)g)[tid*2];
  float4 gb = ((const float4*)g)[tid*2+1];
  uint32_t w0 = f2bf(a.x*sc*ga.x) | ((uint32_t)f2bf(a.y*sc*ga.y) << 16);
  uint32_t w1 = f2bf(a.z*sc*ga.z) | ((uint32_t)f2bf(a.w*sc*ga.w) << 16);
  uint32_t w2 = f2bf(b.x*sc*gb.x) | ((uint32_t)f2bf(b.y*sc*gb.y) << 16);
  uint32_t w3 = f2bf(b.z*sc*gb.z) | ((uint32_t)f2bf(b.w*sc*gb.w) << 16);
  ((uint4*)(out + (size_t)row * D_MODEL))[tid] = make_uint4(w0, w1, w2, w3);
}

// ============ 256x256 8-wave GEMM — 8-phase (r12-proven schedule) ============
// EPI 11: 32-col-interleaved W1|W3 -> fused silu(h1)*h3 bf16 out, pure register epilogue
template<int EPI>
__global__ __launch_bounds__(512, 2) void k_gemm8p(
    const u16* __restrict__ A, const u16* __restrict__ Bt,
    const float* __restrict__ bias, const u16* __restrict__ aux,
    void* __restrict__ Cout, int M, int N, int K,
    int lda, int ldb, int ldc)
{
  extern __shared__ __align__(16) char smem[];
  const int tid = threadIdx.x;
  const int lane = tid & 63, wid = tid >> 6;
  const int wr = wid >> 2, wc = wid & 3;
  const int lrow = lane & 15, lhi = lane >> 4;

  int nwg = gridDim.x, wg = blockIdx.x;

  int nbx = N >> 8, nbm = M >> 8;
  int xcd = wg & 7, sub = wg >> 3;
  int m0, n0;
  if ((nwg & 7) == 0 && (nbm & 1) == 0 && (nbx & 3) == 0){
    int mh = nbm >> 1;
    int mr = sub % mh, nc = sub / mh;
    m0 = (((xcd & 1) * mh) + mr) << 8;
    n0 = (((xcd >> 1) * (nbx >> 2)) + nc) << 8;
  } else {
    int qq = nwg >> 3, rr2 = nwg & 7;
    int swz = (xcd < rr2 ? xcd*(qq+1) : rr2*(qq+1) + (xcd-rr2)*qq) + sub;
    m0 = (swz / nbx) << 8; n0 = (swz % nbx) << 8;
  }

  const int nk = K >> 6;
  const int hA = wr, hB = wc >> 1;
  const int gA = wc;
  const int gB = (wr << 1) | (wc & 1);

  const u16* aSrc[2][2]; int aDst[2][2];
  const u16* bSrc[2][2]; int bDst[2][2];
  #pragma unroll
  for (int q = 0; q < 2; ++q)
    #pragma unroll
    for (int L = 0; L < 2; ++L){
      int p = q*8192 + gA*2048 + L*1024 + lane*16;
      int row = p >> 7;
      int o = (p & 127) ^ ((row & 7) << 4);
      aSrc[q][L] = A + (size_t)(m0 + hA*128 + row)*lda + (o >> 1);
      aDst[q][L] = hA*16384 + p;
      int pb = q*4096 + (gB >> 1)*8192 + (gB & 1)*2048 + L*1024 + lane*16;
      int rowb = pb >> 7;
      int ob = (pb & 127) ^ ((rowb & 7) << 4);
      bSrc[q][L] = Bt + (size_t)(n0 + hB*128 + rowb)*ldb + (ob >> 1);
      bDst[q][L] = 32768 + hB*16384 + pb;
    }
  const int xo0 = (lhi*16) ^ ((lrow & 7) << 4);
  const int xo1 = (64 + lhi*16) ^ ((lrow & 7) << 4);

  auto stA = [&](int d, int kk, int q){
    #pragma unroll
    for (int L = 0; L < 2; ++L)
      __builtin_amdgcn_global_load_lds(
        (const AS1 void*)(aSrc[q][L] + kk),
        (AS3 void*)(smem + d*65536 + aDst[q][L]), 16, 0, 0);
  };
  auto stB = [&](int d, int kk, int s){
    #pragma unroll
    for (int L = 0; L < 2; ++L)
      __builtin_amdgcn_global_load_lds(
        (const AS1 void*)(bSrc[s][L] + kk),
        (AS3 void*)(smem + d*65536 + bDst[s][L]), 16, 0, 0);
  };
  auto rdA = [&](int d, int rloc, int ks)->bf16x8{
    return *(const bf16x8*)(smem + d*65536 + hA*16384 + rloc*128 + (ks ? xo1 : xo0));
  };
  auto rdB = [&](int d, int rloc, int ks)->bf16x8{
    return *(const bf16x8*)(smem + d*65536 + 32768 + hB*16384 + rloc*128 + (ks ? xo1 : xo0));
  };

  f32x4 acc[8][4] = {};

  stA(0, 0, 0); stB(0, 0, 0); stB(0, 0, 1); stA(0, 0, 1);
  asm volatile("s_waitcnt vmcnt(0)" ::: "memory");
  __builtin_amdgcn_s_barrier();

  for (int t = 0; t < nk; ++t){
    int d = t & 1, dn = d ^ 1, kkn = (t + 1) << 6;
    bool pf = (t + 1 < nk);
    bf16x8 aR[8], bQ0[4], bQ1[4];

    // ---- phase 0: Q00 ----
    #pragma unroll
    for (int ii = 0; ii < 4; ++ii){
      aR[ii*2]   = rdA(d, ii*16 + lrow, 0);
      aR[ii*2+1] = rdA(d, ii*16 + lrow, 1);
    }
    #pragma unroll
    for (int j = 0; j < 2; ++j){
      bQ0[j*2]   = rdB(d, (wc&1)*64 + j*16 + lrow, 0);
      bQ0[j*2+1] = rdB(d, (wc&1)*64 + j*16 + lrow, 1);
    }
    if (pf){ stA(dn, kkn, 0); stB(dn, kkn, 0); }
    __builtin_amdgcn_s_barrier();
    asm volatile("s_waitcnt lgkmcnt(0)" ::: "memory");
    __builtin_amdgcn_sched_barrier(0);
    __builtin_amdgcn_s_setprio(1);
    #pragma unroll
    for (int ii = 0; ii < 4; ++ii)
      #pragma unroll
      for (int j = 0; j < 2; ++j){
        acc[ii][j] = __builtin_amdgcn_mfma_f32_16x16x32_bf16(aR[ii*2],   bQ0[j*2],   acc[ii][j], 0, 0, 0);
        acc[ii][j] = __builtin_amdgcn_mfma_f32_16x16x32_bf16(aR[ii*2+1], bQ0[j*2+1], acc[ii][j], 0, 0, 0);
      }
    __builtin_amdgcn_s_setprio(0);
    if (pf) asm volatile("s_waitcnt vmcnt(6)" ::: "memory");
    else    asm volatile("s_waitcnt vmcnt(2)" ::: "memory");
    __builtin_amdgcn_sched_barrier(0);
    __builtin_amdgcn_s_barrier();

    // ---- phase 1: Q01 ----
    #pragma unroll
    for (int j = 0; j < 2; ++j){
      bQ1[j*2]   = rdB(d, (wc&1)*64 + 32 + j*16 + lrow, 0);
      bQ1[j*2+1] = rdB(d, (wc&1)*64 + 32 + j*16 + lrow, 1);
    }
    if (pf) stB(dn, kkn, 1);
    __builtin_amdgcn_s_barrier();
    asm volatile("s_waitcnt lgkmcnt(0)" ::: "memory");
    __builtin_amdgcn_sched_barrier(0);
    __builtin_amdgcn_s_setprio(1);
    #pragma unroll
    for (int ii = 0; ii < 4; ++ii)
      #pragma unroll
      for (int j = 0; j < 2; ++j){
        acc[ii][2+j] = __builtin_amdgcn_mfma_f32_16x16x32_bf16(aR[ii*2],   bQ1[j*2],   acc[ii][2+j], 0, 0, 0);
        acc[ii][2+j] = __builtin_amdgcn_mfma_f32_16x16x32_bf16(aR[ii*2+1], bQ1[j*2+1], acc[ii][2+j], 0, 0, 0);
      }
    __builtin_amdgcn_s_setprio(0);
    if (pf) asm volatile("s_waitcnt vmcnt(6)" ::: "memory");
    else    asm volatile("s_waitcnt vmcnt(0)" ::: "memory");
    __builtin_amdgcn_sched_barrier(0);
    __builtin_amdgcn_s_barrier();

    // ---- phase 2: Q11 ----
    #pragma unroll
    for (int ii = 0; ii < 4; ++ii){
      aR[ii*2]   = rdA(d, 64 + ii*16 + lrow, 0);
      aR[ii*2+1] = rdA(d, 64 + ii*16 + lrow, 1);
    }
    if (pf) stA(dn, kkn, 1);
    __builtin_amdgcn_s_barrier();
    asm volatile("s_waitcnt lgkmcnt(0)" ::: "memory");
    __builtin_amdgcn_sched_barrier(0);
    __builtin_amdgcn_s_setprio(1);
    #pragma unroll
    for (int ii = 0; ii < 4; ++ii)
      #pragma unroll
      for (int j = 0; j < 2; ++j){
        acc[4+ii][2+j] = __builtin_amdgcn_mfma_f32_16x16x32_bf16(aR[ii*2],   bQ1[j*2],   acc[4+ii][2+j], 0, 0, 0);
        acc[4+ii][2+j] = __builtin_amdgcn_mfma_f32_16x16x32_bf16(aR[ii*2+1], bQ1[j*2+1], acc[4+ii][2+j], 0, 0, 0);
      }
    __builtin_amdgcn_s_setprio(0);
    __builtin_amdgcn_s_barrier();

    // ---- phase 3: Q10 ----
    __builtin_amdgcn_s_setprio(1);
    #pragma unroll
    for (int ii = 0; ii < 4; ++ii)
      #pragma unroll
      for (int j = 0; j < 2; ++j){
        acc[4+ii][j] = __builtin_amdgcn_mfma_f32_16x16x32_bf16(aR[ii*2],   bQ0[j*2],   acc[4+ii][j], 0, 0, 0);
        acc[4+ii][j] = __builtin_amdgcn_mfma_f32_16x16x32_bf16(aR[ii*2+1], bQ0[j*2+1], acc[4+ii][j], 0, 0, 0);
      }
    __builtin_amdgcn_s_setprio(0);
    if (pf) asm volatile("s_waitcnt vmcnt(4)" ::: "memory");
    __builtin_amdgcn_sched_barrier(0);
    __builtin_amdgcn_s_barrier();
  }

  if constexpr (EPI == 11){
    // 32-col interleave: acc[i][j] (j<2) = h1, acc[i][j+2] = h3 of SAME logical col
    u16* hg = (u16*)Cout;
    int cbase = (n0 >> 1) + wc*32;
    #pragma unroll
    for (int i = 0; i < 8; ++i)
      #pragma unroll
      for (int j = 0; j < 2; ++j){
        int col = cbase + j*16 + lrow;
        #pragma unroll
        for (int q = 0; q < 4; ++q){
          int row = m0 + wr*128 + i*16 + lhi*4 + q;
          float h1v = acc[i][j][q];
          float h3v = acc[i][j+2][q];
          float v = h1v / (1.f + __expf(-h1v)) * h3v;
          hg[(size_t)row*ldc + col] = f2bf(v);
        }
      }
    return;
  }
  // generic bf16 epilogue (unused EPI values)
  u16* Cw = (u16*)Cout;
  #pragma unroll
  for (int i = 0; i < 8; ++i){
    #pragma unroll
    for (int j = 0; j < 4; ++j){
      int col = n0 + wc*64 + j*16 + lrow;
      float bv = 0.f;
      if constexpr (EPI == 0) bv = bias[col];
      #pragma unroll
      for (int q = 0; q < 4; ++q){
        int row = m0 + wr*128 + i*16 + lhi*4 + q;
        Cw[(size_t)row*ldc + col] = f2bf(acc[i][j][q] + bv);
      }
    }
  }
}

// ============ 256Mx128N 8-wave GEMM — 2-phase, full-round grids ============
// EPI 8: fp32 out = acc + res; EPI 9: fp32 out = acc; EPI 10: bf16 out = acc + bias;
// EPI 12: fp32 out = acc + res + bias (O-proj fused residual+bias).
template<int EPI>
__global__ __launch_bounds__(512, 2) void k_gemm8pn(
    const u16* __restrict__ A, const u16* __restrict__ Bt,
    const float* __restrict__ bias, const float* __restrict__ res,
    void* __restrict__ Cout,
    int M, int N, int K, int lda, int ldb, int ldc)
{
  extern __shared__ __align__(16) char smem[];
  const int tid = threadIdx.x;
  const int lane = tid & 63, wid = tid >> 6;
  const int wr = wid >> 2, wc = wid & 3;
  const int lrow = lane & 15, lhi = lane >> 4;

  int nwg = gridDim.x, wg = blockIdx.x;
  int nbx = N >> 7, nbm = M >> 8;
  int xcd = wg & 7, sub = wg >> 3;
  int m0, n0;
  if ((nwg & 7) == 0 && (nbm & 1) == 0 && (nbx & 3) == 0){
    int mh = nbm >> 1;
    int mr = sub % mh, nc = sub / mh;
    m0 = (((xcd & 1) * mh) + mr) << 8;
    n0 = (((xcd >> 1) * (nbx >> 2)) + nc) << 7;
  } else {
    int qq = nwg >> 3, rr2 = nwg & 7;
    int swz = (xcd < rr2 ? xcd*(qq+1) : rr2*(qq+1) + (xcd-rr2)*qq) + sub;
    m0 = (swz / nbx) << 8; n0 = (swz % nbx) << 7;
  }

  const int nk = K >> 6;
  const int hA = wr;
  const int gA = wc;

  const u16* aSrc[2][2]; int aDst[2][2];
  #pragma unroll
  for (int q = 0; q < 2; ++q)
    #pragma unroll
    for (int L = 0; L < 2; ++L){
      int p = q*8192 + gA*2048 + L*1024 + lane*16;
      int row = p >> 7;
      int o = (p & 127) ^ ((row & 7) << 4);
      aSrc[q][L] = A + (size_t)(m0 + hA*128 + row)*lda + (o >> 1);
      aDst[q][L] = hA*16384 + p;
    }
  const u16* bSrc[2]; int bDst[2];
  #pragma unroll
  for (int s = 0; s < 2; ++s){
    int p = s*8192 + wid*1024 + lane*16;
    int row = p >> 7;
    int o = (p & 127) ^ ((row & 7) << 4);
    bSrc[s] = Bt + (size_t)(n0 + row)*ldb + (o >> 1);
    bDst[s] = 32768 + p;
  }
  const int xo0 = (lhi*16) ^ ((lrow & 7) << 4);
  const int xo1 = (64 + lhi*16) ^ ((lrow & 7) << 4);

  auto stA = [&](int d, int kk, int q){
    #pragma unroll
    for (int L = 0; L < 2; ++L)
      __builtin_amdgcn_global_load_lds(
        (const AS1 void*)(aSrc[q][L] + kk),
        (AS3 void*)(smem + d*49152 + aDst[q][L]), 16, 0, 0);
  };
  auto stB = [&](int d, int kk){
    #pragma unroll
    for (int s = 0; s < 2; ++s)
      __builtin_amdgcn_global_load_lds(
        (const AS1 void*)(bSrc[s] + kk),
        (AS3 void*)(smem + d*49152 + bDst[s]), 16, 0, 0);
  };
  auto rdA = [&](int d, int rloc, int ks)->bf16x8{
    return *(const bf16x8*)(smem + d*49152 + hA*16384 + rloc*128 + (ks ? xo1 : xo0));
  };
  auto rdB = [&](int d, int rloc, int ks)->bf16x8{
    return *(const bf16x8*)(smem + d*49152 + 32768 + rloc*128 + (ks ? xo1 : xo0));
  };

  f32x4 acc[8][2] = {};

  stA(0, 0, 0); stB(0, 0); stA(0, 0, 1);
  asm volatile("s_waitcnt vmcnt(0)" ::: "memory");
  __builtin_amdgcn_s_barrier();

  for (int t = 0; t < nk; ++t){
    int d = t & 1, dn = d ^ 1, kkn = (t + 1) << 6;
    bool pf = (t + 1 < nk);
    bf16x8 aR[8], bQ[4];

    // ---- phase 0: rows 0-63 ----
    #pragma unroll
    for (int ii = 0; ii < 4; ++ii){
      aR[ii*2]   = rdA(d, ii*16 + lrow, 0);
      aR[ii*2+1] = rdA(d, ii*16 + lrow, 1);
    }
    #pragma unroll
    for (int j = 0; j < 2; ++j){
      bQ[j*2]   = rdB(d, wc*32 + j*16 + lrow, 0);
      bQ[j*2+1] = rdB(d, wc*32 + j*16 + lrow, 1);
    }
    if (pf){ stA(dn, kkn, 0); stB(dn, kkn); }
    __builtin_amdgcn_s_barrier();
    asm volatile("s_waitcnt lgkmcnt(0)" ::: "memory");
    __builtin_amdgcn_sched_barrier(0);
    __builtin_amdgcn_s_setprio(1);
    #pragma unroll
    for (int ii = 0; ii < 4; ++ii)
      #pragma unroll
      for (int j = 0; j < 2; ++j){
        acc[ii][j] = __builtin_amdgcn_mfma_f32_16x16x32_bf16(aR[ii*2],   bQ[j*2],   acc[ii][j], 0, 0, 0);
        acc[ii][j] = __builtin_amdgcn_mfma_f32_16x16x32_bf16(aR[ii*2+1], bQ[j*2+1], acc[ii][j], 0, 0, 0);
      }
    __builtin_amdgcn_s_setprio(0);
    if (pf) asm volatile("s_waitcnt vmcnt(4)" ::: "memory");
    else    asm volatile("s_waitcnt vmcnt(0)" ::: "memory");
    __builtin_amdgcn_sched_barrier(0);
    __builtin_amdgcn_s_barrier();

    // ---- phase 1: rows 64-127 (reuse bQ) ----
    #pragma unroll
    for (int ii = 0; ii < 4; ++ii){
      aR[ii*2]   = rdA(d, 64 + ii*16 + lrow, 0);
      aR[ii*2+1] = rdA(d, 64 + ii*16 + lrow, 1);
    }
    if (pf) stA(dn, kkn, 1);
    __builtin_amdgcn_s_barrier();
    asm volatile("s_waitcnt lgkmcnt(0)" ::: "memory");
    __builtin_amdgcn_sched_barrier(0);
    __builtin_amdgcn_s_setprio(1);
    #pragma unroll
    for (int ii = 0; ii < 4; ++ii)
      #pragma unroll
      for (int j = 0; j < 2; ++j){
        acc[4+ii][j] = __builtin_amdgcn_mfma_f32_16x16x32_bf16(aR[ii*2],   bQ[j*2],   acc[4+ii][j], 0, 0, 0);
        acc[4+ii][j] = __builtin_amdgcn_mfma_f32_16x16x32_bf16(aR[ii*2+1], bQ[j*2+1], acc[4+ii][j], 0, 0, 0);
      }
    __builtin_amdgcn_s_setprio(0);
    if (pf) asm volatile("s_waitcnt vmcnt(2)" ::: "memory");
    else    asm volatile("s_waitcnt vmcnt(0)" ::: "memory");
    __builtin_amdgcn_sched_barrier(0);
    __builtin_amdgcn_s_barrier();
  }

  #pragma unroll
  for (int i = 0; i < 8; ++i){
    #pragma unroll
    for (int j = 0; j < 2; ++j){
      int col = n0 + wc*32 + j*16 + lrow;
      #pragma unroll
      for (int q = 0; q < 4; ++q){
        int row = m0 + wr*128 + i*16 + lhi*4 + q;
        size_t idx = (size_t)row*ldc + col;
        if constexpr (EPI == 10){
          ((u16*)Cout)[idx] = f2bf(acc[i][j][q] + bias[col]);
        } else {
          float v = acc[i][j][q];
          if constexpr (EPI == 8) v += res[idx];
          if constexpr (EPI == 12) v += res[idx] + bias[col];
          ((float*)Cout)[idx] = v;
        }
      }
    }
  }
}

// ---- causal flash attention: paired-qblock load balancing (unchanged) ----
__global__ __launch_bounds__(512) void k_attn(
    const u16* __restrict__ Q, const u16* __restrict__ Kb,
    const u16* __restrict__ Vt, u16* __restrict__ O, int ldq)
{
  int tid = threadIdx.x, lane = tid & 63, wave = tid >> 6;
  int lrow = lane & 15, lhi = lane >> 4;
  int bidx = blockIdx.x;
  int bh = bidx >> 3, j = bidx & 7;
  int b = bh >> 4, h = bh & 15;

  __shared__ __align__(16) u16 Kbuf[2][64*128];
  __shared__ __align__(16) u16 Vbuf[2][128*64];
  __shared__ __align__(16) u16 P_lds[8][16*64];
  char* pw = (char*)&P_lds[wave][0];
  const float sc2 = 0.08838834764831845f * 1.44269504088896340736f;

  auto stage = [&](int bufi, int kt){
    int kv0 = kt << 6;
    char* kd = (char*)&Kbuf[bufi][0];
    char* vd = (char*)&Vbuf[bufi][0];
    #pragma unroll
    for (int L = 0; L < 2; ++L){
      int cid = wave*128 + L*64 + lane;
      int r = cid >> 4, c = cid & 15;
      int cg = c ^ (r & 7);
      __builtin_amdgcn_global_load_lds(
        (const AS1 void*)(Kb + (size_t)(b*SS + kv0 + r)*ldq + h*DK + cg*8),
        (AS3 void*)(kd + wave*2048 + L*1024 + lane*16), 16, 0, 0);
      int dd = cid >> 3, c8 = cid & 7;
      int cv = c8 ^ (dd & 7);
      __builtin_amdgcn_global_load_lds(
        (const AS1 void*)(Vt + (size_t)bh*DK*SS + (size_t)dd*SS + kv0 + cv*8),
        (AS3 void*)(vd + wave*2048 + L*1024 + lane*16), 16, 0, 0);
    }
  };

  #pragma unroll 1
  for (int item = 0; item < 2; ++item){
    int qi = item == 0 ? 15 - j : j;
    int qs = qi * 128;
    int nt = 2*qi + 2;
    int qrow = qs + wave * 16;

    bf16x8 qf[4];
    const u16* qbase = Q + (size_t)(b*SS + qrow + lrow)*ldq + h*DK + lhi*8;
    #pragma unroll
    for (int dc = 0; dc < 4; ++dc) qf[dc] = *(const bf16x8*)(qbase + dc*32);

    f32x4 accO[8] = {};
    float mr[4] = {-1e30f,-1e30f,-1e30f,-1e30f};
    float lr[4] = {0.f,0.f,0.f,0.f};

    stage(0, 0);
    __syncthreads();

    for (int kt = 0; kt < nt; ++kt){
      int cur = kt & 1;
      if (kt + 1 < nt) stage(cur ^ 1, kt + 1);
      int kv0 = kt << 6;
      if (kv0 <= qrow + 15){
        const char* kl = (const char*)&Kbuf[cur][0];
        const char* vl = (const char*)&Vbuf[cur][0];
        bool domask = (kv0 + 63 > qrow);

        f32x4 sf[4];
        #pragma unroll
        for (int hf = 0; hf < 4; ++hf){
          int rl = hf*16 + lrow;
          int sw = rl & 7;
          f32x4 a = {};
          #pragma unroll
          for (int dc = 0; dc < 4; ++dc){
            bf16x8 kf = *(const bf16x8*)(kl + rl*256 + (((lhi + dc*4) ^ sw) << 4));
            a = __builtin_amdgcn_mfma_f32_16x16x32_bf16(qf[dc], kf, a, 0, 0, 0);
          }
          sf[hf] = a;
        }

        float p[4][4], mx[4];
        #pragma unroll
        for (int q = 0; q < 4; ++q){
          float s0 = sf[0][q]*sc2, s1 = sf[1][q]*sc2, s2 = sf[2][q]*sc2, s3 = sf[3][q]*sc2;
          if (domask){
            int qg = qrow + lhi*4 + q;
            if (kv0      + lrow > qg) s0 = -1e30f;
            if (kv0 + 16 + lrow > qg) s1 = -1e30f;
            if (kv0 + 32 + lrow > qg) s2 = -1e30f;
            if (kv0 + 48 + lrow > qg) s3 = -1e30f;
          }
          p[q][0]=s0; p[q][1]=s1; p[q][2]=s2; p[q][3]=s3;
          float m = fmaxf(fmaxf(s0,s1), fmaxf(s2,s3));
          m = fmaxf(m, __shfl_xor(m, 1, 64));
          m = fmaxf(m, __shfl_xor(m, 2, 64));
          m = fmaxf(m, __shfl_xor(m, 4, 64));
          m = fmaxf(m, __shfl_xor(m, 8, 64));
          mx[q] = m;
        }
        float dmax = fmaxf(fmaxf(mx[0]-mr[0], mx[1]-mr[1]), fmaxf(mx[2]-mr[2], mx[3]-mr[3]));
        bool rescale = !__all(dmax <= 8.0f);
        float al[4];
        #pragma unroll
        for (int q = 0; q < 4; ++q){
          if (rescale){
            float mn = fmaxf(mr[q], mx[q]);
            al[q] = fexp2(mr[q] - mn);
            mr[q] = mn;
          } else al[q] = 1.0f;
          p[q][0] = fexp2(p[q][0] - mr[q]);
          p[q][1] = fexp2(p[q][1] - mr[q]);
          p[q][2] = fexp2(p[q][2] - mr[q]);
          p[q][3] = fexp2(p[q][3] - mr[q]);
          float sm = (p[q][0] + p[q][1]) + (p[q][2] + p[q][3]);
          sm += __shfl_xor(sm, 1, 64);
          sm += __shfl_xor(sm, 2, 64);
          sm += __shfl_xor(sm, 4, 64);
          sm += __shfl_xor(sm, 8, 64);
          lr[q] = lr[q]*al[q] + sm;
        }
        if (rescale){
          #pragma unroll
          for (int f = 0; f < 8; ++f)
            #pragma unroll
            for (int q = 0; q < 4; ++q) accO[f][q] *= al[q];
        }

        #pragma unroll
        for (int q = 0; q < 4; ++q){
          int row = lhi*4 + q;
          int rb = row*128, sw = (row & 7) << 4;
          #pragma unroll
          for (int hf = 0; hf < 4; ++hf)
            *(u16*)(pw + rb + ((hf*32 + lrow*2) ^ sw)) = cvt_bf16(p[q][hf]);
        }
        __builtin_amdgcn_sched_barrier(0);
        int rsw = (lrow & 7) << 4;
        bf16x8 pa0 = *(const bf16x8*)(pw + lrow*128 + ((     lhi*16) ^ rsw));
        bf16x8 pa1 = *(const bf16x8*)(pw + lrow*128 + ((64 + lhi*16) ^ rsw));

        #pragma unroll
        for (int f = 0; f < 8; ++f){
          int d = f*16 + lrow;
          int swv = d & 7;
          bf16x8 v0 = *(const bf16x8*)(vl + d*128 + (((lhi    ) ^ swv) << 4));
          bf16x8 v1 = *(const bf16x8*)(vl + d*128 + (((lhi + 4) ^ swv) << 4));
          accO[f] = __builtin_amdgcn_mfma_f32_16x16x32_bf16(pa0, v0, accO[f], 0, 0, 0);
          accO[f] = __builtin_amdgcn_mfma_f32_16x16x32_bf16(pa1, v1, accO[f], 0, 0, 0);
        }
      }
      __syncthreads();
    }

    #pragma unroll
    for (int q = 0; q < 4; ++q){
      float inv = 1.0f / lr[q];
      #pragma unroll
      for (int f = 0; f < 8; ++f){
        int row = b*SS + qrow + lhi*4 + q;
        int col = h*DK + f*16 + lrow;
        O[(size_t)row*D_MODEL + col] = cvt_bf16(accO[f][q] * inv);
      }
    }
    __syncthreads();
  }
}

extern "C" void kernel_launch(void* const* d_in, const int* in_sizes, int n_in,
                              void* d_out, int out_size, void* d_ws, size_t ws_size,
                              hipStream_t stream)
{
  (void)in_sizes; (void)n_in; (void)out_size;
  const float* x  = (const float*)d_in[0];
  const float* wq = (const float*)d_in[2];
  const float* bq = (const float*)d_in[3];
  const float* wk = (const float*)d_in[4];
  const float* bk = (const float*)d_in[5];
  const float* wv = (const float*)d_in[6];
  const float* bv = (const float*)d_in[7];
  const float* wo = (const float*)d_in[8];
  const float* bo = (const float*)d_in[9];
  const float* g1 = (const float*)d_in[10];
  const float* g2 = (const float*)d_in[11];
  const float* w1 = (const float*)d_in[12];
  const float* w3 = (const float*)d_in[13];
  const float* w2 = (const float*)d_in[14];
  float* out = (float*)d_out;

  const size_t MB = 1u << 20;
  const size_t W2T_B = (size_t)D_MODEL * DFF * sizeof(u16);
  const size_t NEED = 152*MB + W2T_B + 32768;
  if (ws_size < NEED) return;
  char* ws = (char*)d_ws;
  u16* bufA  = (u16*)(ws + 0);        // 16 MiB: nbf1 -> aob -> nbf2
  u16* qkv   = (u16*)(ws + 16*MB);    // 48 MiB fused QKV [4096][6144]
  u16* h1    = qkv;                   // hg [4096][5632], aliases after attn
  u16* wqkvt = (u16*)(ws + 64*MB);    // 24 MiB, dead after QKV GEMM
  u16* w1w3t = (u16*)(ws + 64*MB);    // [11264][2048] interleaved (64-108)
  u16* wot   = (u16*)(ws + 88*MB);    // 8 MiB (w1w3 transpose AFTER O-proj)
  u16* vtb   = (u16*)(ws + 96*MB);    // 16 MiB (dead after attn)
  u16* w2t   = (u16*)(ws + 152*MB);
  float* bqkv = (float*)(ws + 152*MB + W2T_B);
  // fp32 residual x1 lives in d_out

  hipFuncSetAttribute((const void*)k_gemm8p<11>, hipFuncAttributeMaxDynamicSharedMemorySize, 131072);
  hipFuncSetAttribute((const void*)k_gemm8pn<8>, hipFuncAttributeMaxDynamicSharedMemorySize, 98304);
  hipFuncSetAttribute((const void*)k_gemm8pn<10>, hipFuncAttributeMaxDynamicSharedMemorySize, 98304);
  hipFuncSetAttribute((const void*)k_gemm8pn<12>, hipFuncAttributeMaxDynamicSharedMemorySize, 98304);

  dim3 tb(32, 8);
  k_transpose_w4<<<dim3(64,64,4), tb, 0, stream>>>(wq, wk, wv, wo,
      wqkvt, wqkvt + 2048*2048, wqkvt + 2*2048*2048, wot);
  k_transpose_w<<<dim3(64, DFF/32), tb, 0, stream>>>(w2, w2t, DFF, D_MODEL);
  k_concat3<<<24, 256, 0, stream>>>(bq, bk, bv, bqkv);

  k_rmsnorm<<<MTOK, 256, 0, stream>>>(x, g1, bufA);
  // QKV: 256Mx128N, 768 blocks = 3 full rounds, bf16 + bias
  k_gemm8pn<10><<<(MTOK/256)*(DQKV/128), 512, 98304, stream>>>(bufA, wqkvt, bqkv, nullptr, qkv, MTOK, DQKV, D_MODEL, D_MODEL, D_MODEL, DQKV);
  k_transpose_v<<<dim3(SS/32, 128), tb, 0, stream>>>(qkv + 4096, vtb, DQKV);
  k_attn<<<dim3(BB*NHEADS*8), 512, 0, stream>>>(qkv, qkv + 2048, vtb, bufA, DQKV);
  // O-proj: 256Mx128N, fused residual+bias -> fp32 out directly (x1)
  k_gemm8pn<12><<<(MTOK/256)*(D_MODEL/128), 512, 98304, stream>>>(bufA, wot, bo, x, out, MTOK, D_MODEL, D_MODEL, D_MODEL, D_MODEL, D_MODEL);
  // w1|w3 32-col interleaved -> w1w3t (dead wqkvt + wot + vtb): after O-proj & attn
  k_transpose_w13i<<<dim3(DFFP/32, 64, 2), tb, 0, stream>>>(w1, w3, w1w3t);
  // rmsnorm2: out -> bufA (bf16)
  k_rmsnorm<<<MTOK, 256, 0, stream>>>(out, g2, bufA);
  // W1|W3 interleaved, pure-register silu(h1)*h3 epilogue -> hg (bf16) directly
  k_gemm8p<11><<<(MTOK/256)*((2*DFFP)/256), 512, 131072, stream>>>(bufA, w1w3t, nullptr, nullptr, h1, MTOK, 2*DFFP, D_MODEL, D_MODEL, D_MODEL, DFFP);
  // W2: 256Mx128N, 256 blocks, fused residual -> final out
  k_gemm8pn<8><<<(MTOK/256)*(D_MODEL/128), 512, 98304, stream>>>(h1, w2t, nullptr, out, out, MTOK, D_MODEL, DFF, DFFP, DFF, D_MODEL);
}